// Round 7
// baseline (407.219 us; speedup 1.0000x reference)
//
#include <hip/hip_runtime.h>
#include <math.h>

#define NN 4096

static __device__ __forceinline__ unsigned enc_f(float f){
    unsigned u = __float_as_uint(f);
    return (u & 0x80000000u) ? ~u : (u | 0x80000000u);
}
static __device__ __forceinline__ float dec_f(unsigned u){
    unsigned b = (u & 0x80000000u) ? (u & 0x7fffffffu) : ~u;
    return __uint_as_float(b);
}

// ---------- phase 1: x0 assembly + Ot column sums ----------
__global__ void k_prep(const float* __restrict__ dx1, const float* __restrict__ dx2,
                       const float* __restrict__ Wk, const float* __restrict__ bk,
                       float* __restrict__ x0, float* __restrict__ colsum){
    int n = blockIdx.x*blockDim.x + threadIdx.x;
    if (n >= NN) return;
    float wk[8];
    #pragma unroll
    for (int j=0;j<8;j++) wk[j] = Wk[j];
    float bkv = bk[0];
    #pragma unroll
    for (int c=0;c<4;c++) x0[n*8+c] = dx1[n*4+c];
    #pragma unroll
    for (int c=0;c<4;c++){
        float acc = bkv;
        #pragma unroll
        for (int j=0;j<8;j++) acc += dx2[(n*8+j)*4+c]*wk[j];
        x0[n*8+4+c] = acc;
        atomicAdd(&colsum[c], acc);
    }
}

// ---------- phase 1b: Ty[j] = sum over valid output pos of Cy * Ot ----------
__global__ void k_ty(const float* __restrict__ x0,
        const float* __restrict__ Wcy3, const float* __restrict__ Wcy5, const float* __restrict__ Wcy9,
        float* __restrict__ Ty){
    int j = blockIdx.x*256 + threadIdx.x;
    if (j >= NN) return;
    float Cy[9];
    #pragma unroll
    for (int o=-4;o<=4;o++){
        float c = Wcy9[o+4];
        if (o>=-2 && o<=2) c += Wcy5[o+2];
        if (o>=-1 && o<=1) c += Wcy3[o+1];
        Cy[o+4] = c;
    }
    float4 acc = {0,0,0,0};
    #pragma unroll
    for (int o=-4;o<=4;o++){
        int jj = j - o;
        if ((unsigned)jj < NN){
            float4 ot = *(const float4*)&x0[jj*8+4];
            float c = Cy[o+4];
            acc.x += c*ot.x; acc.y += c*ot.y; acc.z += c*ot.z; acc.w += c*ot.w;
        }
    }
    *(float4*)&Ty[j*4] = acc;
}

// ---------- phase 2: row max dist + top-9 knn + in-deg counts + dOt ----------
__global__ __launch_bounds__(256) void k_dist(const float* __restrict__ dx1,
        const float* __restrict__ x0,
        float* __restrict__ maxd, int* __restrict__ nbr,
        int* __restrict__ cnt3, int* __restrict__ cnt5, int* __restrict__ cnt9,
        float* __restrict__ dOt){
    __shared__ float2 ps[NN];
    int tid = threadIdx.x;
    for (int j=tid; j<NN; j+=256){
        float4 v = *(const float4*)&dx1[j*4];
        ps[j] = make_float2(v.x, v.y);
    }
    __syncthreads();
    int lane = tid & 63;
    int i = blockIdx.x*4 + (tid>>6);
    float2 pi = ps[i];
    unsigned long long best[9];
    #pragma unroll
    for (int q=0;q<9;q++) best[q] = ~0ULL;
    float lmax = 0.f;
    float4 dacc = {0,0,0,0};
    for (int t=0;t<64;t++){
        int j = (t<<6) | lane;
        float2 p = ps[j];
        float dx = pi.x - p.x, dy = pi.y - p.y;
        float d = sqrtf(dx*dx + dy*dy);
        lmax = fmaxf(lmax, d);
        float4 otj = *(const float4*)&x0[j*8+4];
        dacc.x += d*otj.x; dacc.y += d*otj.y; dacc.z += d*otj.z; dacc.w += d*otj.w;
        unsigned long long cand = ((unsigned long long)__float_as_uint(d) << 32) | (unsigned)j;
        if (j != i && cand < best[8]){
            best[8] = cand;
            #pragma unroll
            for (int q=8; q>0; --q){
                if (best[q] < best[q-1]){ unsigned long long tm=best[q]; best[q]=best[q-1]; best[q-1]=tm; }
            }
        }
    }
    #pragma unroll
    for (int m=1;m<64;m<<=1){
        lmax = fmaxf(lmax, __shfl_xor(lmax, m, 64));
        dacc.x += __shfl_xor(dacc.x, m, 64);
        dacc.y += __shfl_xor(dacc.y, m, 64);
        dacc.z += __shfl_xor(dacc.z, m, 64);
        dacc.w += __shfl_xor(dacc.w, m, 64);
    }
    if (lane==0){
        maxd[i] = lmax;
        *(float4*)&dOt[i*4] = dacc;
    }
    for (int t=0;t<9;t++){
        unsigned long long w = best[0];
        #pragma unroll
        for (int m=1;m<64;m<<=1){
            unsigned long long o = __shfl_xor(w, m, 64);
            if (o < w) w = o;
        }
        if (best[0] == w){
            #pragma unroll
            for (int q=0;q<8;q++) best[q] = best[q+1];
            best[8] = ~0ULL;
        }
        if (lane==0){
            int j = (int)(w & 0xffffffffu);
            nbr[i*9+t] = j;
            atomicAdd(&cnt9[j], 1);
            if (t<5) atomicAdd(&cnt5[j], 1);
            if (t<3) atomicAdd(&cnt3[j], 1);
        }
    }
}

// ---------- phase 2b: CSR offsets (exclusive scan) + dinv ----------
__global__ __launch_bounds__(256) void k_scan(const int* __restrict__ cnt3,
        const int* __restrict__ cnt5, const int* __restrict__ cnt9,
        int* __restrict__ offc, float* __restrict__ dinvc){
    __shared__ int part[256];
    int tid = threadIdx.x;
    for (int g=0; g<3; g++){
        const int* cp = g==0?cnt3:(g==1?cnt5:cnt9);
        int base = tid*16;
        int loc[16]; int s=0;
        #pragma unroll
        for (int q=0;q<16;q++){ loc[q]=s; s += cp[base+q]; }
        part[tid]=s; __syncthreads();
        for (int d=1; d<256; d<<=1){
            int v = (tid>=d) ? part[tid-d] : 0;
            __syncthreads();
            part[tid] += v;
            __syncthreads();
        }
        int pre = (tid==0) ? 0 : part[tid-1];
        #pragma unroll
        for (int q=0;q<16;q++){
            offc[g*NN + base + q]  = pre + loc[q];
            dinvc[g*NN + base + q] = rsqrtf((float)cp[base+q] + 1.f);
        }
        __syncthreads();
    }
}

// ---------- phase 2c: fill reverse-edge lists ----------
__global__ void k_fill(const int* __restrict__ nbr, const int* __restrict__ offc,
        int* __restrict__ cur, int* __restrict__ rev){
    int i = blockIdx.x*256 + threadIdx.x;
    if (i >= NN) return;
    #pragma unroll
    for (int t=0;t<9;t++){
        int j = nbr[i*9+t];
        int gmin = t<3 ? 0 : (t<5 ? 1 : 2);
        for (int g=gmin; g<3; g++){
            int pos = atomicAdd(&cur[g*NN+j], 1);
            int rb = (g==0) ? 0 : (g==1 ? NN*3 : NN*8);
            rev[rb + offc[g*NN+j] + pos] = i;
        }
    }
}

// ---------- phase 3: GCN layer-1 input transform ----------
__global__ void k_y1(const float* __restrict__ x0, const float* __restrict__ Wg1,
                     float* __restrict__ xw){
    int idx = blockIdx.x*256 + threadIdx.x;
    if (idx >= NN*64) return;
    int n = idx>>6, c = idx&63;
    float acc = 0.f;
    #pragma unroll
    for (int k=0;k<8;k++) acc += x0[n*8+k]*Wg1[k*64+c];
    xw[idx] = acc;
}

// ---------- phase 3b: gather layer-1 + relu + layer-2 matmul ----------
__global__ __launch_bounds__(256) void k_h1y2(const float* __restrict__ xw,
        const int* __restrict__ offc,
        const int* __restrict__ cnt3, const int* __restrict__ cnt5, const int* __restrict__ cnt9,
        const int* __restrict__ rev, const float* __restrict__ dinvc,
        const float* __restrict__ bg1, const float* __restrict__ Wg2,
        float* __restrict__ y2){
    __shared__ float h1s[12][64];
    int n0 = blockIdx.x*4, tid = threadIdx.x;
    for (int s=tid; s<768; s+=256){
        int p = s>>6, k = s&63, g = p>>2, n = n0+(p&3);
        const int* cp = g==0?cnt3:(g==1?cnt5:cnt9);
        int rb = (g==0) ? 0 : (g==1 ? NN*3 : NN*8);
        int cnt = cp[n];
        int o = rb + offc[g*NN+n];
        float dv = dinvc[g*NN+n];
        float srow = dv*xw[n*64+k];
        for (int e=0;e<cnt;e++){
            int i = rev[o+e];
            srow += dinvc[g*NN+i]*xw[i*64+k];
        }
        float v = dv*srow + bg1[k];
        h1s[p][k] = v>0.f ? v : 0.f;
    }
    __syncthreads();
    int c = tid & 127, ph = tid>>7;
    float a6[6] = {0,0,0,0,0,0};
    for (int k=0;k<64;k++){
        float w = Wg2[k*128+c];
        #pragma unroll
        for (int q=0;q<6;q++) a6[q] += h1s[q*2+ph][k]*w;
    }
    #pragma unroll
    for (int q=0;q<6;q++){
        int p = q*2+ph, g = p>>2, n = n0+(p&3);
        float dv = dinvc[g*NN+n];
        y2[(size_t)g*NN*128 + (size_t)n*128 + c] = dv*a6[q];
    }
}

// ---------- phase 3c: gather layer-2 + bias + log_softmax ----------
__global__ __launch_bounds__(128) void k_fin(const float* __restrict__ y2,
        const int* __restrict__ offc,
        const int* __restrict__ cnt3, const int* __restrict__ cnt5, const int* __restrict__ cnt9,
        const int* __restrict__ rev, const float* __restrict__ dinvc,
        const float* __restrict__ bg2, float* __restrict__ emb){
    __shared__ float sm[2], ss[2];
    int b = blockIdx.x;
    int n = b & (NN-1), g = b >> 12;
    const int* cp = g==0?cnt3:(g==1?cnt5:cnt9);
    int rb = (g==0) ? 0 : (g==1 ? NN*3 : NN*8);
    int cnt = cp[n];
    int o = rb + offc[g*NN+n];
    float dv = dinvc[g*NN+n];
    int c = threadIdx.x;
    const float* yg = y2 + (size_t)g*NN*128;
    float s = yg[(size_t)n*128 + c];
    for (int e=0;e<cnt;e++){
        int i = rev[o+e];
        s += yg[(size_t)i*128 + c];
    }
    float v = dv*s + bg2[c];
    float m = v;
    #pragma unroll
    for (int st=1;st<64;st<<=1) m = fmaxf(m, __shfl_xor(m, st, 64));
    if ((c&63)==0) sm[c>>6] = m;
    __syncthreads();
    m = fmaxf(sm[0], sm[1]);
    float e = expf(v - m);
    float t = e;
    #pragma unroll
    for (int st=1;st<64;st<<=1) t += __shfl_xor(t, st, 64);
    if ((c&63)==0) ss[c>>6] = t;
    __syncthreads();
    t = ss[0]+ss[1];
    emb[n*384 + g*128 + c] = v - m - logf(t);
}

// ---------- phase 4: q/k projections ----------
__global__ __launch_bounds__(256) void k_qk(const float* __restrict__ emb,
        const float* __restrict__ Wq, const float* __restrict__ bq,
        const float* __restrict__ Wkey, const float* __restrict__ bkey,
        float* __restrict__ q, float* __restrict__ kbuf){
    __shared__ float es[8][384];
    int n0 = blockIdx.x*8;
    int tid = threadIdx.x;
    for (int idx=tid; idx<8*384; idx+=256){
        int m = idx/384, k = idx%384;
        es[m][k] = emb[(n0+m)*384+k];
    }
    __syncthreads();
    int c = tid & 127;
    int sel = tid >> 7;
    const float* W = sel ? Wkey : Wq;
    float b = sel ? bkey[c] : bq[c];
    float acc[8];
    #pragma unroll
    for (int m=0;m<8;m++) acc[m]=b;
    for (int k=0;k<384;k++){
        float w = W[k*128+c];
        #pragma unroll
        for (int m=0;m<8;m++) acc[m] += es[m][k]*w;
    }
    float* out = sel ? kbuf : q;
    #pragma unroll
    for (int m=0;m<8;m++) out[(n0+m)*128+c] = acc[m];
}

// ---------- phase 5: scores = q @ k^T + fused per-row max & min ----------
__global__ __launch_bounds__(256) void k_scores(const float* __restrict__ q,
        const float* __restrict__ kb, float* __restrict__ scores,
        unsigned* __restrict__ rowmaxenc, unsigned* __restrict__ rowminenc){
    __shared__ float at[32][132];
    __shared__ float bt[32][132];
    int bx = blockIdx.x & 31;
    int by = blockIdx.x >> 5;
    int r0 = by*128, c0 = bx*128;
    int tid = threadIdx.x;
    int tx = tid & 15, ty = tid >> 4;
    float acc[8][8] = {};
    for (int k0 = 0; k0 < 128; k0 += 32){
        __syncthreads();
        #pragma unroll
        for (int l=0; l<4; l++){
            int idx = tid + l*256;
            int rowi = idx >> 3;
            int kq  = (idx & 7) * 4;
            float4 a = *(const float4*)&q [(size_t)(r0+rowi)*128 + k0 + kq];
            float4 b = *(const float4*)&kb[(size_t)(c0+rowi)*128 + k0 + kq];
            at[kq+0][rowi]=a.x; at[kq+1][rowi]=a.y; at[kq+2][rowi]=a.z; at[kq+3][rowi]=a.w;
            bt[kq+0][rowi]=b.x; bt[kq+1][rowi]=b.y; bt[kq+2][rowi]=b.z; bt[kq+3][rowi]=b.w;
        }
        __syncthreads();
        #pragma unroll
        for (int k=0;k<32;k++){
            float4 a0 = *(const float4*)&at[k][ty*4];
            float4 a1 = *(const float4*)&at[k][64+ty*4];
            float4 b0 = *(const float4*)&bt[k][tx*4];
            float4 b1 = *(const float4*)&bt[k][64+tx*4];
            float av[8] = {a0.x,a0.y,a0.z,a0.w,a1.x,a1.y,a1.z,a1.w};
            float bv[8] = {b0.x,b0.y,b0.z,b0.w,b1.x,b1.y,b1.z,b1.w};
            #pragma unroll
            for (int u=0;u<8;u++){
                #pragma unroll
                for (int v=0;v<8;v++) acc[u][v] += av[u]*bv[v];
            }
        }
    }
    #pragma unroll
    for (int u=0;u<8;u++){
        int rr = r0 + ((u<4)? ty*4+u : 64+ty*4+(u-4));
        float4 s0 = {acc[u][0],acc[u][1],acc[u][2],acc[u][3]};
        float4 s1 = {acc[u][4],acc[u][5],acc[u][6],acc[u][7]};
        *(float4*)&scores[(size_t)rr*NN + c0 + tx*4] = s0;
        *(float4*)&scores[(size_t)rr*NN + c0 + 64 + tx*4] = s1;
        float m = acc[u][0], mn = acc[u][0];
        #pragma unroll
        for (int v=1;v<8;v++){ m = fmaxf(m, acc[u][v]); mn = fminf(mn, acc[u][v]); }
        #pragma unroll
        for (int s=1;s<16;s<<=1){
            m  = fmaxf(m,  __shfl_xor(m,  s, 64));
            mn = fminf(mn, __shfl_xor(mn, s, 64));
        }
        if (tx==0){
            atomicMax(&rowmaxenc[rr], enc_f(m));
            atomicMin(&rowminenc[rr], enc_f(mn));
        }
    }
}

// ---------- phase 5b: invr / im ----------
__global__ void k_invr(const unsigned* __restrict__ rowmaxenc, const float* __restrict__ maxd,
        float* __restrict__ invr, float* __restrict__ im){
    int i = blockIdx.x*256 + threadIdx.x;
    if (i >= NN) return;
    invr[i] = 1.f/dec_f(rowmaxenc[i]);
    im[i]   = 1.f/maxd[i];
}

// ---------- phase 6: streaming conv min/max over A ----------
// wave owns a 64-col strip; rows streamed with depth-9 register rings;
// column stencil via wave-synchronous VOLATILE LDS row buffer + wave_barrier
// (rule #18 class bug: without the fence the compiler reorders the provably
//  non-aliasing ds_read before other lanes' ds_write).
__global__ __launch_bounds__(256) void k_cstream(const float* __restrict__ scores,
        const float* __restrict__ invr,
        const float* __restrict__ Wcy3, const float* __restrict__ Wcx3,
        const float* __restrict__ Wcy5, const float* __restrict__ Wcx5,
        const float* __restrict__ Wcy9, const float* __restrict__ Wcx9,
        const float* __restrict__ bcy3, const float* __restrict__ bcx3,
        const float* __restrict__ bcy5, const float* __restrict__ bcx5,
        const float* __restrict__ bcy9, const float* __restrict__ bcx9,
        float* __restrict__ mnmx){
    __shared__ float rowbuf[4][80];
    __shared__ float smn[4], smx[4];
    int tid = threadIdx.x;
    int w = tid >> 6, lane = tid & 63;
    int jb = blockIdx.x*256 + w*64;
    int j  = jb + lane;
    int i0 = blockIdx.y*64;
    volatile float* rb = rowbuf[w];

    float wy3[3],wx3[3],wy5[5],wx5[5],wy9[9],wx9[9];
    #pragma unroll
    for (int t=0;t<3;t++){ wy3[t]=Wcy3[t]; wx3[t]=Wcx3[t]; }
    #pragma unroll
    for (int t=0;t<5;t++){ wy5[t]=Wcy5[t]; wx5[t]=Wcx5[t]; }
    #pragma unroll
    for (int t=0;t<9;t++){ wy9[t]=Wcy9[t]; wx9[t]=Wcx9[t]; }
    float bc3 = bcy3[0]+bcx3[0];
    float bc5 = bcy5[0]+bcx5[0];
    float bc9 = bcy9[0]+bcx9[0];

    float win[9], cy3r[9], cy5r[9], cy9r[9];
    float mn = INFINITY, mx = -INFINITY;

    bool haloL = (lane < 4);
    bool haloR = (lane >= 60);
    int jL = jb - 4 + lane;            // cols jb-4..jb-1
    int jR = jb + lane + 4;            // cols jb+64..jb+67
    bool vlL = haloL && (jL >= 0);
    bool vlR = haloR && (jR < NN);

    for (int tb = 0; tb < 8; ++tb){
        #pragma unroll
        for (int u = 0; u < 9; ++u){
            int t  = tb*9 + u;
            int ri = i0 - 4 + t;
            bool rv = ((unsigned)ri < NN);
            float iv = 0.f, v = 0.f, vL = 0.f, vR = 0.f;
            if (rv){
                iv = invr[ri];
                const float* rp = scores + (size_t)ri*NN;
                v = rp[j];
                if (vlL) vL = rp[jL];
                if (vlR) vR = rp[jR];
            }
            float a = v*iv;
            rb[lane+4] = a;
            if (haloL) rb[lane]   = vL*iv;
            if (haloR) rb[lane+8] = vR*iv;
            __builtin_amdgcn_wave_barrier();
            float tp[9];
            #pragma unroll
            for (int k=0;k<9;k++) tp[k] = rb[lane+k];
            __builtin_amdgcn_wave_barrier();
            float cy9v = ((tp[0]*wy9[0] + tp[1]*wy9[1]) + (tp[2]*wy9[2] + tp[3]*wy9[3]))
                       + ((tp[4]*wy9[4] + tp[5]*wy9[5]) + (tp[6]*wy9[6] + tp[7]*wy9[7]))
                       + tp[8]*wy9[8];
            float cy5v = ((tp[2]*wy5[0] + tp[3]*wy5[1]) + (tp[4]*wy5[2] + tp[5]*wy5[3]))
                       + tp[6]*wy5[4];
            float cy3v = (tp[3]*wy3[0] + tp[4]*wy3[1]) + tp[5]*wy3[2];
            win[u]  = a;
            cy3r[u] = cy3v; cy5r[u] = cy5v; cy9r[u] = cy9v;
            if (t >= 8){
                // output row ro = i0 + t - 8 ; row ro-4+k lives in slot (u+1+k)%9
                float cx9v = ((win[(u+1)%9]*wx9[0] + win[(u+2)%9]*wx9[1]) + (win[(u+3)%9]*wx9[2] + win[(u+4)%9]*wx9[3]))
                           + ((win[(u+5)%9]*wx9[4] + win[(u+6)%9]*wx9[5]) + (win[(u+7)%9]*wx9[6] + win[(u+8)%9]*wx9[7]))
                           + win[u]*wx9[8];
                float cx5v = ((win[(u+3)%9]*wx5[0] + win[(u+4)%9]*wx5[1]) + (win[(u+5)%9]*wx5[2] + win[(u+6)%9]*wx5[3]))
                           + win[(u+7)%9]*wx5[4];
                float cx3v = (win[(u+4)%9]*wx3[0] + win[(u+5)%9]*wx3[1]) + win[(u+6)%9]*wx3[2];
                float c9 = cy9r[(u+5)%9] + cx9v + bc9;
                float c5 = cy5r[(u+5)%9] + cx5v + bc5;
                float c3 = cy3r[(u+5)%9] + cx3v + bc3;
                mn = fminf(mn, fminf(fminf(c3,c5),c9));
                mx = fmaxf(mx, fmaxf(fmaxf(c3,c5),c9));
            }
        }
    }
    #pragma unroll
    for (int m=1; m<64; m<<=1){
        mn = fminf(mn, __shfl_xor(mn, m, 64));
        mx = fmaxf(mx, __shfl_xor(mx, m, 64));
    }
    if (lane == 0){ smn[w] = mn; smx[w] = mx; }
    __syncthreads();
    if (tid == 0){
        float a0 = fminf(fminf(smn[0],smn[1]), fminf(smn[2],smn[3]));
        float b0 = fmaxf(fmaxf(smx[0],smx[1]), fmaxf(smx[2],smx[3]));
        int bid = blockIdx.y*16 + blockIdx.x;
        mnmx[bid] = a0;
        mnmx[1024 + bid] = b0;
    }
}

// ---------- phase 6b: row dots: ASdot = A@Ot, B = everything row-local ----------
__global__ __launch_bounds__(256) void k_rowdot(const float* __restrict__ scores,
        const float* __restrict__ x0, const float* __restrict__ Ty,
        const float* __restrict__ invr, const float* __restrict__ im,
        const float* __restrict__ dOt, const float* __restrict__ colsum,
        const float* __restrict__ bcy3, const float* __restrict__ bcx3,
        const float* __restrict__ bcy5, const float* __restrict__ bcx5,
        const float* __restrict__ bcy9, const float* __restrict__ bcx9,
        float* __restrict__ ASdot, float* __restrict__ Bv){
    int tid = threadIdx.x;
    int tc = tid & 31, tr = tid >> 5;
    int i = blockIdx.x*8 + tr;
    const float* srow = scores + (size_t)i*NN;
    float4 ss = {0,0,0,0}, st = {0,0,0,0};
    for (int c0 = tc; c0 < NN; c0 += 32){
        float sv = srow[c0];
        float4 ot = *(const float4*)&x0[c0*8+4];
        float4 ty = *(const float4*)&Ty[c0*4];
        ss.x += sv*ot.x; ss.y += sv*ot.y; ss.z += sv*ot.z; ss.w += sv*ot.w;
        st.x += sv*ty.x; st.y += sv*ty.y; st.z += sv*ty.z; st.w += sv*ty.w;
    }
    #pragma unroll
    for (int s=1; s<32; s<<=1){
        ss.x += __shfl_xor(ss.x, s, 64); ss.y += __shfl_xor(ss.y, s, 64);
        ss.z += __shfl_xor(ss.z, s, 64); ss.w += __shfl_xor(ss.w, s, 64);
        st.x += __shfl_xor(st.x, s, 64); st.y += __shfl_xor(st.y, s, 64);
        st.z += __shfl_xor(st.z, s, 64); st.w += __shfl_xor(st.w, s, 64);
    }
    if (tc == 0){
        float iv = invr[i], imv = im[i];
        float bcsum = bcy3[0]+bcx3[0]+bcy5[0]+bcx5[0]+bcy9[0]+bcx9[0];
        float4 cs = *(const float4*)colsum;
        float4 dv = *(const float4*)&dOt[i*4];
        float4 as;
        as.x = iv*ss.x; as.y = iv*ss.y; as.z = iv*ss.z; as.w = iv*ss.w;
        float k = 1.f + bcsum;
        float4 b;
        b.x = cs.x*k - imv*dv.x + iv*st.x;
        b.y = cs.y*k - imv*dv.y + iv*st.y;
        b.z = cs.z*k - imv*dv.z + iv*st.z;
        b.w = cs.w*k - imv*dv.w + iv*st.w;
        *(float4*)&ASdot[i*4] = as;
        *(float4*)&Bv[i*4]   = b;
    }
}

// ---------- phase 6c: global min/max = conv blocks U A-range U {0,1} ----------
__global__ __launch_bounds__(256) void k_gmm(const float* __restrict__ mnmx,
        const unsigned* __restrict__ rowminenc, const unsigned* __restrict__ rowmaxenc,
        float* __restrict__ gmm){
    __shared__ float smn[256], smx[256];
    int tid = threadIdx.x;
    float mn = 0.f, mx = 1.f;   // oushi range is exactly [0,1]
    for (int i=tid; i<NN; i+=256){
        float rmx = dec_f(rowmaxenc[i]);
        float q = dec_f(rowminenc[i]) / rmx;
        mn = fminf(mn, fminf(1.f, q));
        mx = fmaxf(mx, fmaxf(1.f, q));
    }
    for (int b=tid; b<1024; b+=256){
        mn = fminf(mn, mnmx[b]);
        mx = fmaxf(mx, mnmx[1024+b]);
    }
    smn[tid]=mn; smx[tid]=mx; __syncthreads();
    for (int s=128;s>0;s>>=1){
        if (tid<s){ smn[tid]=fminf(smn[tid],smn[tid+s]); smx[tid]=fmaxf(smx[tid],smx[tid+s]); }
        __syncthreads();
    }
    if (tid==0){ gmm[0]=smn[0]; gmm[1]=smx[0]; }
}

// ---------- phase 7a: row-conv of ASdot + affine -> hfin ----------
__global__ void k_hfin(const float* __restrict__ ASdot, const float* __restrict__ Bv,
        const float* __restrict__ Wcx3, const float* __restrict__ Wcx5, const float* __restrict__ Wcx9,
        const float* __restrict__ gmm, const float* __restrict__ colsum,
        float* __restrict__ hfin){
    int i = blockIdx.x*256 + threadIdx.x;
    if (i >= NN) return;
    float Cx[9];
    #pragma unroll
    for (int o=-4;o<=4;o++){
        float c = Wcx9[o+4];
        if (o>=-2 && o<=2) c += Wcx5[o+2];
        if (o>=-1 && o<=1) c += Wcx3[o+1];
        Cx[o+4] = c;
    }
    float4 h = *(const float4*)&Bv[i*4];
    float4 a0 = *(const float4*)&ASdot[i*4];
    h.x += a0.x; h.y += a0.y; h.z += a0.z; h.w += a0.w;
    #pragma unroll
    for (int o=-4;o<=4;o++){
        int r = i + o;
        if ((unsigned)r < NN){
            float4 av = *(const float4*)&ASdot[r*4];
            float c = Cx[o+4];
            h.x += c*av.x; h.y += c*av.y; h.z += c*av.z; h.w += c*av.w;
        }
    }
    float mnv = gmm[0], mxv = gmm[1];
    float s = 1.f/(mxv-mnv), oa = -mnv*s;
    float4 cs = *(const float4*)colsum;
    float4 out;
    out.x = s*h.x + 5.f*oa*cs.x;
    out.y = s*h.y + 5.f*oa*cs.y;
    out.z = s*h.z + 5.f*oa*cs.z;
    out.w = s*h.w + 5.f*oa*cs.w;
    *(float4*)&hfin[i*4] = out;
}

// ---------- phase 7b: MLP head ----------
__global__ __launch_bounds__(256) void k_mlp(const float* __restrict__ hfin,
        const float* __restrict__ Woff, const float* __restrict__ boff, const float* __restrict__ pw,
        const float* __restrict__ Wf1, const float* __restrict__ bf1,
        const float* __restrict__ Wf2, const float* __restrict__ bf2,
        const float* __restrict__ Wf3, const float* __restrict__ bf3,
        float* __restrict__ out){
    __shared__ float h1[8][128];
    __shared__ float h2[8][256];
    __shared__ float h3[8][256];
    __shared__ float4 red4[256];
    int n0 = blockIdx.x*8, tid = threadIdx.x;
    float p = pw[0];
    {
        int c = tid & 127, mb = (tid>>7)*4;
        #pragma unroll
        for (int mm=0; mm<4; mm++){
            int m = mb+mm;
            float v = boff[c];
            #pragma unroll
            for (int k=0;k<4;k++) v += hfin[(n0+m)*4+k]*Woff[k*128+c];
            h1[m][c] = v>0.f ? v : p*v;
        }
    }
    __syncthreads();
    {
        int c = tid;
        float acc[8];
        #pragma unroll
        for (int m=0;m<8;m++) acc[m] = bf1[c];
        for (int k=0;k<128;k++){
            float w = Wf1[k*256+c];
            #pragma unroll
            for (int m=0;m<8;m++) acc[m] += h1[m][k]*w;
        }
        #pragma unroll
        for (int m=0;m<8;m++) h2[m][c] = acc[m]>0.f?acc[m]:0.f;
    }
    __syncthreads();
    {
        int c = tid;
        float acc[8];
        #pragma unroll
        for (int m=0;m<8;m++) acc[m] = bf2[c];
        for (int k=0;k<256;k++){
            float w = Wf2[k*256+c];
            #pragma unroll
            for (int m=0;m<8;m++) acc[m] += h2[m][k]*w;
        }
        #pragma unroll
        for (int m=0;m<8;m++) h3[m][c] = acc[m]>0.f?acc[m]:0.f;
    }
    __syncthreads();
    float w3_0 = Wf3[tid*4+0], w3_1 = Wf3[tid*4+1], w3_2 = Wf3[tid*4+2], w3_3 = Wf3[tid*4+3];
    for (int m=0;m<8;m++){
        float hv = h3[m][tid];
        float4 r; r.x = hv*w3_0; r.y = hv*w3_1; r.z = hv*w3_2; r.w = hv*w3_3;
        red4[tid]=r; __syncthreads();
        for (int s=128;s>0;s>>=1){
            if(tid<s){
                red4[tid].x+=red4[tid+s].x; red4[tid].y+=red4[tid+s].y;
                red4[tid].z+=red4[tid+s].z; red4[tid].w+=red4[tid+s].w;
            }
            __syncthreads();
        }
        if (tid==0){
            float4 o;
            o.x = red4[0].x + bf3[0]; o.y = red4[0].y + bf3[1];
            o.z = red4[0].z + bf3[2]; o.w = red4[0].w + bf3[3];
            *(float4*)&out[(n0+m)*4] = o;
        }
        __syncthreads();
    }
}

// ---------- host ----------
extern "C" void kernel_launch(void* const* d_in, const int* in_sizes, int n_in,
                              void* d_out, int out_size, void* d_ws, size_t ws_size,
                              hipStream_t stream){
    const float* dx1  = (const float*)d_in[0];
    const float* dx2  = (const float*)d_in[1];
    const float* Wk   = (const float*)d_in[2];
    const float* bk   = (const float*)d_in[3];
    const float* Wg1  = (const float*)d_in[4];
    const float* bg1  = (const float*)d_in[5];
    const float* Wg2  = (const float*)d_in[6];
    const float* bg2  = (const float*)d_in[7];
    const float* Wq   = (const float*)d_in[8];
    const float* bq   = (const float*)d_in[9];
    const float* Wkey = (const float*)d_in[10];
    const float* bkey = (const float*)d_in[11];
    const float* Woff = (const float*)d_in[12];
    const float* boff = (const float*)d_in[13];
    const float* pw   = (const float*)d_in[14];
    const float* Wf1  = (const float*)d_in[15];
    const float* bf1  = (const float*)d_in[16];
    const float* Wf2  = (const float*)d_in[17];
    const float* bf2  = (const float*)d_in[18];
    const float* Wf3  = (const float*)d_in[19];
    const float* bf3  = (const float*)d_in[20];
    const float* Wcy3 = (const float*)d_in[21];
    const float* bcy3 = (const float*)d_in[22];
    const float* Wcx3 = (const float*)d_in[23];
    const float* bcx3 = (const float*)d_in[24];
    const float* Wcy5 = (const float*)d_in[25];
    const float* bcy5 = (const float*)d_in[26];
    const float* Wcx5 = (const float*)d_in[27];
    const float* bcx5 = (const float*)d_in[28];
    const float* Wcy9 = (const float*)d_in[29];
    const float* bcy9 = (const float*)d_in[30];
    const float* Wcx9 = (const float*)d_in[31];
    const float* bcx9 = (const float*)d_in[32];

    char* ws = (char*)d_ws;
    size_t off = 0;
    auto alloc = [&](size_t b)->void*{ void* p = ws + off; off += (b + 255) & ~(size_t)255; return p; };

    // --- zero-init region (one small memset) ---
    char* zbase = ws + off;
    float*    colsum    = (float*)   alloc(4*4);
    int*      cnt3      = (int*)     alloc((size_t)NN*4);
    int*      cnt5      = (int*)     alloc((size_t)NN*4);
    int*      cnt9      = (int*)     alloc((size_t)NN*4);
    int*      cur       = (int*)     alloc((size_t)3*NN*4);
    unsigned* rowmaxenc = (unsigned*)alloc((size_t)NN*4);
    size_t zbytes = (size_t)((ws + off) - zbase);
    unsigned* rowminenc = (unsigned*)alloc((size_t)NN*4);   // memset 0xFF

    // --- non-zeroed ---
    float* x0     = (float*)alloc((size_t)NN*8*4);
    float* maxd   = (float*)alloc((size_t)NN*4);
    int*   nbr    = (int*)  alloc((size_t)NN*9*4);
    int*   offc   = (int*)  alloc((size_t)3*NN*4);
    float* dinvc  = (float*)alloc((size_t)3*NN*4);
    int*   rev    = (int*)  alloc((size_t)NN*17*4);
    float* xw     = (float*)alloc((size_t)NN*64*4);
    float* y2     = (float*)alloc((size_t)3*NN*128*4);
    float* emb    = (float*)alloc((size_t)NN*384*4);
    float* qb     = (float*)alloc((size_t)NN*128*4);
    float* kb     = (float*)alloc((size_t)NN*128*4);
    float* scores = (float*)alloc((size_t)NN*NN*4);
    float* Tyb    = (float*)alloc((size_t)NN*4*4);
    float* invr   = (float*)alloc((size_t)NN*4);
    float* im     = (float*)alloc((size_t)NN*4);
    float* dOt    = (float*)alloc((size_t)NN*4*4);
    float* ASd    = (float*)alloc((size_t)NN*4*4);
    float* Bv     = (float*)alloc((size_t)NN*4*4);
    float* mnmx   = (float*)alloc((size_t)2*1024*4);
    float* gmm    = (float*)alloc(2*4);
    float* hfin   = (float*)alloc((size_t)NN*4*4);
    (void)ws_size; (void)in_sizes; (void)n_in; (void)out_size;

    hipMemsetAsync(zbase, 0, zbytes, stream);
    hipMemsetAsync(rowminenc, 0xFF, (size_t)NN*4, stream);

    k_prep<<<16,256,0,stream>>>(dx1,dx2,Wk,bk,x0,colsum);
    k_ty  <<<16,256,0,stream>>>(x0,Wcy3,Wcy5,Wcy9,Tyb);
    k_dist<<<NN/4,256,0,stream>>>(dx1,x0,maxd,nbr,cnt3,cnt5,cnt9,dOt);
    k_scan<<<1,256,0,stream>>>(cnt3,cnt5,cnt9,offc,dinvc);
    k_fill<<<16,256,0,stream>>>(nbr,offc,cur,rev);

    k_y1  <<<NN*64/256,256,0,stream>>>(x0,Wg1,xw);
    k_h1y2<<<NN/4,256,0,stream>>>(xw,offc,cnt3,cnt5,cnt9,rev,dinvc,bg1,Wg2,y2);
    k_fin <<<NN*3,128,0,stream>>>(y2,offc,cnt3,cnt5,cnt9,rev,dinvc,bg2,emb);

    k_qk<<<NN/8,256,0,stream>>>(emb,Wq,bq,Wkey,bkey,qb,kb);
    k_scores<<<1024,256,0,stream>>>(qb,kb,scores,rowmaxenc,rowminenc);
    k_invr<<<16,256,0,stream>>>(rowmaxenc,maxd,invr,im);

    k_cstream<<<dim3(16,64),256,0,stream>>>(scores,invr,
        Wcy3,Wcx3,Wcy5,Wcx5,Wcy9,Wcx9,
        bcy3,bcx3,bcy5,bcx5,bcy9,bcx9, mnmx);
    k_rowdot<<<NN/8,256,0,stream>>>(scores,x0,Tyb,invr,im,dOt,colsum,
        bcy3,bcx3,bcy5,bcx5,bcy9,bcx9, ASd, Bv);
    k_gmm<<<1,256,0,stream>>>(mnmx,rowminenc,rowmaxenc,gmm);
    k_hfin<<<16,256,0,stream>>>(ASd,Bv,Wcx3,Wcx5,Wcx9,gmm,colsum,hfin);
    k_mlp<<<NN/8,256,0,stream>>>(hfin,Woff,boff,pw,Wf1,bf1,Wf2,bf2,Wf3,bf3,(float*)d_out);
}

// Round 8
// 353.178 us; speedup vs baseline: 1.1530x; 1.1530x over previous
//
#include <hip/hip_runtime.h>
#include <math.h>

#define NN 4096

static __device__ __forceinline__ unsigned enc_f(float f){
    unsigned u = __float_as_uint(f);
    return (u & 0x80000000u) ? ~u : (u | 0x80000000u);
}
static __device__ __forceinline__ float dec_f(unsigned u){
    unsigned b = (u & 0x80000000u) ? (u & 0x7fffffffu) : ~u;
    return __uint_as_float(b);
}

// ---------- phase 1: x0 assembly + Ot column sums ----------
__global__ void k_prep(const float* __restrict__ dx1, const float* __restrict__ dx2,
                       const float* __restrict__ Wk, const float* __restrict__ bk,
                       float* __restrict__ x0, float* __restrict__ colsum){
    int n = blockIdx.x*blockDim.x + threadIdx.x;
    if (n >= NN) return;
    float wk[8];
    #pragma unroll
    for (int j=0;j<8;j++) wk[j] = Wk[j];
    float bkv = bk[0];
    #pragma unroll
    for (int c=0;c<4;c++) x0[n*8+c] = dx1[n*4+c];
    #pragma unroll
    for (int c=0;c<4;c++){
        float acc = bkv;
        #pragma unroll
        for (int j=0;j<8;j++) acc += dx2[(n*8+j)*4+c]*wk[j];
        x0[n*8+4+c] = acc;
        atomicAdd(&colsum[c], acc);
    }
}

// ---------- phase 1b: Ty[j] = sum over valid output pos of Cy * Ot ----------
__global__ void k_ty(const float* __restrict__ x0,
        const float* __restrict__ Wcy3, const float* __restrict__ Wcy5, const float* __restrict__ Wcy9,
        float* __restrict__ Ty){
    int j = blockIdx.x*256 + threadIdx.x;
    if (j >= NN) return;
    float Cy[9];
    #pragma unroll
    for (int o=-4;o<=4;o++){
        float c = Wcy9[o+4];
        if (o>=-2 && o<=2) c += Wcy5[o+2];
        if (o>=-1 && o<=1) c += Wcy3[o+1];
        Cy[o+4] = c;
    }
    float4 acc = {0,0,0,0};
    #pragma unroll
    for (int o=-4;o<=4;o++){
        int jj = j - o;
        if ((unsigned)jj < NN){
            float4 ot = *(const float4*)&x0[jj*8+4];
            float c = Cy[o+4];
            acc.x += c*ot.x; acc.y += c*ot.y; acc.z += c*ot.z; acc.w += c*ot.w;
        }
    }
    *(float4*)&Ty[j*4] = acc;
}

// ---------- phase 2: row max dist + top-9 knn + in-deg counts + dOt ----------
__global__ __launch_bounds__(256) void k_dist(const float* __restrict__ dx1,
        const float* __restrict__ x0,
        float* __restrict__ maxd, int* __restrict__ nbr,
        int* __restrict__ cnt3, int* __restrict__ cnt5, int* __restrict__ cnt9,
        float* __restrict__ dOt){
    __shared__ float2 ps[NN];
    int tid = threadIdx.x;
    for (int j=tid; j<NN; j+=256){
        float4 v = *(const float4*)&dx1[j*4];
        ps[j] = make_float2(v.x, v.y);
    }
    __syncthreads();
    int lane = tid & 63;
    int i = blockIdx.x*4 + (tid>>6);
    float2 pi = ps[i];
    unsigned long long best[9];
    #pragma unroll
    for (int q=0;q<9;q++) best[q] = ~0ULL;
    float lmax = 0.f;
    float4 dacc = {0,0,0,0};
    for (int t=0;t<64;t++){
        int j = (t<<6) | lane;
        float2 p = ps[j];
        float dx = pi.x - p.x, dy = pi.y - p.y;
        float d = sqrtf(dx*dx + dy*dy);
        lmax = fmaxf(lmax, d);
        float4 otj = *(const float4*)&x0[j*8+4];
        dacc.x += d*otj.x; dacc.y += d*otj.y; dacc.z += d*otj.z; dacc.w += d*otj.w;
        unsigned long long cand = ((unsigned long long)__float_as_uint(d) << 32) | (unsigned)j;
        if (j != i && cand < best[8]){
            best[8] = cand;
            #pragma unroll
            for (int q=8; q>0; --q){
                if (best[q] < best[q-1]){ unsigned long long tm=best[q]; best[q]=best[q-1]; best[q-1]=tm; }
            }
        }
    }
    #pragma unroll
    for (int m=1;m<64;m<<=1){
        lmax = fmaxf(lmax, __shfl_xor(lmax, m, 64));
        dacc.x += __shfl_xor(dacc.x, m, 64);
        dacc.y += __shfl_xor(dacc.y, m, 64);
        dacc.z += __shfl_xor(dacc.z, m, 64);
        dacc.w += __shfl_xor(dacc.w, m, 64);
    }
    if (lane==0){
        maxd[i] = lmax;
        *(float4*)&dOt[i*4] = dacc;
    }
    for (int t=0;t<9;t++){
        unsigned long long w = best[0];
        #pragma unroll
        for (int m=1;m<64;m<<=1){
            unsigned long long o = __shfl_xor(w, m, 64);
            if (o < w) w = o;
        }
        if (best[0] == w){
            #pragma unroll
            for (int q=0;q<8;q++) best[q] = best[q+1];
            best[8] = ~0ULL;
        }
        if (lane==0){
            int j = (int)(w & 0xffffffffu);
            nbr[i*9+t] = j;
            atomicAdd(&cnt9[j], 1);
            if (t<5) atomicAdd(&cnt5[j], 1);
            if (t<3) atomicAdd(&cnt3[j], 1);
        }
    }
}

// ---------- phase 2b: CSR offsets (exclusive scan) + dinv ----------
__global__ __launch_bounds__(256) void k_scan(const int* __restrict__ cnt3,
        const int* __restrict__ cnt5, const int* __restrict__ cnt9,
        int* __restrict__ offc, float* __restrict__ dinvc){
    __shared__ int part[256];
    int tid = threadIdx.x;
    for (int g=0; g<3; g++){
        const int* cp = g==0?cnt3:(g==1?cnt5:cnt9);
        int base = tid*16;
        int loc[16]; int s=0;
        #pragma unroll
        for (int q=0;q<16;q++){ loc[q]=s; s += cp[base+q]; }
        part[tid]=s; __syncthreads();
        for (int d=1; d<256; d<<=1){
            int v = (tid>=d) ? part[tid-d] : 0;
            __syncthreads();
            part[tid] += v;
            __syncthreads();
        }
        int pre = (tid==0) ? 0 : part[tid-1];
        #pragma unroll
        for (int q=0;q<16;q++){
            offc[g*NN + base + q]  = pre + loc[q];
            dinvc[g*NN + base + q] = rsqrtf((float)cp[base+q] + 1.f);
        }
        __syncthreads();
    }
}

// ---------- phase 2c: fill reverse-edge lists ----------
__global__ void k_fill(const int* __restrict__ nbr, const int* __restrict__ offc,
        int* __restrict__ cur, int* __restrict__ rev){
    int i = blockIdx.x*256 + threadIdx.x;
    if (i >= NN) return;
    #pragma unroll
    for (int t=0;t<9;t++){
        int j = nbr[i*9+t];
        int gmin = t<3 ? 0 : (t<5 ? 1 : 2);
        for (int g=gmin; g<3; g++){
            int pos = atomicAdd(&cur[g*NN+j], 1);
            int rb = (g==0) ? 0 : (g==1 ? NN*3 : NN*8);
            rev[rb + offc[g*NN+j] + pos] = i;
        }
    }
}

// ---------- phase 3: GCN layer-1 input transform ----------
__global__ void k_y1(const float* __restrict__ x0, const float* __restrict__ Wg1,
                     float* __restrict__ xw){
    int idx = blockIdx.x*256 + threadIdx.x;
    if (idx >= NN*64) return;
    int n = idx>>6, c = idx&63;
    float acc = 0.f;
    #pragma unroll
    for (int k=0;k<8;k++) acc += x0[n*8+k]*Wg1[k*64+c];
    xw[idx] = acc;
}

// ---------- phase 3b: gather layer-1 + relu + layer-2 matmul ----------
__global__ __launch_bounds__(256) void k_h1y2(const float* __restrict__ xw,
        const int* __restrict__ offc,
        const int* __restrict__ cnt3, const int* __restrict__ cnt5, const int* __restrict__ cnt9,
        const int* __restrict__ rev, const float* __restrict__ dinvc,
        const float* __restrict__ bg1, const float* __restrict__ Wg2,
        float* __restrict__ y2){
    __shared__ float h1s[12][64];
    int n0 = blockIdx.x*4, tid = threadIdx.x;
    for (int s=tid; s<768; s+=256){
        int p = s>>6, k = s&63, g = p>>2, n = n0+(p&3);
        const int* cp = g==0?cnt3:(g==1?cnt5:cnt9);
        int rb = (g==0) ? 0 : (g==1 ? NN*3 : NN*8);
        int cnt = cp[n];
        int o = rb + offc[g*NN+n];
        float dv = dinvc[g*NN+n];
        float srow = dv*xw[n*64+k];
        for (int e=0;e<cnt;e++){
            int i = rev[o+e];
            srow += dinvc[g*NN+i]*xw[i*64+k];
        }
        float v = dv*srow + bg1[k];
        h1s[p][k] = v>0.f ? v : 0.f;
    }
    __syncthreads();
    int c = tid & 127, ph = tid>>7;
    float a6[6] = {0,0,0,0,0,0};
    for (int k=0;k<64;k++){
        float w = Wg2[k*128+c];
        #pragma unroll
        for (int q=0;q<6;q++) a6[q] += h1s[q*2+ph][k]*w;
    }
    #pragma unroll
    for (int q=0;q<6;q++){
        int p = q*2+ph, g = p>>2, n = n0+(p&3);
        float dv = dinvc[g*NN+n];
        y2[(size_t)g*NN*128 + (size_t)n*128 + c] = dv*a6[q];
    }
}

// ---------- phase 3c: gather layer-2 + bias + log_softmax ----------
__global__ __launch_bounds__(128) void k_fin(const float* __restrict__ y2,
        const int* __restrict__ offc,
        const int* __restrict__ cnt3, const int* __restrict__ cnt5, const int* __restrict__ cnt9,
        const int* __restrict__ rev, const float* __restrict__ dinvc,
        const float* __restrict__ bg2, float* __restrict__ emb){
    __shared__ float sm[2], ss[2];
    int b = blockIdx.x;
    int n = b & (NN-1), g = b >> 12;
    const int* cp = g==0?cnt3:(g==1?cnt5:cnt9);
    int rb = (g==0) ? 0 : (g==1 ? NN*3 : NN*8);
    int cnt = cp[n];
    int o = rb + offc[g*NN+n];
    float dv = dinvc[g*NN+n];
    int c = threadIdx.x;
    const float* yg = y2 + (size_t)g*NN*128;
    float s = yg[(size_t)n*128 + c];
    for (int e=0;e<cnt;e++){
        int i = rev[o+e];
        s += yg[(size_t)i*128 + c];
    }
    float v = dv*s + bg2[c];
    float m = v;
    #pragma unroll
    for (int st=1;st<64;st<<=1) m = fmaxf(m, __shfl_xor(m, st, 64));
    if ((c&63)==0) sm[c>>6] = m;
    __syncthreads();
    m = fmaxf(sm[0], sm[1]);
    float e = expf(v - m);
    float t = e;
    #pragma unroll
    for (int st=1;st<64;st<<=1) t += __shfl_xor(t, st, 64);
    if ((c&63)==0) ss[c>>6] = t;
    __syncthreads();
    t = ss[0]+ss[1];
    emb[n*384 + g*128 + c] = v - m - logf(t);
}

// ---------- phase 4: q/k projections ----------
__global__ __launch_bounds__(256) void k_qk(const float* __restrict__ emb,
        const float* __restrict__ Wq, const float* __restrict__ bq,
        const float* __restrict__ Wkey, const float* __restrict__ bkey,
        float* __restrict__ q, float* __restrict__ kbuf){
    __shared__ float es[8][384];
    int n0 = blockIdx.x*8;
    int tid = threadIdx.x;
    for (int idx=tid; idx<8*384; idx+=256){
        int m = idx/384, k = idx%384;
        es[m][k] = emb[(n0+m)*384+k];
    }
    __syncthreads();
    int c = tid & 127;
    int sel = tid >> 7;
    const float* W = sel ? Wkey : Wq;
    float b = sel ? bkey[c] : bq[c];
    float acc[8];
    #pragma unroll
    for (int m=0;m<8;m++) acc[m]=b;
    for (int k=0;k<384;k++){
        float w = W[k*128+c];
        #pragma unroll
        for (int m=0;m<8;m++) acc[m] += es[m][k]*w;
    }
    float* out = sel ? kbuf : q;
    #pragma unroll
    for (int m=0;m<8;m++) out[(n0+m)*128+c] = acc[m];
}

// ---------- phase 5: scores = q @ k^T + fused per-row max & min ----------
__global__ __launch_bounds__(256) void k_scores(const float* __restrict__ q,
        const float* __restrict__ kb, float* __restrict__ scores,
        unsigned* __restrict__ rowmaxenc, unsigned* __restrict__ rowminenc){
    __shared__ float at[32][132];
    __shared__ float bt[32][132];
    int bx = blockIdx.x & 31;
    int by = blockIdx.x >> 5;
    int r0 = by*128, c0 = bx*128;
    int tid = threadIdx.x;
    int tx = tid & 15, ty = tid >> 4;
    float acc[8][8] = {};
    for (int k0 = 0; k0 < 128; k0 += 32){
        __syncthreads();
        #pragma unroll
        for (int l=0; l<4; l++){
            int idx = tid + l*256;
            int rowi = idx >> 3;
            int kq  = (idx & 7) * 4;
            float4 a = *(const float4*)&q [(size_t)(r0+rowi)*128 + k0 + kq];
            float4 b = *(const float4*)&kb[(size_t)(c0+rowi)*128 + k0 + kq];
            at[kq+0][rowi]=a.x; at[kq+1][rowi]=a.y; at[kq+2][rowi]=a.z; at[kq+3][rowi]=a.w;
            bt[kq+0][rowi]=b.x; bt[kq+1][rowi]=b.y; bt[kq+2][rowi]=b.z; bt[kq+3][rowi]=b.w;
        }
        __syncthreads();
        #pragma unroll
        for (int k=0;k<32;k++){
            float4 a0 = *(const float4*)&at[k][ty*4];
            float4 a1 = *(const float4*)&at[k][64+ty*4];
            float4 b0 = *(const float4*)&bt[k][tx*4];
            float4 b1 = *(const float4*)&bt[k][64+tx*4];
            float av[8] = {a0.x,a0.y,a0.z,a0.w,a1.x,a1.y,a1.z,a1.w};
            float bv[8] = {b0.x,b0.y,b0.z,b0.w,b1.x,b1.y,b1.z,b1.w};
            #pragma unroll
            for (int u=0;u<8;u++){
                #pragma unroll
                for (int v=0;v<8;v++) acc[u][v] += av[u]*bv[v];
            }
        }
    }
    #pragma unroll
    for (int u=0;u<8;u++){
        int rr = r0 + ((u<4)? ty*4+u : 64+ty*4+(u-4));
        float4 s0 = {acc[u][0],acc[u][1],acc[u][2],acc[u][3]};
        float4 s1 = {acc[u][4],acc[u][5],acc[u][6],acc[u][7]};
        *(float4*)&scores[(size_t)rr*NN + c0 + tx*4] = s0;
        *(float4*)&scores[(size_t)rr*NN + c0 + 64 + tx*4] = s1;
        float m = acc[u][0], mn = acc[u][0];
        #pragma unroll
        for (int v=1;v<8;v++){ m = fmaxf(m, acc[u][v]); mn = fminf(mn, acc[u][v]); }
        #pragma unroll
        for (int s=1;s<16;s<<=1){
            m  = fmaxf(m,  __shfl_xor(m,  s, 64));
            mn = fminf(mn, __shfl_xor(mn, s, 64));
        }
        if (tx==0){
            atomicMax(&rowmaxenc[rr], enc_f(m));
            atomicMin(&rowminenc[rr], enc_f(mn));
        }
    }
}

// ---------- phase 5b: invr / im ----------
__global__ void k_invr(const unsigned* __restrict__ rowmaxenc, const float* __restrict__ maxd,
        float* __restrict__ invr, float* __restrict__ im){
    int i = blockIdx.x*256 + threadIdx.x;
    if (i >= NN) return;
    invr[i] = 1.f/dec_f(rowmaxenc[i]);
    im[i]   = 1.f/maxd[i];
}

// ---------- phase 6: streaming conv min/max over A (shuffle column stencil) ----------
// Wave loads 64 cols, owns middle 56 as outputs (4-lane halo each side).
// Column stencil via __shfl (wave-synchronous, no LDS / volatile / fences),
// row stencil via depth-9 register rings. Compiler free to pipeline loads.
__global__ __launch_bounds__(256) void k_cstream(const float* __restrict__ scores,
        const float* __restrict__ invr,
        const float* __restrict__ Wcy3, const float* __restrict__ Wcx3,
        const float* __restrict__ Wcy5, const float* __restrict__ Wcx5,
        const float* __restrict__ Wcy9, const float* __restrict__ Wcx9,
        const float* __restrict__ bcy3, const float* __restrict__ bcx3,
        const float* __restrict__ bcy5, const float* __restrict__ bcx5,
        const float* __restrict__ bcy9, const float* __restrict__ bcx9,
        float* __restrict__ mnmx){
    __shared__ float smn[4], smx[4];
    int tid = threadIdx.x;
    int w = tid >> 6, lane = tid & 63;
    int strip = blockIdx.x*4 + w;
    int jj = strip*56 - 4 + lane;               // loaded col
    bool cvalid = (unsigned)jj < NN;
    bool outLane = (lane >= 4) && (lane < 60) && cvalid;
    int i0 = blockIdx.y*64;

    float wy3[3],wx3[3],wy5[5],wx5[5],wy9[9],wx9[9];
    #pragma unroll
    for (int t=0;t<3;t++){ wy3[t]=Wcy3[t]; wx3[t]=Wcx3[t]; }
    #pragma unroll
    for (int t=0;t<5;t++){ wy5[t]=Wcy5[t]; wx5[t]=Wcx5[t]; }
    #pragma unroll
    for (int t=0;t<9;t++){ wy9[t]=Wcy9[t]; wx9[t]=Wcx9[t]; }
    float bc3 = bcy3[0]+bcx3[0];
    float bc5 = bcy5[0]+bcx5[0];
    float bc9 = bcy9[0]+bcx9[0];

    float win[9], cy3r[9], cy5r[9], cy9r[9];
    float mn = INFINITY, mx = -INFINITY;

    for (int tb = 0; tb < 8; ++tb){
        #pragma unroll
        for (int u = 0; u < 9; ++u){
            int t  = tb*9 + u;
            int ri = i0 - 4 + t;
            float a = 0.f;
            if (((unsigned)ri < NN) && cvalid)
                a = scores[(size_t)ri*NN + jj] * invr[ri];
            float tp[9];
            #pragma unroll
            for (int k=0;k<9;k++) tp[k] = (k==4) ? a : __shfl(a, lane + k - 4, 64);
            float cy9v = ((tp[0]*wy9[0] + tp[1]*wy9[1]) + (tp[2]*wy9[2] + tp[3]*wy9[3]))
                       + ((tp[4]*wy9[4] + tp[5]*wy9[5]) + (tp[6]*wy9[6] + tp[7]*wy9[7]))
                       + tp[8]*wy9[8];
            float cy5v = ((tp[2]*wy5[0] + tp[3]*wy5[1]) + (tp[4]*wy5[2] + tp[5]*wy5[3]))
                       + tp[6]*wy5[4];
            float cy3v = (tp[3]*wy3[0] + tp[4]*wy3[1]) + tp[5]*wy3[2];
            win[u]  = a;
            cy3r[u] = cy3v; cy5r[u] = cy5v; cy9r[u] = cy9v;
            if (t >= 8 && outLane){
                // output row ro = i0 + t - 8 ; row ro-4+k lives in slot (u+1+k)%9
                float cx9v = ((win[(u+1)%9]*wx9[0] + win[(u+2)%9]*wx9[1]) + (win[(u+3)%9]*wx9[2] + win[(u+4)%9]*wx9[3]))
                           + ((win[(u+5)%9]*wx9[4] + win[(u+6)%9]*wx9[5]) + (win[(u+7)%9]*wx9[6] + win[(u+8)%9]*wx9[7]))
                           + win[u]*wx9[8];
                float cx5v = ((win[(u+3)%9]*wx5[0] + win[(u+4)%9]*wx5[1]) + (win[(u+5)%9]*wx5[2] + win[(u+6)%9]*wx5[3]))
                           + win[(u+7)%9]*wx5[4];
                float cx3v = (win[(u+4)%9]*wx3[0] + win[(u+5)%9]*wx3[1]) + win[(u+6)%9]*wx3[2];
                float c9 = cy9r[(u+5)%9] + cx9v + bc9;
                float c5 = cy5r[(u+5)%9] + cx5v + bc5;
                float c3 = cy3r[(u+5)%9] + cx3v + bc3;
                mn = fminf(mn, fminf(fminf(c3,c5),c9));
                mx = fmaxf(mx, fmaxf(fmaxf(c3,c5),c9));
            }
        }
    }
    #pragma unroll
    for (int m=1; m<64; m<<=1){
        mn = fminf(mn, __shfl_xor(mn, m, 64));
        mx = fmaxf(mx, __shfl_xor(mx, m, 64));
    }
    if (lane == 0){ smn[w] = mn; smx[w] = mx; }
    __syncthreads();
    if (tid == 0){
        float a0 = fminf(fminf(smn[0],smn[1]), fminf(smn[2],smn[3]));
        float b0 = fmaxf(fmaxf(smx[0],smx[1]), fmaxf(smx[2],smx[3]));
        int bid = blockIdx.y*gridDim.x + blockIdx.x;
        mnmx[bid] = a0;
        mnmx[1216 + bid] = b0;
    }
}

// ---------- phase 6b: row dots: ASdot = A@Ot, B = everything row-local ----------
__global__ __launch_bounds__(256) void k_rowdot(const float* __restrict__ scores,
        const float* __restrict__ x0, const float* __restrict__ Ty,
        const float* __restrict__ invr, const float* __restrict__ im,
        const float* __restrict__ dOt, const float* __restrict__ colsum,
        const float* __restrict__ bcy3, const float* __restrict__ bcx3,
        const float* __restrict__ bcy5, const float* __restrict__ bcx5,
        const float* __restrict__ bcy9, const float* __restrict__ bcx9,
        float* __restrict__ ASdot, float* __restrict__ Bv){
    int tid = threadIdx.x;
    int tc = tid & 31, tr = tid >> 5;
    int i = blockIdx.x*8 + tr;
    const float* srow = scores + (size_t)i*NN;
    float4 ss = {0,0,0,0}, st = {0,0,0,0};
    for (int c0 = tc; c0 < NN; c0 += 32){
        float sv = srow[c0];
        float4 ot = *(const float4*)&x0[c0*8+4];
        float4 ty = *(const float4*)&Ty[c0*4];
        ss.x += sv*ot.x; ss.y += sv*ot.y; ss.z += sv*ot.z; ss.w += sv*ot.w;
        st.x += sv*ty.x; st.y += sv*ty.y; st.z += sv*ty.z; st.w += sv*ty.w;
    }
    #pragma unroll
    for (int s=1; s<32; s<<=1){
        ss.x += __shfl_xor(ss.x, s, 64); ss.y += __shfl_xor(ss.y, s, 64);
        ss.z += __shfl_xor(ss.z, s, 64); ss.w += __shfl_xor(ss.w, s, 64);
        st.x += __shfl_xor(st.x, s, 64); st.y += __shfl_xor(st.y, s, 64);
        st.z += __shfl_xor(st.z, s, 64); st.w += __shfl_xor(st.w, s, 64);
    }
    if (tc == 0){
        float iv = invr[i], imv = im[i];
        float bcsum = bcy3[0]+bcx3[0]+bcy5[0]+bcx5[0]+bcy9[0]+bcx9[0];
        float4 cs = *(const float4*)colsum;
        float4 dv = *(const float4*)&dOt[i*4];
        float4 as;
        as.x = iv*ss.x; as.y = iv*ss.y; as.z = iv*ss.z; as.w = iv*ss.w;
        float k = 1.f + bcsum;
        float4 b;
        b.x = cs.x*k - imv*dv.x + iv*st.x;
        b.y = cs.y*k - imv*dv.y + iv*st.y;
        b.z = cs.z*k - imv*dv.z + iv*st.z;
        b.w = cs.w*k - imv*dv.w + iv*st.w;
        *(float4*)&ASdot[i*4] = as;
        *(float4*)&Bv[i*4]   = b;
    }
}

// ---------- phase 6c: global min/max = conv blocks U A-range U {0,1} ----------
__global__ __launch_bounds__(256) void k_gmm(const float* __restrict__ mnmx,
        const unsigned* __restrict__ rowminenc, const unsigned* __restrict__ rowmaxenc,
        float* __restrict__ gmm){
    __shared__ float smn[256], smx[256];
    int tid = threadIdx.x;
    float mn = 0.f, mx = 1.f;   // oushi range is exactly [0,1]
    for (int i=tid; i<NN; i+=256){
        float rmx = dec_f(rowmaxenc[i]);
        float q = dec_f(rowminenc[i]) / rmx;
        mn = fminf(mn, fminf(1.f, q));
        mx = fmaxf(mx, fmaxf(1.f, q));
    }
    for (int b=tid; b<1216; b+=256){
        mn = fminf(mn, mnmx[b]);
        mx = fmaxf(mx, mnmx[1216+b]);
    }
    smn[tid]=mn; smx[tid]=mx; __syncthreads();
    for (int s=128;s>0;s>>=1){
        if (tid<s){ smn[tid]=fminf(smn[tid],smn[tid+s]); smx[tid]=fmaxf(smx[tid],smx[tid+s]); }
        __syncthreads();
    }
    if (tid==0){ gmm[0]=smn[0]; gmm[1]=smx[0]; }
}

// ---------- phase 7a: row-conv of ASdot + affine -> hfin ----------
__global__ void k_hfin(const float* __restrict__ ASdot, const float* __restrict__ Bv,
        const float* __restrict__ Wcx3, const float* __restrict__ Wcx5, const float* __restrict__ Wcx9,
        const float* __restrict__ gmm, const float* __restrict__ colsum,
        float* __restrict__ hfin){
    int i = blockIdx.x*256 + threadIdx.x;
    if (i >= NN) return;
    float Cx[9];
    #pragma unroll
    for (int o=-4;o<=4;o++){
        float c = Wcx9[o+4];
        if (o>=-2 && o<=2) c += Wcx5[o+2];
        if (o>=-1 && o<=1) c += Wcx3[o+1];
        Cx[o+4] = c;
    }
    float4 h = *(const float4*)&Bv[i*4];
    float4 a0 = *(const float4*)&ASdot[i*4];
    h.x += a0.x; h.y += a0.y; h.z += a0.z; h.w += a0.w;
    #pragma unroll
    for (int o=-4;o<=4;o++){
        int r = i + o;
        if ((unsigned)r < NN){
            float4 av = *(const float4*)&ASdot[r*4];
            float c = Cx[o+4];
            h.x += c*av.x; h.y += c*av.y; h.z += c*av.z; h.w += c*av.w;
        }
    }
    float mnv = gmm[0], mxv = gmm[1];
    float s = 1.f/(mxv-mnv), oa = -mnv*s;
    float4 cs = *(const float4*)colsum;
    float4 out;
    out.x = s*h.x + 5.f*oa*cs.x;
    out.y = s*h.y + 5.f*oa*cs.y;
    out.z = s*h.z + 5.f*oa*cs.z;
    out.w = s*h.w + 5.f*oa*cs.w;
    *(float4*)&hfin[i*4] = out;
}

// ---------- phase 7b: MLP head ----------
__global__ __launch_bounds__(256) void k_mlp(const float* __restrict__ hfin,
        const float* __restrict__ Woff, const float* __restrict__ boff, const float* __restrict__ pw,
        const float* __restrict__ Wf1, const float* __restrict__ bf1,
        const float* __restrict__ Wf2, const float* __restrict__ bf2,
        const float* __restrict__ Wf3, const float* __restrict__ bf3,
        float* __restrict__ out){
    __shared__ float h1[8][128];
    __shared__ float h2[8][256];
    __shared__ float h3[8][256];
    __shared__ float4 red4[256];
    int n0 = blockIdx.x*8, tid = threadIdx.x;
    float p = pw[0];
    {
        int c = tid & 127, mb = (tid>>7)*4;
        #pragma unroll
        for (int mm=0; mm<4; mm++){
            int m = mb+mm;
            float v = boff[c];
            #pragma unroll
            for (int k=0;k<4;k++) v += hfin[(n0+m)*4+k]*Woff[k*128+c];
            h1[m][c] = v>0.f ? v : p*v;
        }
    }
    __syncthreads();
    {
        int c = tid;
        float acc[8];
        #pragma unroll
        for (int m=0;m<8;m++) acc[m] = bf1[c];
        for (int k=0;k<128;k++){
            float w = Wf1[k*256+c];
            #pragma unroll
            for (int m=0;m<8;m++) acc[m] += h1[m][k]*w;
        }
        #pragma unroll
        for (int m=0;m<8;m++) h2[m][c] = acc[m]>0.f?acc[m]:0.f;
    }
    __syncthreads();
    {
        int c = tid;
        float acc[8];
        #pragma unroll
        for (int m=0;m<8;m++) acc[m] = bf2[c];
        for (int k=0;k<256;k++){
            float w = Wf2[k*256+c];
            #pragma unroll
            for (int m=0;m<8;m++) acc[m] += h2[m][k]*w;
        }
        #pragma unroll
        for (int m=0;m<8;m++) h3[m][c] = acc[m]>0.f?acc[m]:0.f;
    }
    __syncthreads();
    float w3_0 = Wf3[tid*4+0], w3_1 = Wf3[tid*4+1], w3_2 = Wf3[tid*4+2], w3_3 = Wf3[tid*4+3];
    for (int m=0;m<8;m++){
        float hv = h3[m][tid];
        float4 r; r.x = hv*w3_0; r.y = hv*w3_1; r.z = hv*w3_2; r.w = hv*w3_3;
        red4[tid]=r; __syncthreads();
        for (int s=128;s>0;s>>=1){
            if(tid<s){
                red4[tid].x+=red4[tid+s].x; red4[tid].y+=red4[tid+s].y;
                red4[tid].z+=red4[tid+s].z; red4[tid].w+=red4[tid+s].w;
            }
            __syncthreads();
        }
        if (tid==0){
            float4 o;
            o.x = red4[0].x + bf3[0]; o.y = red4[0].y + bf3[1];
            o.z = red4[0].z + bf3[2]; o.w = red4[0].w + bf3[3];
            *(float4*)&out[(n0+m)*4] = o;
        }
        __syncthreads();
    }
}

// ---------- host ----------
extern "C" void kernel_launch(void* const* d_in, const int* in_sizes, int n_in,
                              void* d_out, int out_size, void* d_ws, size_t ws_size,
                              hipStream_t stream){
    const float* dx1  = (const float*)d_in[0];
    const float* dx2  = (const float*)d_in[1];
    const float* Wk   = (const float*)d_in[2];
    const float* bk   = (const float*)d_in[3];
    const float* Wg1  = (const float*)d_in[4];
    const float* bg1  = (const float*)d_in[5];
    const float* Wg2  = (const float*)d_in[6];
    const float* bg2  = (const float*)d_in[7];
    const float* Wq   = (const float*)d_in[8];
    const float* bq   = (const float*)d_in[9];
    const float* Wkey = (const float*)d_in[10];
    const float* bkey = (const float*)d_in[11];
    const float* Woff = (const float*)d_in[12];
    const float* boff = (const float*)d_in[13];
    const float* pw   = (const float*)d_in[14];
    const float* Wf1  = (const float*)d_in[15];
    const float* bf1  = (const float*)d_in[16];
    const float* Wf2  = (const float*)d_in[17];
    const float* bf2  = (const float*)d_in[18];
    const float* Wf3  = (const float*)d_in[19];
    const float* bf3  = (const float*)d_in[20];
    const float* Wcy3 = (const float*)d_in[21];
    const float* bcy3 = (const float*)d_in[22];
    const float* Wcx3 = (const float*)d_in[23];
    const float* bcx3 = (const float*)d_in[24];
    const float* Wcy5 = (const float*)d_in[25];
    const float* bcy5 = (const float*)d_in[26];
    const float* Wcx5 = (const float*)d_in[27];
    const float* bcx5 = (const float*)d_in[28];
    const float* Wcy9 = (const float*)d_in[29];
    const float* bcy9 = (const float*)d_in[30];
    const float* Wcx9 = (const float*)d_in[31];
    const float* bcx9 = (const float*)d_in[32];

    char* ws = (char*)d_ws;
    size_t off = 0;
    auto alloc = [&](size_t b)->void*{ void* p = ws + off; off += (b + 255) & ~(size_t)255; return p; };

    // --- zero-init region (one small memset) ---
    char* zbase = ws + off;
    float*    colsum    = (float*)   alloc(4*4);
    int*      cnt3      = (int*)     alloc((size_t)NN*4);
    int*      cnt5      = (int*)     alloc((size_t)NN*4);
    int*      cnt9      = (int*)     alloc((size_t)NN*4);
    int*      cur       = (int*)     alloc((size_t)3*NN*4);
    unsigned* rowmaxenc = (unsigned*)alloc((size_t)NN*4);
    size_t zbytes = (size_t)((ws + off) - zbase);
    unsigned* rowminenc = (unsigned*)alloc((size_t)NN*4);   // memset 0xFF

    // --- non-zeroed ---
    float* x0     = (float*)alloc((size_t)NN*8*4);
    float* maxd   = (float*)alloc((size_t)NN*4);
    int*   nbr    = (int*)  alloc((size_t)NN*9*4);
    int*   offc   = (int*)  alloc((size_t)3*NN*4);
    float* dinvc  = (float*)alloc((size_t)3*NN*4);
    int*   rev    = (int*)  alloc((size_t)NN*17*4);
    float* xw     = (float*)alloc((size_t)NN*64*4);
    float* y2     = (float*)alloc((size_t)3*NN*128*4);
    float* emb    = (float*)alloc((size_t)NN*384*4);
    float* qb     = (float*)alloc((size_t)NN*128*4);
    float* kb     = (float*)alloc((size_t)NN*128*4);
    float* scores = (float*)alloc((size_t)NN*NN*4);
    float* Tyb    = (float*)alloc((size_t)NN*4*4);
    float* invr   = (float*)alloc((size_t)NN*4);
    float* im     = (float*)alloc((size_t)NN*4);
    float* dOt    = (float*)alloc((size_t)NN*4*4);
    float* ASd    = (float*)alloc((size_t)NN*4*4);
    float* Bv     = (float*)alloc((size_t)NN*4*4);
    float* mnmx   = (float*)alloc((size_t)2*1216*4);
    float* gmm    = (float*)alloc(2*4);
    float* hfin   = (float*)alloc((size_t)NN*4*4);
    (void)ws_size; (void)in_sizes; (void)n_in; (void)out_size;

    hipMemsetAsync(zbase, 0, zbytes, stream);
    hipMemsetAsync(rowminenc, 0xFF, (size_t)NN*4, stream);

    k_prep<<<16,256,0,stream>>>(dx1,dx2,Wk,bk,x0,colsum);
    k_ty  <<<16,256,0,stream>>>(x0,Wcy3,Wcy5,Wcy9,Tyb);
    k_dist<<<NN/4,256,0,stream>>>(dx1,x0,maxd,nbr,cnt3,cnt5,cnt9,dOt);
    k_scan<<<1,256,0,stream>>>(cnt3,cnt5,cnt9,offc,dinvc);
    k_fill<<<16,256,0,stream>>>(nbr,offc,cur,rev);

    k_y1  <<<NN*64/256,256,0,stream>>>(x0,Wg1,xw);
    k_h1y2<<<NN/4,256,0,stream>>>(xw,offc,cnt3,cnt5,cnt9,rev,dinvc,bg1,Wg2,y2);
    k_fin <<<NN*3,128,0,stream>>>(y2,offc,cnt3,cnt5,cnt9,rev,dinvc,bg2,emb);

    k_qk<<<NN/8,256,0,stream>>>(emb,Wq,bq,Wkey,bkey,qb,kb);
    k_scores<<<1024,256,0,stream>>>(qb,kb,scores,rowmaxenc,rowminenc);
    k_invr<<<16,256,0,stream>>>(rowmaxenc,maxd,invr,im);

    k_cstream<<<dim3(19,64),256,0,stream>>>(scores,invr,
        Wcy3,Wcx3,Wcy5,Wcx5,Wcy9,Wcx9,
        bcy3,bcx3,bcy5,bcx5,bcy9,bcx9, mnmx);
    k_rowdot<<<NN/8,256,0,stream>>>(scores,x0,Tyb,invr,im,dOt,colsum,
        bcy3,bcx3,bcy5,bcx5,bcy9,bcx9, ASd, Bv);
    k_gmm<<<1,256,0,stream>>>(mnmx,rowminenc,rowmaxenc,gmm);
    k_hfin<<<16,256,0,stream>>>(ASd,Bv,Wcx3,Wcx5,Wcx9,gmm,colsum,hfin);
    k_mlp<<<NN/8,256,0,stream>>>(hfin,Woff,boff,pw,Wf1,bf1,Wf2,bf2,Wf3,bf3,(float*)d_out);
}

// Round 9
// 347.188 us; speedup vs baseline: 1.1729x; 1.0173x over previous
//
#include <hip/hip_runtime.h>
#include <math.h>

#define NN 4096

typedef __bf16 bf16x8 __attribute__((ext_vector_type(8)));
typedef float  f32x4  __attribute__((ext_vector_type(4)));

static __device__ __forceinline__ unsigned enc_f(float f){
    unsigned u = __float_as_uint(f);
    return (u & 0x80000000u) ? ~u : (u | 0x80000000u);
}
static __device__ __forceinline__ float dec_f(unsigned u){
    unsigned b = (u & 0x80000000u) ? (u & 0x7fffffffu) : ~u;
    return __uint_as_float(b);
}

// ---------- phase 1: x0 assembly + Ot column sums ----------
__global__ void k_prep(const float* __restrict__ dx1, const float* __restrict__ dx2,
                       const float* __restrict__ Wk, const float* __restrict__ bk,
                       float* __restrict__ x0, float* __restrict__ colsum){
    int n = blockIdx.x*blockDim.x + threadIdx.x;
    if (n >= NN) return;
    float wk[8];
    #pragma unroll
    for (int j=0;j<8;j++) wk[j] = Wk[j];
    float bkv = bk[0];
    #pragma unroll
    for (int c=0;c<4;c++) x0[n*8+c] = dx1[n*4+c];
    #pragma unroll
    for (int c=0;c<4;c++){
        float acc = bkv;
        #pragma unroll
        for (int j=0;j<8;j++) acc += dx2[(n*8+j)*4+c]*wk[j];
        x0[n*8+4+c] = acc;
        atomicAdd(&colsum[c], acc);
    }
}

// ---------- phase 1b: Ty[j] = sum over valid output pos of Cy * Ot ----------
__global__ void k_ty(const float* __restrict__ x0,
        const float* __restrict__ Wcy3, const float* __restrict__ Wcy5, const float* __restrict__ Wcy9,
        float* __restrict__ Ty){
    int j = blockIdx.x*256 + threadIdx.x;
    if (j >= NN) return;
    float Cy[9];
    #pragma unroll
    for (int o=-4;o<=4;o++){
        float c = Wcy9[o+4];
        if (o>=-2 && o<=2) c += Wcy5[o+2];
        if (o>=-1 && o<=1) c += Wcy3[o+1];
        Cy[o+4] = c;
    }
    float4 acc = {0,0,0,0};
    #pragma unroll
    for (int o=-4;o<=4;o++){
        int jj = j - o;
        if ((unsigned)jj < NN){
            float4 ot = *(const float4*)&x0[jj*8+4];
            float c = Cy[o+4];
            acc.x += c*ot.x; acc.y += c*ot.y; acc.z += c*ot.z; acc.w += c*ot.w;
        }
    }
    *(float4*)&Ty[j*4] = acc;
}

// ---------- phase 2: row max dist + top-9 knn + in-deg counts + dOt ----------
__global__ __launch_bounds__(256) void k_dist(const float* __restrict__ dx1,
        const float* __restrict__ x0,
        float* __restrict__ maxd, int* __restrict__ nbr,
        int* __restrict__ cnt3, int* __restrict__ cnt5, int* __restrict__ cnt9,
        float* __restrict__ dOt){
    __shared__ float2 ps[NN];
    int tid = threadIdx.x;
    for (int j=tid; j<NN; j+=256){
        float4 v = *(const float4*)&dx1[j*4];
        ps[j] = make_float2(v.x, v.y);
    }
    __syncthreads();
    int lane = tid & 63;
    int i = blockIdx.x*4 + (tid>>6);
    float2 pi = ps[i];
    unsigned long long best[9];
    #pragma unroll
    for (int q=0;q<9;q++) best[q] = ~0ULL;
    float lmax = 0.f;
    float4 dacc = {0,0,0,0};
    for (int t=0;t<64;t++){
        int j = (t<<6) | lane;
        float2 p = ps[j];
        float dx = pi.x - p.x, dy = pi.y - p.y;
        float d = sqrtf(dx*dx + dy*dy);
        lmax = fmaxf(lmax, d);
        float4 otj = *(const float4*)&x0[j*8+4];
        dacc.x += d*otj.x; dacc.y += d*otj.y; dacc.z += d*otj.z; dacc.w += d*otj.w;
        unsigned long long cand = ((unsigned long long)__float_as_uint(d) << 32) | (unsigned)j;
        if (j != i && cand < best[8]){
            best[8] = cand;
            #pragma unroll
            for (int q=8; q>0; --q){
                if (best[q] < best[q-1]){ unsigned long long tm=best[q]; best[q]=best[q-1]; best[q-1]=tm; }
            }
        }
    }
    #pragma unroll
    for (int m=1;m<64;m<<=1){
        lmax = fmaxf(lmax, __shfl_xor(lmax, m, 64));
        dacc.x += __shfl_xor(dacc.x, m, 64);
        dacc.y += __shfl_xor(dacc.y, m, 64);
        dacc.z += __shfl_xor(dacc.z, m, 64);
        dacc.w += __shfl_xor(dacc.w, m, 64);
    }
    if (lane==0){
        maxd[i] = lmax;
        *(float4*)&dOt[i*4] = dacc;
    }
    for (int t=0;t<9;t++){
        unsigned long long w = best[0];
        #pragma unroll
        for (int m=1;m<64;m<<=1){
            unsigned long long o = __shfl_xor(w, m, 64);
            if (o < w) w = o;
        }
        if (best[0] == w){
            #pragma unroll
            for (int q=0;q<8;q++) best[q] = best[q+1];
            best[8] = ~0ULL;
        }
        if (lane==0){
            int j = (int)(w & 0xffffffffu);
            nbr[i*9+t] = j;
            atomicAdd(&cnt9[j], 1);
            if (t<5) atomicAdd(&cnt5[j], 1);
            if (t<3) atomicAdd(&cnt3[j], 1);
        }
    }
}

// ---------- phase 2b: CSR offsets (exclusive scan) + dinv ----------
__global__ __launch_bounds__(256) void k_scan(const int* __restrict__ cnt3,
        const int* __restrict__ cnt5, const int* __restrict__ cnt9,
        int* __restrict__ offc, float* __restrict__ dinvc){
    __shared__ int part[256];
    int tid = threadIdx.x;
    for (int g=0; g<3; g++){
        const int* cp = g==0?cnt3:(g==1?cnt5:cnt9);
        int base = tid*16;
        int loc[16]; int s=0;
        #pragma unroll
        for (int q=0;q<16;q++){ loc[q]=s; s += cp[base+q]; }
        part[tid]=s; __syncthreads();
        for (int d=1; d<256; d<<=1){
            int v = (tid>=d) ? part[tid-d] : 0;
            __syncthreads();
            part[tid] += v;
            __syncthreads();
        }
        int pre = (tid==0) ? 0 : part[tid-1];
        #pragma unroll
        for (int q=0;q<16;q++){
            offc[g*NN + base + q]  = pre + loc[q];
            dinvc[g*NN + base + q] = rsqrtf((float)cp[base+q] + 1.f);
        }
        __syncthreads();
    }
}

// ---------- phase 2c: fill reverse-edge lists ----------
__global__ void k_fill(const int* __restrict__ nbr, const int* __restrict__ offc,
        int* __restrict__ cur, int* __restrict__ rev){
    int i = blockIdx.x*256 + threadIdx.x;
    if (i >= NN) return;
    #pragma unroll
    for (int t=0;t<9;t++){
        int j = nbr[i*9+t];
        int gmin = t<3 ? 0 : (t<5 ? 1 : 2);
        for (int g=gmin; g<3; g++){
            int pos = atomicAdd(&cur[g*NN+j], 1);
            int rb = (g==0) ? 0 : (g==1 ? NN*3 : NN*8);
            rev[rb + offc[g*NN+j] + pos] = i;
        }
    }
}

// ---------- phase 3: GCN layer-1 input transform ----------
__global__ void k_y1(const float* __restrict__ x0, const float* __restrict__ Wg1,
                     float* __restrict__ xw){
    int idx = blockIdx.x*256 + threadIdx.x;
    if (idx >= NN*64) return;
    int n = idx>>6, c = idx&63;
    float acc = 0.f;
    #pragma unroll
    for (int k=0;k<8;k++) acc += x0[n*8+k]*Wg1[k*64+c];
    xw[idx] = acc;
}

// ---------- phase 3b: gather layer-1 + relu + layer-2 matmul ----------
__global__ __launch_bounds__(256) void k_h1y2(const float* __restrict__ xw,
        const int* __restrict__ offc,
        const int* __restrict__ cnt3, const int* __restrict__ cnt5, const int* __restrict__ cnt9,
        const int* __restrict__ rev, const float* __restrict__ dinvc,
        const float* __restrict__ bg1, const float* __restrict__ Wg2,
        float* __restrict__ y2){
    __shared__ float h1s[12][64];
    int n0 = blockIdx.x*4, tid = threadIdx.x;
    for (int s=tid; s<768; s+=256){
        int p = s>>6, k = s&63, g = p>>2, n = n0+(p&3);
        const int* cp = g==0?cnt3:(g==1?cnt5:cnt9);
        int rb = (g==0) ? 0 : (g==1 ? NN*3 : NN*8);
        int cnt = cp[n];
        int o = rb + offc[g*NN+n];
        float dv = dinvc[g*NN+n];
        float srow = dv*xw[n*64+k];
        for (int e=0;e<cnt;e++){
            int i = rev[o+e];
            srow += dinvc[g*NN+i]*xw[i*64+k];
        }
        float v = dv*srow + bg1[k];
        h1s[p][k] = v>0.f ? v : 0.f;
    }
    __syncthreads();
    int c = tid & 127, ph = tid>>7;
    float a6[6] = {0,0,0,0,0,0};
    for (int k=0;k<64;k++){
        float w = Wg2[k*128+c];
        #pragma unroll
        for (int q=0;q<6;q++) a6[q] += h1s[q*2+ph][k]*w;
    }
    #pragma unroll
    for (int q=0;q<6;q++){
        int p = q*2+ph, g = p>>2, n = n0+(p&3);
        float dv = dinvc[g*NN+n];
        y2[(size_t)g*NN*128 + (size_t)n*128 + c] = dv*a6[q];
    }
}

// ---------- phase 3c: gather layer-2 + bias + log_softmax ----------
__global__ __launch_bounds__(128) void k_fin(const float* __restrict__ y2,
        const int* __restrict__ offc,
        const int* __restrict__ cnt3, const int* __restrict__ cnt5, const int* __restrict__ cnt9,
        const int* __restrict__ rev, const float* __restrict__ dinvc,
        const float* __restrict__ bg2, float* __restrict__ emb){
    __shared__ float sm[2], ss[2];
    int b = blockIdx.x;
    int n = b & (NN-1), g = b >> 12;
    const int* cp = g==0?cnt3:(g==1?cnt5:cnt9);
    int rb = (g==0) ? 0 : (g==1 ? NN*3 : NN*8);
    int cnt = cp[n];
    int o = rb + offc[g*NN+n];
    float dv = dinvc[g*NN+n];
    int c = threadIdx.x;
    const float* yg = y2 + (size_t)g*NN*128;
    float s = yg[(size_t)n*128 + c];
    for (int e=0;e<cnt;e++){
        int i = rev[o+e];
        s += yg[(size_t)i*128 + c];
    }
    float v = dv*s + bg2[c];
    float m = v;
    #pragma unroll
    for (int st=1;st<64;st<<=1) m = fmaxf(m, __shfl_xor(m, st, 64));
    if ((c&63)==0) sm[c>>6] = m;
    __syncthreads();
    m = fmaxf(sm[0], sm[1]);
    float e = expf(v - m);
    float t = e;
    #pragma unroll
    for (int st=1;st<64;st<<=1) t += __shfl_xor(t, st, 64);
    if ((c&63)==0) ss[c>>6] = t;
    __syncthreads();
    t = ss[0]+ss[1];
    emb[n*384 + g*128 + c] = v - m - logf(t);
}

// ---------- phase 4: q/k projections -> bf16 hi/lo split ----------
__global__ __launch_bounds__(256) void k_qk(const float* __restrict__ emb,
        const float* __restrict__ Wq, const float* __restrict__ bq,
        const float* __restrict__ Wkey, const float* __restrict__ bkey,
        __bf16* __restrict__ qh, __bf16* __restrict__ ql,
        __bf16* __restrict__ kh, __bf16* __restrict__ kl){
    __shared__ float es[8][384];
    int n0 = blockIdx.x*8;
    int tid = threadIdx.x;
    for (int idx=tid; idx<8*384; idx+=256){
        int m = idx/384, k = idx%384;
        es[m][k] = emb[(n0+m)*384+k];
    }
    __syncthreads();
    int c = tid & 127;
    int sel = tid >> 7;
    const float* W = sel ? Wkey : Wq;
    float b = sel ? bkey[c] : bq[c];
    float acc[8];
    #pragma unroll
    for (int m=0;m<8;m++) acc[m]=b;
    for (int k=0;k<384;k++){
        float w = W[k*128+c];
        #pragma unroll
        for (int m=0;m<8;m++) acc[m] += es[m][k]*w;
    }
    __bf16* oh = sel ? kh : qh;
    __bf16* ol = sel ? kl : ql;
    #pragma unroll
    for (int m=0;m<8;m++){
        float v = acc[m];
        __bf16 h = (__bf16)v;
        oh[(size_t)(n0+m)*128+c] = h;
        ol[(size_t)(n0+m)*128+c] = (__bf16)(v - (float)h);
    }
}

// ---------- phase 5: scores = q @ k^T via bf16-split MFMA + fused row max/min ----------
// scores ~= qh*kh + qh*kl + ql*kh  (ql*kl ~ 2^-18 rel, dropped)
// Fragment layouts (m89-verified family): A/B lane l: row/col = l&15, k = (l>>4)*8+j;
// D: col = l&15, row = (l>>4)*4 + reg.
__global__ __launch_bounds__(256) void k_scores(
        const __bf16* __restrict__ qh, const __bf16* __restrict__ ql,
        const __bf16* __restrict__ kh, const __bf16* __restrict__ kl,
        float* __restrict__ scores,
        unsigned* __restrict__ rowmaxenc, unsigned* __restrict__ rowminenc){
    int bx = blockIdx.x & 31;
    int by = blockIdx.x >> 5;
    int tid = threadIdx.x;
    int w = tid >> 6, lane = tid & 63;
    int li = lane & 15, g = lane >> 4;
    int r0 = by*128 + (w>>1)*64;
    int c0 = bx*128 + (w&1)*64;

    f32x4 acc[4][4] = {};
    for (int ks=0; ks<4; ++ks){
        int kofs = ks*32 + g*8;
        bf16x8 ah[4], al[4], bh[4], bl[4];
        #pragma unroll
        for (int f=0; f<4; ++f){
            ah[f] = *(const bf16x8*)&qh[(size_t)(r0+f*16+li)*128 + kofs];
            al[f] = *(const bf16x8*)&ql[(size_t)(r0+f*16+li)*128 + kofs];
            bh[f] = *(const bf16x8*)&kh[(size_t)(c0+f*16+li)*128 + kofs];
            bl[f] = *(const bf16x8*)&kl[(size_t)(c0+f*16+li)*128 + kofs];
        }
        #pragma unroll
        for (int fr=0; fr<4; ++fr){
            #pragma unroll
            for (int fc=0; fc<4; ++fc){
                acc[fr][fc] = __builtin_amdgcn_mfma_f32_16x16x32_bf16(ah[fr], bh[fc], acc[fr][fc], 0, 0, 0);
                acc[fr][fc] = __builtin_amdgcn_mfma_f32_16x16x32_bf16(ah[fr], bl[fc], acc[fr][fc], 0, 0, 0);
                acc[fr][fc] = __builtin_amdgcn_mfma_f32_16x16x32_bf16(al[fr], bh[fc], acc[fr][fc], 0, 0, 0);
            }
        }
    }
    #pragma unroll
    for (int fr=0; fr<4; ++fr){
        #pragma unroll
        for (int r=0; r<4; ++r){
            int row = r0 + fr*16 + g*4 + r;
            float mx = -INFINITY, mn = INFINITY;
            #pragma unroll
            for (int fc=0; fc<4; ++fc){
                float v = acc[fr][fc][r];
                scores[(size_t)row*NN + c0 + fc*16 + li] = v;
                mx = fmaxf(mx, v);
                mn = fminf(mn, v);
            }
            #pragma unroll
            for (int s=1; s<16; s<<=1){
                mx = fmaxf(mx, __shfl_xor(mx, s, 64));
                mn = fminf(mn, __shfl_xor(mn, s, 64));
            }
            if (li == 0){
                atomicMax(&rowmaxenc[row], enc_f(mx));
                atomicMin(&rowminenc[row], enc_f(mn));
            }
        }
    }
}

// ---------- phase 6: streaming conv min/max over A (shuffle column stencil) ----------
__global__ __launch_bounds__(256) void k_cstream(const float* __restrict__ scores,
        const unsigned* __restrict__ rowmaxenc,
        const float* __restrict__ Wcy3, const float* __restrict__ Wcx3,
        const float* __restrict__ Wcy5, const float* __restrict__ Wcx5,
        const float* __restrict__ Wcy9, const float* __restrict__ Wcx9,
        const float* __restrict__ bcy3, const float* __restrict__ bcx3,
        const float* __restrict__ bcy5, const float* __restrict__ bcx5,
        const float* __restrict__ bcy9, const float* __restrict__ bcx9,
        float* __restrict__ mnmx){
    __shared__ float smn[4], smx[4];
    int tid = threadIdx.x;
    int w = tid >> 6, lane = tid & 63;
    int strip = blockIdx.x*4 + w;
    int jj = strip*56 - 4 + lane;               // loaded col
    bool cvalid = (unsigned)jj < NN;
    bool outLane = (lane >= 4) && (lane < 60) && cvalid;
    int i0 = blockIdx.y*64;

    float wy3[3],wx3[3],wy5[5],wx5[5],wy9[9],wx9[9];
    #pragma unroll
    for (int t=0;t<3;t++){ wy3[t]=Wcy3[t]; wx3[t]=Wcx3[t]; }
    #pragma unroll
    for (int t=0;t<5;t++){ wy5[t]=Wcy5[t]; wx5[t]=Wcx5[t]; }
    #pragma unroll
    for (int t=0;t<9;t++){ wy9[t]=Wcy9[t]; wx9[t]=Wcx9[t]; }
    float bc3 = bcy3[0]+bcx3[0];
    float bc5 = bcy5[0]+bcx5[0];
    float bc9 = bcy9[0]+bcx9[0];

    float win[9], cy3r[9], cy5r[9], cy9r[9];
    float mn = INFINITY, mx = -INFINITY;

    for (int tb = 0; tb < 8; ++tb){
        #pragma unroll
        for (int u = 0; u < 9; ++u){
            int t  = tb*9 + u;
            int ri = i0 - 4 + t;
            float a = 0.f;
            if (((unsigned)ri < NN) && cvalid)
                a = scores[(size_t)ri*NN + jj] * (1.f/dec_f(rowmaxenc[ri]));
            float tp[9];
            #pragma unroll
            for (int k=0;k<9;k++) tp[k] = (k==4) ? a : __shfl(a, lane + k - 4, 64);
            float cy9v = ((tp[0]*wy9[0] + tp[1]*wy9[1]) + (tp[2]*wy9[2] + tp[3]*wy9[3]))
                       + ((tp[4]*wy9[4] + tp[5]*wy9[5]) + (tp[6]*wy9[6] + tp[7]*wy9[7]))
                       + tp[8]*wy9[8];
            float cy5v = ((tp[2]*wy5[0] + tp[3]*wy5[1]) + (tp[4]*wy5[2] + tp[5]*wy5[3]))
                       + tp[6]*wy5[4];
            float cy3v = (tp[3]*wy3[0] + tp[4]*wy3[1]) + tp[5]*wy3[2];
            win[u]  = a;
            cy3r[u] = cy3v; cy5r[u] = cy5v; cy9r[u] = cy9v;
            if (t >= 8 && outLane){
                float cx9v = ((win[(u+1)%9]*wx9[0] + win[(u+2)%9]*wx9[1]) + (win[(u+3)%9]*wx9[2] + win[(u+4)%9]*wx9[3]))
                           + ((win[(u+5)%9]*wx9[4] + win[(u+6)%9]*wx9[5]) + (win[(u+7)%9]*wx9[6] + win[(u+8)%9]*wx9[7]))
                           + win[u]*wx9[8];
                float cx5v = ((win[(u+3)%9]*wx5[0] + win[(u+4)%9]*wx5[1]) + (win[(u+5)%9]*wx5[2] + win[(u+6)%9]*wx5[3]))
                           + win[(u+7)%9]*wx5[4];
                float cx3v = (win[(u+4)%9]*wx3[0] + win[(u+5)%9]*wx3[1]) + win[(u+6)%9]*wx3[2];
                float c9 = cy9r[(u+5)%9] + cx9v + bc9;
                float c5 = cy5r[(u+5)%9] + cx5v + bc5;
                float c3 = cy3r[(u+5)%9] + cx3v + bc3;
                mn = fminf(mn, fminf(fminf(c3,c5),c9));
                mx = fmaxf(mx, fmaxf(fmaxf(c3,c5),c9));
            }
        }
    }
    #pragma unroll
    for (int m=1; m<64; m<<=1){
        mn = fminf(mn, __shfl_xor(mn, m, 64));
        mx = fmaxf(mx, __shfl_xor(mx, m, 64));
    }
    if (lane == 0){ smn[w] = mn; smx[w] = mx; }
    __syncthreads();
    if (tid == 0){
        float a0 = fminf(fminf(smn[0],smn[1]), fminf(smn[2],smn[3]));
        float b0 = fmaxf(fmaxf(smx[0],smx[1]), fmaxf(smx[2],smx[3]));
        int bid = blockIdx.y*gridDim.x + blockIdx.x;
        mnmx[bid] = a0;
        mnmx[1216 + bid] = b0;
    }
}

// ---------- phase 6b: row dots: ASdot = A@Ot, B = everything row-local ----------
__global__ __launch_bounds__(256) void k_rowdot(const float* __restrict__ scores,
        const float* __restrict__ x0, const float* __restrict__ Ty,
        const unsigned* __restrict__ rowmaxenc, const float* __restrict__ maxd,
        const float* __restrict__ dOt, const float* __restrict__ colsum,
        const float* __restrict__ bcy3, const float* __restrict__ bcx3,
        const float* __restrict__ bcy5, const float* __restrict__ bcx5,
        const float* __restrict__ bcy9, const float* __restrict__ bcx9,
        float* __restrict__ ASdot, float* __restrict__ Bv){
    int tid = threadIdx.x;
    int tc = tid & 31, tr = tid >> 5;
    int i = blockIdx.x*8 + tr;
    const float* srow = scores + (size_t)i*NN;
    float4 ss = {0,0,0,0}, st = {0,0,0,0};
    for (int c0 = tc; c0 < NN; c0 += 32){
        float sv = srow[c0];
        float4 ot = *(const float4*)&x0[c0*8+4];
        float4 ty = *(const float4*)&Ty[c0*4];
        ss.x += sv*ot.x; ss.y += sv*ot.y; ss.z += sv*ot.z; ss.w += sv*ot.w;
        st.x += sv*ty.x; st.y += sv*ty.y; st.z += sv*ty.z; st.w += sv*ty.w;
    }
    #pragma unroll
    for (int s=1; s<32; s<<=1){
        ss.x += __shfl_xor(ss.x, s, 64); ss.y += __shfl_xor(ss.y, s, 64);
        ss.z += __shfl_xor(ss.z, s, 64); ss.w += __shfl_xor(ss.w, s, 64);
        st.x += __shfl_xor(st.x, s, 64); st.y += __shfl_xor(st.y, s, 64);
        st.z += __shfl_xor(st.z, s, 64); st.w += __shfl_xor(st.w, s, 64);
    }
    if (tc == 0){
        float iv = 1.f/dec_f(rowmaxenc[i]);
        float imv = 1.f/maxd[i];
        float bcsum = bcy3[0]+bcx3[0]+bcy5[0]+bcx5[0]+bcy9[0]+bcx9[0];
        float4 cs = *(const float4*)colsum;
        float4 dv = *(const float4*)&dOt[i*4];
        float4 as;
        as.x = iv*ss.x; as.y = iv*ss.y; as.z = iv*ss.z; as.w = iv*ss.w;
        float k = 1.f + bcsum;
        float4 b;
        b.x = cs.x*k - imv*dv.x + iv*st.x;
        b.y = cs.y*k - imv*dv.y + iv*st.y;
        b.z = cs.z*k - imv*dv.z + iv*st.z;
        b.w = cs.w*k - imv*dv.w + iv*st.w;
        *(float4*)&ASdot[i*4] = as;
        *(float4*)&Bv[i*4]   = b;
    }
}

// ---------- phase 6c: global min/max = conv blocks U A-range U {0,1} ----------
__global__ __launch_bounds__(256) void k_gmm(const float* __restrict__ mnmx,
        const unsigned* __restrict__ rowminenc, const unsigned* __restrict__ rowmaxenc,
        float* __restrict__ gmm){
    __shared__ float smn[256], smx[256];
    int tid = threadIdx.x;
    float mn = 0.f, mx = 1.f;   // oushi range is exactly [0,1]
    for (int i=tid; i<NN; i+=256){
        float rmx = dec_f(rowmaxenc[i]);
        float q = dec_f(rowminenc[i]) / rmx;
        mn = fminf(mn, fminf(1.f, q));
        mx = fmaxf(mx, fmaxf(1.f, q));
    }
    for (int b=tid; b<1216; b+=256){
        mn = fminf(mn, mnmx[b]);
        mx = fmaxf(mx, mnmx[1216+b]);
    }
    smn[tid]=mn; smx[tid]=mx; __syncthreads();
    for (int s=128;s>0;s>>=1){
        if (tid<s){ smn[tid]=fminf(smn[tid],smn[tid+s]); smx[tid]=fmaxf(smx[tid],smx[tid+s]); }
        __syncthreads();
    }
    if (tid==0){ gmm[0]=smn[0]; gmm[1]=smx[0]; }
}

// ---------- phase 7a: row-conv of ASdot + affine -> hfin ----------
__global__ void k_hfin(const float* __restrict__ ASdot, const float* __restrict__ Bv,
        const float* __restrict__ Wcx3, const float* __restrict__ Wcx5, const float* __restrict__ Wcx9,
        const float* __restrict__ gmm, const float* __restrict__ colsum,
        float* __restrict__ hfin){
    int i = blockIdx.x*256 + threadIdx.x;
    if (i >= NN) return;
    float Cx[9];
    #pragma unroll
    for (int o=-4;o<=4;o++){
        float c = Wcx9[o+4];
        if (o>=-2 && o<=2) c += Wcx5[o+2];
        if (o>=-1 && o<=1) c += Wcx3[o+1];
        Cx[o+4] = c;
    }
    float4 h = *(const float4*)&Bv[i*4];
    float4 a0 = *(const float4*)&ASdot[i*4];
    h.x += a0.x; h.y += a0.y; h.z += a0.z; h.w += a0.w;
    #pragma unroll
    for (int o=-4;o<=4;o++){
        int r = i + o;
        if ((unsigned)r < NN){
            float4 av = *(const float4*)&ASdot[r*4];
            float c = Cx[o+4];
            h.x += c*av.x; h.y += c*av.y; h.z += c*av.z; h.w += c*av.w;
        }
    }
    float mnv = gmm[0], mxv = gmm[1];
    float s = 1.f/(mxv-mnv), oa = -mnv*s;
    float4 cs = *(const float4*)colsum;
    float4 out;
    out.x = s*h.x + 5.f*oa*cs.x;
    out.y = s*h.y + 5.f*oa*cs.y;
    out.z = s*h.z + 5.f*oa*cs.z;
    out.w = s*h.w + 5.f*oa*cs.w;
    *(float4*)&hfin[i*4] = out;
}

// ---------- phase 7b: MLP head ----------
__global__ __launch_bounds__(256) void k_mlp(const float* __restrict__ hfin,
        const float* __restrict__ Woff, const float* __restrict__ boff, const float* __restrict__ pw,
        const float* __restrict__ Wf1, const float* __restrict__ bf1,
        const float* __restrict__ Wf2, const float* __restrict__ bf2,
        const float* __restrict__ Wf3, const float* __restrict__ bf3,
        float* __restrict__ out){
    __shared__ float h1[8][128];
    __shared__ float h2[8][256];
    __shared__ float h3[8][256];
    __shared__ float4 red4[256];
    int n0 = blockIdx.x*8, tid = threadIdx.x;
    float p = pw[0];
    {
        int c = tid & 127, mb = (tid>>7)*4;
        #pragma unroll
        for (int mm=0; mm<4; mm++){
            int m = mb+mm;
            float v = boff[c];
            #pragma unroll
            for (int k=0;k<4;k++) v += hfin[(n0+m)*4+k]*Woff[k*128+c];
            h1[m][c] = v>0.f ? v : p*v;
        }
    }
    __syncthreads();
    {
        int c = tid;
        float acc[8];
        #pragma unroll
        for (int m=0;m<8;m++) acc[m] = bf1[c];
        for (int k=0;k<128;k++){
            float w = Wf1[k*256+c];
            #pragma unroll
            for (int m=0;m<8;m++) acc[m] += h1[m][k]*w;
        }
        #pragma unroll
        for (int m=0;m<8;m++) h2[m][c] = acc[m]>0.f?acc[m]:0.f;
    }
    __syncthreads();
    {
        int c = tid;
        float acc[8];
        #pragma unroll
        for (int m=0;m<8;m++) acc[m] = bf2[c];
        for (int k=0;k<256;k++){
            float w = Wf2[k*256+c];
            #pragma unroll
            for (int m=0;m<8;m++) acc[m] += h2[m][k]*w;
        }
        #pragma unroll
        for (int m=0;m<8;m++) h3[m][c] = acc[m]>0.f?acc[m]:0.f;
    }
    __syncthreads();
    float w3_0 = Wf3[tid*4+0], w3_1 = Wf3[tid*4+1], w3_2 = Wf3[tid*4+2], w3_3 = Wf3[tid*4+3];
    for (int m=0;m<8;m++){
        float hv = h3[m][tid];
        float4 r; r.x = hv*w3_0; r.y = hv*w3_1; r.z = hv*w3_2; r.w = hv*w3_3;
        red4[tid]=r; __syncthreads();
        for (int s=128;s>0;s>>=1){
            if(tid<s){
                red4[tid].x+=red4[tid+s].x; red4[tid].y+=red4[tid+s].y;
                red4[tid].z+=red4[tid+s].z; red4[tid].w+=red4[tid+s].w;
            }
            __syncthreads();
        }
        if (tid==0){
            float4 o;
            o.x = red4[0].x + bf3[0]; o.y = red4[0].y + bf3[1];
            o.z = red4[0].z + bf3[2]; o.w = red4[0].w + bf3[3];
            *(float4*)&out[(n0+m)*4] = o;
        }
        __syncthreads();
    }
}

// ---------- host ----------
extern "C" void kernel_launch(void* const* d_in, const int* in_sizes, int n_in,
                              void* d_out, int out_size, void* d_ws, size_t ws_size,
                              hipStream_t stream){
    const float* dx1  = (const float*)d_in[0];
    const float* dx2  = (const float*)d_in[1];
    const float* Wk   = (const float*)d_in[2];
    const float* bk   = (const float*)d_in[3];
    const float* Wg1  = (const float*)d_in[4];
    const float* bg1  = (const float*)d_in[5];
    const float* Wg2  = (const float*)d_in[6];
    const float* bg2  = (const float*)d_in[7];
    const float* Wq   = (const float*)d_in[8];
    const float* bq   = (const float*)d_in[9];
    const float* Wkey = (const float*)d_in[10];
    const float* bkey = (const float*)d_in[11];
    const float* Woff = (const float*)d_in[12];
    const float* boff = (const float*)d_in[13];
    const float* pw   = (const float*)d_in[14];
    const float* Wf1  = (const float*)d_in[15];
    const float* bf1  = (const float*)d_in[16];
    const float* Wf2  = (const float*)d_in[17];
    const float* bf2  = (const float*)d_in[18];
    const float* Wf3  = (const float*)d_in[19];
    const float* bf3  = (const float*)d_in[20];
    const float* Wcy3 = (const float*)d_in[21];
    const float* bcy3 = (const float*)d_in[22];
    const float* Wcx3 = (const float*)d_in[23];
    const float* bcx3 = (const float*)d_in[24];
    const float* Wcy5 = (const float*)d_in[25];
    const float* bcy5 = (const float*)d_in[26];
    const float* Wcx5 = (const float*)d_in[27];
    const float* bcx5 = (const float*)d_in[28];
    const float* Wcy9 = (const float*)d_in[29];
    const float* bcy9 = (const float*)d_in[30];
    const float* Wcx9 = (const float*)d_in[31];
    const float* bcx9 = (const float*)d_in[32];

    char* ws = (char*)d_ws;
    size_t off = 0;
    auto alloc = [&](size_t b)->void*{ void* p = ws + off; off += (b + 255) & ~(size_t)255; return p; };

    // --- zero-init region (one small memset) ---
    char* zbase = ws + off;
    float*    colsum    = (float*)   alloc(4*4);
    int*      cnt3      = (int*)     alloc((size_t)NN*4);
    int*      cnt5      = (int*)     alloc((size_t)NN*4);
    int*      cnt9      = (int*)     alloc((size_t)NN*4);
    int*      cur       = (int*)     alloc((size_t)3*NN*4);
    unsigned* rowmaxenc = (unsigned*)alloc((size_t)NN*4);
    size_t zbytes = (size_t)((ws + off) - zbase);
    unsigned* rowminenc = (unsigned*)alloc((size_t)NN*4);   // memset 0xFF

    // --- non-zeroed ---
    float* x0     = (float*)alloc((size_t)NN*8*4);
    float* maxd   = (float*)alloc((size_t)NN*4);
    int*   nbr    = (int*)  alloc((size_t)NN*9*4);
    int*   offc   = (int*)  alloc((size_t)3*NN*4);
    float* dinvc  = (float*)alloc((size_t)3*NN*4);
    int*   rev    = (int*)  alloc((size_t)NN*17*4);
    float* xw     = (float*)alloc((size_t)NN*64*4);
    float* y2     = (float*)alloc((size_t)3*NN*128*4);
    float* emb    = (float*)alloc((size_t)NN*384*4);
    __bf16* qh   = (__bf16*)alloc((size_t)NN*128*2);
    __bf16* ql   = (__bf16*)alloc((size_t)NN*128*2);
    __bf16* kh   = (__bf16*)alloc((size_t)NN*128*2);
    __bf16* kl   = (__bf16*)alloc((size_t)NN*128*2);
    float* scores = (float*)alloc((size_t)NN*NN*4);
    float* Tyb    = (float*)alloc((size_t)NN*4*4);
    float* dOt    = (float*)alloc((size_t)NN*4*4);
    float* ASd    = (float*)alloc((size_t)NN*4*4);
    float* Bv     = (float*)alloc((size_t)NN*4*4);
    float* mnmx   = (float*)alloc((size_t)2*1216*4);
    float* gmm    = (float*)alloc(2*4);
    float* hfin   = (float*)alloc((size_t)NN*4*4);
    (void)ws_size; (void)in_sizes; (void)n_in; (void)out_size;

    hipMemsetAsync(zbase, 0, zbytes, stream);
    hipMemsetAsync(rowminenc, 0xFF, (size_t)NN*4, stream);

    k_prep<<<16,256,0,stream>>>(dx1,dx2,Wk,bk,x0,colsum);
    k_ty  <<<16,256,0,stream>>>(x0,Wcy3,Wcy5,Wcy9,Tyb);
    k_dist<<<NN/4,256,0,stream>>>(dx1,x0,maxd,nbr,cnt3,cnt5,cnt9,dOt);
    k_scan<<<1,256,0,stream>>>(cnt3,cnt5,cnt9,offc,dinvc);
    k_fill<<<16,256,0,stream>>>(nbr,offc,cur,rev);

    k_y1  <<<NN*64/256,256,0,stream>>>(x0,Wg1,xw);
    k_h1y2<<<NN/4,256,0,stream>>>(xw,offc,cnt3,cnt5,cnt9,rev,dinvc,bg1,Wg2,y2);
    k_fin <<<NN*3,128,0,stream>>>(y2,offc,cnt3,cnt5,cnt9,rev,dinvc,bg2,emb);

    k_qk<<<NN/8,256,0,stream>>>(emb,Wq,bq,Wkey,bkey,qh,ql,kh,kl);
    k_scores<<<1024,256,0,stream>>>(qh,ql,kh,kl,scores,rowmaxenc,rowminenc);

    k_cstream<<<dim3(19,64),256,0,stream>>>(scores,rowmaxenc,
        Wcy3,Wcx3,Wcy5,Wcx5,Wcy9,Wcx9,
        bcy3,bcx3,bcy5,bcx5,bcy9,bcx9, mnmx);
    k_rowdot<<<NN/8,256,0,stream>>>(scores,x0,Tyb,rowmaxenc,maxd,dOt,colsum,
        bcy3,bcx3,bcy5,bcx5,bcy9,bcx9, ASd, Bv);
    k_gmm<<<1,256,0,stream>>>(mnmx,rowminenc,rowmaxenc,gmm);
    k_hfin<<<16,256,0,stream>>>(ASd,Bv,Wcx3,Wcx5,Wcx9,gmm,colsum,hfin);
    k_mlp<<<NN/8,256,0,stream>>>(hfin,Woff,boff,pw,Wf1,bf1,Wf2,bf2,Wf3,bf3,(float*)d_out);
}

// Round 10
// 334.512 us; speedup vs baseline: 1.2174x; 1.0379x over previous
//
#include <hip/hip_runtime.h>
#include <math.h>

#define NN 4096

typedef __bf16 bf16x8 __attribute__((ext_vector_type(8)));
typedef float  f32x4  __attribute__((ext_vector_type(4)));

static __device__ __forceinline__ unsigned enc_f(float f){
    unsigned u = __float_as_uint(f);
    return (u & 0x80000000u) ? ~u : (u | 0x80000000u);
}
static __device__ __forceinline__ float dec_f(unsigned u){
    unsigned b = (u & 0x80000000u) ? (u & 0x7fffffffu) : ~u;
    return __uint_as_float(b);
}
static __device__ __forceinline__ float4 shfl4(float4 v, int src){
    float4 r;
    r.x = __shfl(v.x, src, 64);
    r.y = __shfl(v.y, src, 64);
    r.z = __shfl(v.z, src, 64);
    r.w = __shfl(v.w, src, 64);
    return r;
}

// ---------- phase 1: x0 assembly + Ot column sums ----------
__global__ void k_prep(const float* __restrict__ dx1, const float* __restrict__ dx2,
                       const float* __restrict__ Wk, const float* __restrict__ bk,
                       float* __restrict__ x0, float* __restrict__ colsum){
    int n = blockIdx.x*blockDim.x + threadIdx.x;
    if (n >= NN) return;
    float wk[8];
    #pragma unroll
    for (int j=0;j<8;j++) wk[j] = Wk[j];
    float bkv = bk[0];
    #pragma unroll
    for (int c=0;c<4;c++) x0[n*8+c] = dx1[n*4+c];
    #pragma unroll
    for (int c=0;c<4;c++){
        float acc = bkv;
        #pragma unroll
        for (int j=0;j<8;j++) acc += dx2[(n*8+j)*4+c]*wk[j];
        x0[n*8+4+c] = acc;
        atomicAdd(&colsum[c], acc);
    }
}

// ---------- phase 1b: Ty[j] = column-conv kernel applied to Ot ----------
__global__ void k_ty(const float* __restrict__ x0,
        const float* __restrict__ Wcy3, const float* __restrict__ Wcy5, const float* __restrict__ Wcy9,
        float* __restrict__ Ty){
    int j = blockIdx.x*256 + threadIdx.x;
    if (j >= NN) return;
    float Cy[9];
    #pragma unroll
    for (int o=-4;o<=4;o++){
        float c = Wcy9[o+4];
        if (o>=-2 && o<=2) c += Wcy5[o+2];
        if (o>=-1 && o<=1) c += Wcy3[o+1];
        Cy[o+4] = c;
    }
    float4 acc = {0,0,0,0};
    #pragma unroll
    for (int o=-4;o<=4;o++){
        int jj = j - o;
        if ((unsigned)jj < NN){
            float4 ot = *(const float4*)&x0[jj*8+4];
            float c = Cy[o+4];
            acc.x += c*ot.x; acc.y += c*ot.y; acc.z += c*ot.z; acc.w += c*ot.w;
        }
    }
    *(float4*)&Ty[j*4] = acc;
}

// ---------- phase 2: row max dist + top-9 knn + in-deg counts + dOt ----------
__global__ __launch_bounds__(256) void k_dist(const float* __restrict__ dx1,
        const float* __restrict__ x0,
        float* __restrict__ maxd, int* __restrict__ nbr,
        int* __restrict__ cnt3, int* __restrict__ cnt5, int* __restrict__ cnt9,
        float* __restrict__ dOt){
    __shared__ float2 ps[NN];
    int tid = threadIdx.x;
    for (int j=tid; j<NN; j+=256){
        float4 v = *(const float4*)&dx1[j*4];
        ps[j] = make_float2(v.x, v.y);
    }
    __syncthreads();
    int lane = tid & 63;
    int i = blockIdx.x*4 + (tid>>6);
    float2 pi = ps[i];
    unsigned long long best[9];
    #pragma unroll
    for (int q=0;q<9;q++) best[q] = ~0ULL;
    float lmax = 0.f;
    float4 dacc = {0,0,0,0};
    for (int t=0;t<64;t++){
        int j = (t<<6) | lane;
        float2 p = ps[j];
        float dx = pi.x - p.x, dy = pi.y - p.y;
        float d = sqrtf(dx*dx + dy*dy);
        lmax = fmaxf(lmax, d);
        float4 otj = *(const float4*)&x0[j*8+4];
        dacc.x += d*otj.x; dacc.y += d*otj.y; dacc.z += d*otj.z; dacc.w += d*otj.w;
        unsigned long long cand = ((unsigned long long)__float_as_uint(d) << 32) | (unsigned)j;
        if (j != i && cand < best[8]){
            best[8] = cand;
            #pragma unroll
            for (int q=8; q>0; --q){
                if (best[q] < best[q-1]){ unsigned long long tm=best[q]; best[q]=best[q-1]; best[q-1]=tm; }
            }
        }
    }
    #pragma unroll
    for (int m=1;m<64;m<<=1){
        lmax = fmaxf(lmax, __shfl_xor(lmax, m, 64));
        dacc.x += __shfl_xor(dacc.x, m, 64);
        dacc.y += __shfl_xor(dacc.y, m, 64);
        dacc.z += __shfl_xor(dacc.z, m, 64);
        dacc.w += __shfl_xor(dacc.w, m, 64);
    }
    if (lane==0){
        maxd[i] = lmax;
        *(float4*)&dOt[i*4] = dacc;
    }
    for (int t=0;t<9;t++){
        unsigned long long w = best[0];
        #pragma unroll
        for (int m=1;m<64;m<<=1){
            unsigned long long o = __shfl_xor(w, m, 64);
            if (o < w) w = o;
        }
        if (best[0] == w){
            #pragma unroll
            for (int q=0;q<8;q++) best[q] = best[q+1];
            best[8] = ~0ULL;
        }
        if (lane==0){
            int j = (int)(w & 0xffffffffu);
            nbr[i*9+t] = j;
            atomicAdd(&cnt9[j], 1);
            if (t<5) atomicAdd(&cnt5[j], 1);
            if (t<3) atomicAdd(&cnt3[j], 1);
        }
    }
}

// ---------- phase 2b: CSR offsets (exclusive scan) + dinv ----------
__global__ __launch_bounds__(256) void k_scan(const int* __restrict__ cnt3,
        const int* __restrict__ cnt5, const int* __restrict__ cnt9,
        int* __restrict__ offc, float* __restrict__ dinvc){
    __shared__ int part[256];
    int tid = threadIdx.x;
    for (int g=0; g<3; g++){
        const int* cp = g==0?cnt3:(g==1?cnt5:cnt9);
        int base = tid*16;
        int loc[16]; int s=0;
        #pragma unroll
        for (int q=0;q<16;q++){ loc[q]=s; s += cp[base+q]; }
        part[tid]=s; __syncthreads();
        for (int d=1; d<256; d<<=1){
            int v = (tid>=d) ? part[tid-d] : 0;
            __syncthreads();
            part[tid] += v;
            __syncthreads();
        }
        int pre = (tid==0) ? 0 : part[tid-1];
        #pragma unroll
        for (int q=0;q<16;q++){
            offc[g*NN + base + q]  = pre + loc[q];
            dinvc[g*NN + base + q] = rsqrtf((float)cp[base+q] + 1.f);
        }
        __syncthreads();
    }
}

// ---------- phase 2c: fill reverse-edge lists ----------
__global__ void k_fill(const int* __restrict__ nbr, const int* __restrict__ offc,
        int* __restrict__ cur, int* __restrict__ rev){
    int i = blockIdx.x*256 + threadIdx.x;
    if (i >= NN) return;
    #pragma unroll
    for (int t=0;t<9;t++){
        int j = nbr[i*9+t];
        int gmin = t<3 ? 0 : (t<5 ? 1 : 2);
        for (int g=gmin; g<3; g++){
            int pos = atomicAdd(&cur[g*NN+j], 1);
            int rb = (g==0) ? 0 : (g==1 ? NN*3 : NN*8);
            rev[rb + offc[g*NN+j] + pos] = i;
        }
    }
}

// ---------- phase 3: GCN layer-1 input transform ----------
__global__ void k_y1(const float* __restrict__ x0, const float* __restrict__ Wg1,
                     float* __restrict__ xw){
    int idx = blockIdx.x*256 + threadIdx.x;
    if (idx >= NN*64) return;
    int n = idx>>6, c = idx&63;
    float acc = 0.f;
    #pragma unroll
    for (int k=0;k<8;k++) acc += x0[n*8+k]*Wg1[k*64+c];
    xw[idx] = acc;
}

// ---------- phase 3b: gather layer-1 + relu + layer-2 matmul ----------
__global__ __launch_bounds__(256) void k_h1y2(const float* __restrict__ xw,
        const int* __restrict__ offc,
        const int* __restrict__ cnt3, const int* __restrict__ cnt5, const int* __restrict__ cnt9,
        const int* __restrict__ rev, const float* __restrict__ dinvc,
        const float* __restrict__ bg1, const float* __restrict__ Wg2,
        float* __restrict__ y2){
    __shared__ float h1s[12][64];
    int n0 = blockIdx.x*4, tid = threadIdx.x;
    for (int s=tid; s<768; s+=256){
        int p = s>>6, k = s&63, g = p>>2, n = n0+(p&3);
        const int* cp = g==0?cnt3:(g==1?cnt5:cnt9);
        int rb = (g==0) ? 0 : (g==1 ? NN*3 : NN*8);
        int cnt = cp[n];
        int o = rb + offc[g*NN+n];
        float dv = dinvc[g*NN+n];
        float srow = dv*xw[n*64+k];
        for (int e=0;e<cnt;e++){
            int i = rev[o+e];
            srow += dinvc[g*NN+i]*xw[i*64+k];
        }
        float v = dv*srow + bg1[k];
        h1s[p][k] = v>0.f ? v : 0.f;
    }
    __syncthreads();
    int c = tid & 127, ph = tid>>7;
    float a6[6] = {0,0,0,0,0,0};
    for (int k=0;k<64;k++){
        float w = Wg2[k*128+c];
        #pragma unroll
        for (int q=0;q<6;q++) a6[q] += h1s[q*2+ph][k]*w;
    }
    #pragma unroll
    for (int q=0;q<6;q++){
        int p = q*2+ph, g = p>>2, n = n0+(p&3);
        float dv = dinvc[g*NN+n];
        y2[(size_t)g*NN*128 + (size_t)n*128 + c] = dv*a6[q];
    }
}

// ---------- phase 3c: gather layer-2 + bias + log_softmax ----------
__global__ __launch_bounds__(128) void k_fin(const float* __restrict__ y2,
        const int* __restrict__ offc,
        const int* __restrict__ cnt3, const int* __restrict__ cnt5, const int* __restrict__ cnt9,
        const int* __restrict__ rev, const float* __restrict__ dinvc,
        const float* __restrict__ bg2, float* __restrict__ emb){
    __shared__ float sm[2], ss[2];
    int b = blockIdx.x;
    int n = b & (NN-1), g = b >> 12;
    const int* cp = g==0?cnt3:(g==1?cnt5:cnt9);
    int rb = (g==0) ? 0 : (g==1 ? NN*3 : NN*8);
    int cnt = cp[n];
    int o = rb + offc[g*NN+n];
    float dv = dinvc[g*NN+n];
    int c = threadIdx.x;
    const float* yg = y2 + (size_t)g*NN*128;
    float s = yg[(size_t)n*128 + c];
    for (int e=0;e<cnt;e++){
        int i = rev[o+e];
        s += yg[(size_t)i*128 + c];
    }
    float v = dv*s + bg2[c];
    float m = v;
    #pragma unroll
    for (int st=1;st<64;st<<=1) m = fmaxf(m, __shfl_xor(m, st, 64));
    if ((c&63)==0) sm[c>>6] = m;
    __syncthreads();
    m = fmaxf(sm[0], sm[1]);
    float e = expf(v - m);
    float t = e;
    #pragma unroll
    for (int st=1;st<64;st<<=1) t += __shfl_xor(t, st, 64);
    if ((c&63)==0) ss[c>>6] = t;
    __syncthreads();
    t = ss[0]+ss[1];
    emb[n*384 + g*128 + c] = v - m - logf(t);
}

// ---------- phase 4: q/k projections -> bf16 hi/lo split ----------
__global__ __launch_bounds__(256) void k_qk(const float* __restrict__ emb,
        const float* __restrict__ Wq, const float* __restrict__ bq,
        const float* __restrict__ Wkey, const float* __restrict__ bkey,
        __bf16* __restrict__ qh, __bf16* __restrict__ ql,
        __bf16* __restrict__ kh, __bf16* __restrict__ kl){
    __shared__ float es[8][384];
    int n0 = blockIdx.x*8;
    int tid = threadIdx.x;
    for (int idx=tid; idx<8*384; idx+=256){
        int m = idx/384, k = idx%384;
        es[m][k] = emb[(n0+m)*384+k];
    }
    __syncthreads();
    int c = tid & 127;
    int sel = tid >> 7;
    const float* W = sel ? Wkey : Wq;
    float b = sel ? bkey[c] : bq[c];
    float acc[8];
    #pragma unroll
    for (int m=0;m<8;m++) acc[m]=b;
    for (int k=0;k<384;k++){
        float w = W[k*128+c];
        #pragma unroll
        for (int m=0;m<8;m++) acc[m] += es[m][k]*w;
    }
    __bf16* oh = sel ? kh : qh;
    __bf16* ol = sel ? kl : ql;
    #pragma unroll
    for (int m=0;m<8;m++){
        float v = acc[m];
        __bf16 h = (__bf16)v;
        oh[(size_t)(n0+m)*128+c] = h;
        ol[(size_t)(n0+m)*128+c] = (__bf16)(v - (float)h);
    }
}

// ---------- phase 5: scores = q @ k^T via bf16-split MFMA + fused row max/min ----------
__global__ __launch_bounds__(256) void k_scores(
        const __bf16* __restrict__ qh, const __bf16* __restrict__ ql,
        const __bf16* __restrict__ kh, const __bf16* __restrict__ kl,
        float* __restrict__ scores,
        unsigned* __restrict__ rowmaxenc, unsigned* __restrict__ rowminenc){
    int bx = blockIdx.x & 31;
    int by = blockIdx.x >> 5;
    int tid = threadIdx.x;
    int w = tid >> 6, lane = tid & 63;
    int li = lane & 15, g = lane >> 4;
    int r0 = by*128 + (w>>1)*64;
    int c0 = bx*128 + (w&1)*64;

    f32x4 acc[4][4] = {};
    for (int ks=0; ks<4; ++ks){
        int kofs = ks*32 + g*8;
        bf16x8 ah[4], al[4], bh[4], bl[4];
        #pragma unroll
        for (int f=0; f<4; ++f){
            ah[f] = *(const bf16x8*)&qh[(size_t)(r0+f*16+li)*128 + kofs];
            al[f] = *(const bf16x8*)&ql[(size_t)(r0+f*16+li)*128 + kofs];
            bh[f] = *(const bf16x8*)&kh[(size_t)(c0+f*16+li)*128 + kofs];
            bl[f] = *(const bf16x8*)&kl[(size_t)(c0+f*16+li)*128 + kofs];
        }
        #pragma unroll
        for (int fr=0; fr<4; ++fr){
            #pragma unroll
            for (int fc=0; fc<4; ++fc){
                acc[fr][fc] = __builtin_amdgcn_mfma_f32_16x16x32_bf16(ah[fr], bh[fc], acc[fr][fc], 0, 0, 0);
                acc[fr][fc] = __builtin_amdgcn_mfma_f32_16x16x32_bf16(ah[fr], bl[fc], acc[fr][fc], 0, 0, 0);
                acc[fr][fc] = __builtin_amdgcn_mfma_f32_16x16x32_bf16(al[fr], bh[fc], acc[fr][fc], 0, 0, 0);
            }
        }
    }
    #pragma unroll
    for (int fr=0; fr<4; ++fr){
        #pragma unroll
        for (int r=0; r<4; ++r){
            int row = r0 + fr*16 + g*4 + r;
            float mx = -INFINITY, mn = INFINITY;
            #pragma unroll
            for (int fc=0; fc<4; ++fc){
                float v = acc[fr][fc][r];
                scores[(size_t)row*NN + c0 + fc*16 + li] = v;
                mx = fmaxf(mx, v);
                mn = fminf(mn, v);
            }
            #pragma unroll
            for (int s=1; s<16; s<<=1){
                mx = fmaxf(mx, __shfl_xor(mx, s, 64));
                mn = fminf(mn, __shfl_xor(mn, s, 64));
            }
            if (li == 0){
                atomicMax(&rowmaxenc[row], enc_f(mx));
                atomicMin(&rowminenc[row], enc_f(mn));
            }
        }
    }
}

// ---------- phase 5b: invr = 1/rowmax ----------
__global__ void k_invr(const unsigned* __restrict__ rowmaxenc, float* __restrict__ invr){
    int i = blockIdx.x*256 + threadIdx.x;
    if (i >= NN) return;
    invr[i] = 1.f/dec_f(rowmaxenc[i]);
}

// ---------- phase 6: fused streaming pass over A:
//   conv min/max + per-row dots (A@Ot, A@Ty) -> hpart[row][strip][8]
// 4 cols/lane (float4), col stencil via 2 neighbor float4 shuffles,
// row stencil via depth-9 float4 register ring. 28 output rows/wave (36 streamed).
__global__ __launch_bounds__(256) void k_cfuse(const float* __restrict__ scores,
        const float* __restrict__ invr,
        const float* __restrict__ x0, const float* __restrict__ Ty,
        const float* __restrict__ Wcy3, const float* __restrict__ Wcx3,
        const float* __restrict__ Wcy5, const float* __restrict__ Wcx5,
        const float* __restrict__ Wcy9, const float* __restrict__ Wcx9,
        const float* __restrict__ bcy3, const float* __restrict__ bcx3,
        const float* __restrict__ bcy5, const float* __restrict__ bcx5,
        const float* __restrict__ bcy9, const float* __restrict__ bcx9,
        float* __restrict__ mnmx, float* __restrict__ hpart){
    __shared__ float smn[4], smx[4];
    int tid = threadIdx.x;
    int w = tid >> 6, lane = tid & 63;
    int strip = blockIdx.x;                       // 0..16, 248 output cols each
    int rb = blockIdx.y*4 + w;                    // row block, 28 rows each
    int i0 = rb*28;
    int colbase = strip*248 - 4 + lane*4;         // this lane's 4 cols
    bool lv = (colbase >= 0) && (colbase + 3 < NN);
    bool outLane = (lane >= 1) && (lane < 63) && lv;

    float wy3[3],wx3[3],wy5[5],wx5[5],wy9[9],wx9[9];
    #pragma unroll
    for (int t=0;t<3;t++){ wy3[t]=Wcy3[t]; wx3[t]=Wcx3[t]; }
    #pragma unroll
    for (int t=0;t<5;t++){ wy5[t]=Wcy5[t]; wx5[t]=Wcx5[t]; }
    #pragma unroll
    for (int t=0;t<9;t++){ wy9[t]=Wcy9[t]; wx9[t]=Wcx9[t]; }
    float bc3 = bcy3[0]+bcx3[0];
    float bc5 = bcy5[0]+bcx5[0];
    float bc9 = bcy9[0]+bcx9[0];

    // Ot / Ty for this lane's 4 cols
    float4 ot[4], ty[4];
    #pragma unroll
    for (int c=0;c<4;c++){
        if (lv){
            ot[c] = *(const float4*)&x0[(colbase+c)*8+4];
            ty[c] = *(const float4*)&Ty[(colbase+c)*4];
        } else {
            ot[c] = make_float4(0,0,0,0);
            ty[c] = make_float4(0,0,0,0);
        }
    }

    float4 win[9];
    float mn = INFINITY, mx = -INFINITY;
    const int laneL = lane - 1, laneR = lane + 1;

    for (int tb = 0; tb < 4; ++tb){
        #pragma unroll
        for (int u = 0; u < 9; ++u){
            int t  = tb*9 + u;
            int ri = i0 - 4 + t;
            float4 a = make_float4(0,0,0,0);
            if (((unsigned)ri < NN) && lv){
                float iv = invr[ri];
                float4 v = *(const float4*)&scores[(size_t)ri*NN + colbase];
                a.x = v.x*iv; a.y = v.y*iv; a.z = v.z*iv; a.w = v.w*iv;
            }
            win[u] = a;
            int ro = i0 + t - 8;
            if (t >= 8 && ro < NN){
                // center-row float4 (slot (u+5)%9) and its neighbors
                float4 ctr = win[(u+5)%9];
                float4 wl = shfl4(ctr, laneL);
                float4 wr = shfl4(ctr, laneR);
                float cw[12] = {wl.x,wl.y,wl.z,wl.w, ctr.x,ctr.y,ctr.z,ctr.w, wr.x,wr.y,wr.z,wr.w};
                float4 pA = make_float4(0,0,0,0), pT = make_float4(0,0,0,0);
                if (outLane){
                    #pragma unroll
                    for (int c=0;c<4;c++){
                        // row-axis convs (Wcx), taps from ring: row ro-4+k at slot (u+1+k)%9
                        float cx9 = ((win[(u+1)%9][c]*wx9[0] + win[(u+2)%9][c]*wx9[1]) + (win[(u+3)%9][c]*wx9[2] + win[(u+4)%9][c]*wx9[3]))
                                  + ((win[(u+5)%9][c]*wx9[4] + win[(u+6)%9][c]*wx9[5]) + (win[(u+7)%9][c]*wx9[6] + win[(u+8)%9][c]*wx9[7]))
                                  + win[u][c]*wx9[8];
                        float cx5 = ((win[(u+3)%9][c]*wx5[0] + win[(u+4)%9][c]*wx5[1]) + (win[(u+5)%9][c]*wx5[2] + win[(u+6)%9][c]*wx5[3]))
                                  + win[(u+7)%9][c]*wx5[4];
                        float cx3 = (win[(u+4)%9][c]*wx3[0] + win[(u+5)%9][c]*wx3[1]) + win[(u+6)%9][c]*wx3[2];
                        // col-axis convs (Wcy), window cw[c..c+8]
                        float cy9 = ((cw[c+0]*wy9[0] + cw[c+1]*wy9[1]) + (cw[c+2]*wy9[2] + cw[c+3]*wy9[3]))
                                  + ((cw[c+4]*wy9[4] + cw[c+5]*wy9[5]) + (cw[c+6]*wy9[6] + cw[c+7]*wy9[7]))
                                  + cw[c+8]*wy9[8];
                        float cy5 = ((cw[c+2]*wy5[0] + cw[c+3]*wy5[1]) + (cw[c+4]*wy5[2] + cw[c+5]*wy5[3]))
                                  + cw[c+6]*wy5[4];
                        float cy3 = (cw[c+3]*wy3[0] + cw[c+4]*wy3[1]) + cw[c+5]*wy3[2];
                        float c3v = cy3+cx3+bc3, c5v = cy5+cx5+bc5, c9v = cy9+cx9+bc9;
                        mn = fminf(mn, fminf(fminf(c3v,c5v),c9v));
                        mx = fmaxf(mx, fmaxf(fmaxf(c3v,c5v),c9v));
                        float av = cw[c+4];
                        pA.x += av*ot[c].x; pA.y += av*ot[c].y; pA.z += av*ot[c].z; pA.w += av*ot[c].w;
                        pT.x += av*ty[c].x; pT.y += av*ty[c].y; pT.z += av*ty[c].z; pT.w += av*ty[c].w;
                    }
                }
                // wave-reduce the 8 dot partials
                #pragma unroll
                for (int m=1; m<64; m<<=1){
                    pA.x += __shfl_xor(pA.x, m, 64); pA.y += __shfl_xor(pA.y, m, 64);
                    pA.z += __shfl_xor(pA.z, m, 64); pA.w += __shfl_xor(pA.w, m, 64);
                    pT.x += __shfl_xor(pT.x, m, 64); pT.y += __shfl_xor(pT.y, m, 64);
                    pT.z += __shfl_xor(pT.z, m, 64); pT.w += __shfl_xor(pT.w, m, 64);
                }
                if (lane == 0){
                    float* hp = &hpart[((size_t)ro*17 + strip)*8];
                    *(float4*)hp = pA;
                    *(float4*)(hp+4) = pT;
                }
            }
        }
    }
    #pragma unroll
    for (int m=1; m<64; m<<=1){
        mn = fminf(mn, __shfl_xor(mn, m, 64));
        mx = fmaxf(mx, __shfl_xor(mx, m, 64));
    }
    if (lane == 0){ smn[w] = mn; smx[w] = mx; }
    __syncthreads();
    if (tid == 0){
        float a0 = fminf(fminf(smn[0],smn[1]), fminf(smn[2],smn[3]));
        float b0 = fmaxf(fmaxf(smx[0],smx[1]), fmaxf(smx[2],smx[3]));
        int bid = blockIdx.y*gridDim.x + blockIdx.x;
        mnmx[bid] = a0;
        mnmx[640 + bid] = b0;
    }
}

// ---------- phase 6b: global min/max = conv blocks U A-range U {0,1} ----------
__global__ __launch_bounds__(256) void k_gmm(const float* __restrict__ mnmx,
        const unsigned* __restrict__ rowminenc, const unsigned* __restrict__ rowmaxenc,
        float* __restrict__ gmm){
    __shared__ float smn[256], smx[256];
    int tid = threadIdx.x;
    float mn = 0.f, mx = 1.f;   // oushi range is exactly [0,1]
    for (int i=tid; i<NN; i+=256){
        float rmx = dec_f(rowmaxenc[i]);
        float q = dec_f(rowminenc[i]) / rmx;
        mn = fminf(mn, fminf(1.f, q));
        mx = fmaxf(mx, fmaxf(1.f, q));
    }
    for (int b=tid; b<629; b+=256){   // 17 x 37 blocks
        mn = fminf(mn, mnmx[b]);
        mx = fmaxf(mx, mnmx[640+b]);
    }
    smn[tid]=mn; smx[tid]=mx; __syncthreads();
    for (int s=128;s>0;s>>=1){
        if (tid<s){ smn[tid]=fminf(smn[tid],smn[tid+s]); smx[tid]=fmaxf(smx[tid],smx[tid+s]); }
        __syncthreads();
    }
    if (tid==0){ gmm[0]=smn[0]; gmm[1]=smx[0]; }
}

// ---------- phase 7a: reduce strip partials -> ASd, Bv ----------
__global__ void k_hred(const float* __restrict__ hpart,
        const float* __restrict__ maxd, const float* __restrict__ dOt,
        const float* __restrict__ colsum,
        const float* __restrict__ bcy3, const float* __restrict__ bcx3,
        const float* __restrict__ bcy5, const float* __restrict__ bcx5,
        const float* __restrict__ bcy9, const float* __restrict__ bcx9,
        float* __restrict__ ASdot, float* __restrict__ Bv){
    int i = blockIdx.x*256 + threadIdx.x;
    if (i >= NN) return;
    float4 pa = {0,0,0,0}, pt = {0,0,0,0};
    const float* hp = &hpart[(size_t)i*17*8];
    #pragma unroll
    for (int s=0; s<17; ++s){
        float4 a = *(const float4*)&hp[s*8];
        float4 t = *(const float4*)&hp[s*8+4];
        pa.x+=a.x; pa.y+=a.y; pa.z+=a.z; pa.w+=a.w;
        pt.x+=t.x; pt.y+=t.y; pt.z+=t.z; pt.w+=t.w;
    }
    float imv = 1.f/maxd[i];
    float bcsum = bcy3[0]+bcx3[0]+bcy5[0]+bcx5[0]+bcy9[0]+bcx9[0];
    float k = 1.f + bcsum;
    float4 cs = *(const float4*)colsum;
    float4 dv = *(const float4*)&dOt[i*4];
    float4 b;
    b.x = cs.x*k - imv*dv.x + pt.x;
    b.y = cs.y*k - imv*dv.y + pt.y;
    b.z = cs.z*k - imv*dv.z + pt.z;
    b.w = cs.w*k - imv*dv.w + pt.w;
    *(float4*)&ASdot[i*4] = pa;
    *(float4*)&Bv[i*4]    = b;
}

// ---------- phase 7b: row-conv of ASdot + affine -> hfin ----------
__global__ void k_hfin(const float* __restrict__ ASdot, const float* __restrict__ Bv,
        const float* __restrict__ Wcx3, const float* __restrict__ Wcx5, const float* __restrict__ Wcx9,
        const float* __restrict__ gmm, const float* __restrict__ colsum,
        float* __restrict__ hfin){
    int i = blockIdx.x*256 + threadIdx.x;
    if (i >= NN) return;
    float Cx[9];
    #pragma unroll
    for (int o=-4;o<=4;o++){
        float c = Wcx9[o+4];
        if (o>=-2 && o<=2) c += Wcx5[o+2];
        if (o>=-1 && o<=1) c += Wcx3[o+1];
        Cx[o+4] = c;
    }
    float4 h = *(const float4*)&Bv[i*4];
    float4 a0 = *(const float4*)&ASdot[i*4];
    h.x += a0.x; h.y += a0.y; h.z += a0.z; h.w += a0.w;
    #pragma unroll
    for (int o=-4;o<=4;o++){
        int r = i + o;
        if ((unsigned)r < NN){
            float4 av = *(const float4*)&ASdot[r*4];
            float c = Cx[o+4];
            h.x += c*av.x; h.y += c*av.y; h.z += c*av.z; h.w += c*av.w;
        }
    }
    float mnv = gmm[0], mxv = gmm[1];
    float s = 1.f/(mxv-mnv), oa = -mnv*s;
    float4 cs = *(const float4*)colsum;
    float4 out;
    out.x = s*h.x + 5.f*oa*cs.x;
    out.y = s*h.y + 5.f*oa*cs.y;
    out.z = s*h.z + 5.f*oa*cs.z;
    out.w = s*h.w + 5.f*oa*cs.w;
    *(float4*)&hfin[i*4] = out;
}

// ---------- phase 7c: MLP head ----------
__global__ __launch_bounds__(256) void k_mlp(const float* __restrict__ hfin,
        const float* __restrict__ Woff, const float* __restrict__ boff, const float* __restrict__ pw,
        const float* __restrict__ Wf1, const float* __restrict__ bf1,
        const float* __restrict__ Wf2, const float* __restrict__ bf2,
        const float* __restrict__ Wf3, const float* __restrict__ bf3,
        float* __restrict__ out){
    __shared__ float h1[8][128];
    __shared__ float h2[8][256];
    __shared__ float h3[8][256];
    __shared__ float4 red4[256];
    int n0 = blockIdx.x*8, tid = threadIdx.x;
    float p = pw[0];
    {
        int c = tid & 127, mb = (tid>>7)*4;
        #pragma unroll
        for (int mm=0; mm<4; mm++){
            int m = mb+mm;
            float v = boff[c];
            #pragma unroll
            for (int k=0;k<4;k++) v += hfin[(n0+m)*4+k]*Woff[k*128+c];
            h1[m][c] = v>0.f ? v : p*v;
        }
    }
    __syncthreads();
    {
        int c = tid;
        float acc[8];
        #pragma unroll
        for (int m=0;m<8;m++) acc[m] = bf1[c];
        for (int k=0;k<128;k++){
            float w = Wf1[k*256+c];
            #pragma unroll
            for (int m=0;m<8;m++) acc[m] += h1[m][k]*w;
        }
        #pragma unroll
        for (int m=0;m<8;m++) h2[m][c] = acc[m]>0.f?acc[m]:0.f;
    }
    __syncthreads();
    {
        int c = tid;
        float acc[8];
        #pragma unroll
        for (int m=0;m<8;m++) acc[m] = bf2[c];
        for (int k=0;k<256;k++){
            float w = Wf2[k*256+c];
            #pragma unroll
            for (int m=0;m<8;m++) acc[m] += h2[m][k]*w;
        }
        #pragma unroll
        for (int m=0;m<8;m++) h3[m][c] = acc[m]>0.f?acc[m]:0.f;
    }
    __syncthreads();
    float w3_0 = Wf3[tid*4+0], w3_1 = Wf3[tid*4+1], w3_2 = Wf3[tid*4+2], w3_3 = Wf3[tid*4+3];
    for (int m=0;m<8;m++){
        float hv = h3[m][tid];
        float4 r; r.x = hv*w3_0; r.y = hv*w3_1; r.z = hv*w3_2; r.w = hv*w3_3;
        red4[tid]=r; __syncthreads();
        for (int s=128;s>0;s>>=1){
            if(tid<s){
                red4[tid].x+=red4[tid+s].x; red4[tid].y+=red4[tid+s].y;
                red4[tid].z+=red4[tid+s].z; red4[tid].w+=red4[tid+s].w;
            }
            __syncthreads();
        }
        if (tid==0){
            float4 o;
            o.x = red4[0].x + bf3[0]; o.y = red4[0].y + bf3[1];
            o.z = red4[0].z + bf3[2]; o.w = red4[0].w + bf3[3];
            *(float4*)&out[(n0+m)*4] = o;
        }
        __syncthreads();
    }
}

// ---------- host ----------
extern "C" void kernel_launch(void* const* d_in, const int* in_sizes, int n_in,
                              void* d_out, int out_size, void* d_ws, size_t ws_size,
                              hipStream_t stream){
    const float* dx1  = (const float*)d_in[0];
    const float* dx2  = (const float*)d_in[1];
    const float* Wk   = (const float*)d_in[2];
    const float* bk   = (const float*)d_in[3];
    const float* Wg1  = (const float*)d_in[4];
    const float* bg1  = (const float*)d_in[5];
    const float* Wg2  = (const float*)d_in[6];
    const float* bg2  = (const float*)d_in[7];
    const float* Wq   = (const float*)d_in[8];
    const float* bq   = (const float*)d_in[9];
    const float* Wkey = (const float*)d_in[10];
    const float* bkey = (const float*)d_in[11];
    const float* Woff = (const float*)d_in[12];
    const float* boff = (const float*)d_in[13];
    const float* pw   = (const float*)d_in[14];
    const float* Wf1  = (const float*)d_in[15];
    const float* bf1  = (const float*)d_in[16];
    const float* Wf2  = (const float*)d_in[17];
    const float* bf2  = (const float*)d_in[18];
    const float* Wf3  = (const float*)d_in[19];
    const float* bf3  = (const float*)d_in[20];
    const float* Wcy3 = (const float*)d_in[21];
    const float* bcy3 = (const float*)d_in[22];
    const float* Wcx3 = (const float*)d_in[23];
    const float* bcx3 = (const float*)d_in[24];
    const float* Wcy5 = (const float*)d_in[25];
    const float* bcy5 = (const float*)d_in[26];
    const float* Wcx5 = (const float*)d_in[27];
    const float* bcx5 = (const float*)d_in[28];
    const float* Wcy9 = (const float*)d_in[29];
    const float* bcy9 = (const float*)d_in[30];
    const float* Wcx9 = (const float*)d_in[31];
    const float* bcx9 = (const float*)d_in[32];

    char* ws = (char*)d_ws;
    size_t off = 0;
    auto alloc = [&](size_t b)->void*{ void* p = ws + off; off += (b + 255) & ~(size_t)255; return p; };

    // --- zero-init region (one small memset) ---
    char* zbase = ws + off;
    float*    colsum    = (float*)   alloc(4*4);
    int*      cnt3      = (int*)     alloc((size_t)NN*4);
    int*      cnt5      = (int*)     alloc((size_t)NN*4);
    int*      cnt9      = (int*)     alloc((size_t)NN*4);
    int*      cur       = (int*)     alloc((size_t)3*NN*4);
    unsigned* rowmaxenc = (unsigned*)alloc((size_t)NN*4);
    size_t zbytes = (size_t)((ws + off) - zbase);
    unsigned* rowminenc = (unsigned*)alloc((size_t)NN*4);   // memset 0xFF

    // --- non-zeroed ---
    float* x0     = (float*)alloc((size_t)NN*8*4);
    float* maxd   = (float*)alloc((size_t)NN*4);
    int*   nbr    = (int*)  alloc((size_t)NN*9*4);
    int*   offc   = (int*)  alloc((size_t)3*NN*4);
    float* dinvc  = (float*)alloc((size_t)3*NN*4);
    int*   rev    = (int*)  alloc((size_t)NN*17*4);
    float* xw     = (float*)alloc((size_t)NN*64*4);
    float* y2     = (float*)alloc((size_t)3*NN*128*4);
    float* emb    = (float*)alloc((size_t)NN*384*4);
    __bf16* qh   = (__bf16*)alloc((size_t)NN*128*2);
    __bf16* ql   = (__bf16*)alloc((size_t)NN*128*2);
    __bf16* kh   = (__bf16*)alloc((size_t)NN*128*2);
    __bf16* kl   = (__bf16*)alloc((size_t)NN*128*2);
    float* scores = (float*)alloc((size_t)NN*NN*4);
    float* Tyb    = (float*)alloc((size_t)NN*4*4);
    float* invr   = (float*)alloc((size_t)NN*4);
    float* dOt    = (float*)alloc((size_t)NN*4*4);
    float* ASd    = (float*)alloc((size_t)NN*4*4);
    float* Bv     = (float*)alloc((size_t)NN*4*4);
    float* hpart  = (float*)alloc((size_t)NN*17*8*4);
    float* mnmx   = (float*)alloc((size_t)2*640*4);
    float* gmm    = (float*)alloc(2*4);
    float* hfin   = (float*)alloc((size_t)NN*4*4);
    (void)ws_size; (void)in_sizes; (void)n_in; (void)out_size;

    hipMemsetAsync(zbase, 0, zbytes, stream);
    hipMemsetAsync(rowminenc, 0xFF, (size_t)NN*4, stream);

    k_prep<<<16,256,0,stream>>>(dx1,dx2,Wk,bk,x0,colsum);
    k_ty  <<<16,256,0,stream>>>(x0,Wcy3,Wcy5,Wcy9,Tyb);
    k_dist<<<NN/4,256,0,stream>>>(dx1,x0,maxd,nbr,cnt3,cnt5,cnt9,dOt);
    k_scan<<<1,256,0,stream>>>(cnt3,cnt5,cnt9,offc,dinvc);
    k_fill<<<16,256,0,stream>>>(nbr,offc,cur,rev);

    k_y1  <<<NN*64/256,256,0,stream>>>(x0,Wg1,xw);
    k_h1y2<<<NN/4,256,0,stream>>>(xw,offc,cnt3,cnt5,cnt9,rev,dinvc,bg1,Wg2,y2);
    k_fin <<<NN*3,128,0,stream>>>(y2,offc,cnt3,cnt5,cnt9,rev,dinvc,bg2,emb);

    k_qk<<<NN/8,256,0,stream>>>(emb,Wq,bq,Wkey,bkey,qh,ql,kh,kl);
    k_scores<<<1024,256,0,stream>>>(qh,ql,kh,kl,scores,rowmaxenc,rowminenc);
    k_invr<<<16,256,0,stream>>>(rowmaxenc,invr);

    k_cfuse<<<dim3(17,37),256,0,stream>>>(scores,invr,x0,Tyb,
        Wcy3,Wcx3,Wcy5,Wcx5,Wcy9,Wcx9,
        bcy3,bcx3,bcy5,bcx5,bcy9,bcx9, mnmx, hpart);
    k_gmm<<<1,256,0,stream>>>(mnmx,rowminenc,rowmaxenc,gmm);
    k_hred<<<16,256,0,stream>>>(hpart,maxd,dOt,colsum,
        bcy3,bcx3,bcy5,bcx5,bcy9,bcx9, ASd, Bv);
    k_hfin<<<16,256,0,stream>>>(ASd,Bv,Wcx3,Wcx5,Wcx9,gmm,colsum,hfin);
    k_mlp<<<NN/8,256,0,stream>>>(hfin,Woff,boff,pw,Wf1,bf1,Wf2,bf2,Wf3,bf3,(float*)d_out);
}

// Round 11
// 309.922 us; speedup vs baseline: 1.3139x; 1.0793x over previous
//
#include <hip/hip_runtime.h>
#include <math.h>

#define NN 4096

typedef __bf16 bf16x8 __attribute__((ext_vector_type(8)));
typedef float  f32x4  __attribute__((ext_vector_type(4)));

static __device__ __forceinline__ unsigned enc_f(float f){
    unsigned u = __float_as_uint(f);
    return (u & 0x80000000u) ? ~u : (u | 0x80000000u);
}
static __device__ __forceinline__ float dec_f(unsigned u){
    unsigned b = (u & 0x80000000u) ? (u & 0x7fffffffu) : ~u;
    return __uint_as_float(b);
}
static __device__ __forceinline__ float4 shfl4(float4 v, int src){
    float4 r;
    r.x = __shfl(v.x, src, 64);
    r.y = __shfl(v.y, src, 64);
    r.z = __shfl(v.z, src, 64);
    r.w = __shfl(v.w, src, 64);
    return r;
}

// ---------- phase 1: x0 assembly + Ot column sums ----------
__global__ void k_prep(const float* __restrict__ dx1, const float* __restrict__ dx2,
                       const float* __restrict__ Wk, const float* __restrict__ bk,
                       float* __restrict__ x0, float* __restrict__ colsum){
    int n = blockIdx.x*blockDim.x + threadIdx.x;
    if (n >= NN) return;
    float wk[8];
    #pragma unroll
    for (int j=0;j<8;j++) wk[j] = Wk[j];
    float bkv = bk[0];
    #pragma unroll
    for (int c=0;c<4;c++) x0[n*8+c] = dx1[n*4+c];
    #pragma unroll
    for (int c=0;c<4;c++){
        float acc = bkv;
        #pragma unroll
        for (int j=0;j<8;j++) acc += dx2[(n*8+j)*4+c]*wk[j];
        x0[n*8+4+c] = acc;
        atomicAdd(&colsum[c], acc);
    }
}

// ---------- phase 1b: Ty[j] = column-conv kernel applied to Ot ----------
__global__ void k_ty(const float* __restrict__ x0,
        const float* __restrict__ Wcy3, const float* __restrict__ Wcy5, const float* __restrict__ Wcy9,
        float* __restrict__ Ty){
    int j = blockIdx.x*256 + threadIdx.x;
    if (j >= NN) return;
    float Cy[9];
    #pragma unroll
    for (int o=-4;o<=4;o++){
        float c = Wcy9[o+4];
        if (o>=-2 && o<=2) c += Wcy5[o+2];
        if (o>=-1 && o<=1) c += Wcy3[o+1];
        Cy[o+4] = c;
    }
    float4 acc = {0,0,0,0};
    #pragma unroll
    for (int o=-4;o<=4;o++){
        int jj = j - o;
        if ((unsigned)jj < NN){
            float4 ot = *(const float4*)&x0[jj*8+4];
            float c = Cy[o+4];
            acc.x += c*ot.x; acc.y += c*ot.y; acc.z += c*ot.z; acc.w += c*ot.w;
        }
    }
    *(float4*)&Ty[j*4] = acc;
}

// ---------- phase 2: row max dist + top-9 knn + in-deg counts + dOt ----------
__global__ __launch_bounds__(256) void k_dist(const float* __restrict__ dx1,
        const float* __restrict__ x0,
        float* __restrict__ maxd, int* __restrict__ nbr,
        int* __restrict__ cnt3, int* __restrict__ cnt5, int* __restrict__ cnt9,
        float* __restrict__ dOt){
    __shared__ float2 ps[NN];
    int tid = threadIdx.x;
    for (int j=tid; j<NN; j+=256){
        float4 v = *(const float4*)&dx1[j*4];
        ps[j] = make_float2(v.x, v.y);
    }
    __syncthreads();
    int lane = tid & 63;
    int i = blockIdx.x*4 + (tid>>6);
    float2 pi = ps[i];
    unsigned long long best[9];
    #pragma unroll
    for (int q=0;q<9;q++) best[q] = ~0ULL;
    float lmax = 0.f;
    float4 dacc = {0,0,0,0};
    for (int t=0;t<64;t++){
        int j = (t<<6) | lane;
        float2 p = ps[j];
        float dx = pi.x - p.x, dy = pi.y - p.y;
        float d = sqrtf(dx*dx + dy*dy);
        lmax = fmaxf(lmax, d);
        float4 otj = *(const float4*)&x0[j*8+4];
        dacc.x += d*otj.x; dacc.y += d*otj.y; dacc.z += d*otj.z; dacc.w += d*otj.w;
        unsigned long long cand = ((unsigned long long)__float_as_uint(d) << 32) | (unsigned)j;
        if (j != i && cand < best[8]){
            best[8] = cand;
            #pragma unroll
            for (int q=8; q>0; --q){
                if (best[q] < best[q-1]){ unsigned long long tm=best[q]; best[q]=best[q-1]; best[q-1]=tm; }
            }
        }
    }
    #pragma unroll
    for (int m=1;m<64;m<<=1){
        lmax = fmaxf(lmax, __shfl_xor(lmax, m, 64));
        dacc.x += __shfl_xor(dacc.x, m, 64);
        dacc.y += __shfl_xor(dacc.y, m, 64);
        dacc.z += __shfl_xor(dacc.z, m, 64);
        dacc.w += __shfl_xor(dacc.w, m, 64);
    }
    if (lane==0){
        maxd[i] = lmax;
        *(float4*)&dOt[i*4] = dacc;
    }
    for (int t=0;t<9;t++){
        unsigned long long w = best[0];
        #pragma unroll
        for (int m=1;m<64;m<<=1){
            unsigned long long o = __shfl_xor(w, m, 64);
            if (o < w) w = o;
        }
        if (best[0] == w){
            #pragma unroll
            for (int q=0;q<8;q++) best[q] = best[q+1];
            best[8] = ~0ULL;
        }
        if (lane==0){
            int j = (int)(w & 0xffffffffu);
            nbr[i*9+t] = j;
            atomicAdd(&cnt9[j], 1);
            if (t<5) atomicAdd(&cnt5[j], 1);
            if (t<3) atomicAdd(&cnt3[j], 1);
        }
    }
}

// ---------- phase 2b: CSR offsets (exclusive scan) + dinv ----------
__global__ __launch_bounds__(256) void k_scan(const int* __restrict__ cnt3,
        const int* __restrict__ cnt5, const int* __restrict__ cnt9,
        int* __restrict__ offc, float* __restrict__ dinvc){
    __shared__ int part[256];
    int tid = threadIdx.x;
    for (int g=0; g<3; g++){
        const int* cp = g==0?cnt3:(g==1?cnt5:cnt9);
        int base = tid*16;
        int loc[16]; int s=0;
        #pragma unroll
        for (int q=0;q<16;q++){ loc[q]=s; s += cp[base+q]; }
        part[tid]=s; __syncthreads();
        for (int d=1; d<256; d<<=1){
            int v = (tid>=d) ? part[tid-d] : 0;
            __syncthreads();
            part[tid] += v;
            __syncthreads();
        }
        int pre = (tid==0) ? 0 : part[tid-1];
        #pragma unroll
        for (int q=0;q<16;q++){
            offc[g*NN + base + q]  = pre + loc[q];
            dinvc[g*NN + base + q] = rsqrtf((float)cp[base+q] + 1.f);
        }
        __syncthreads();
    }
}

// ---------- phase 2c: fill reverse-edge lists ----------
__global__ void k_fill(const int* __restrict__ nbr, const int* __restrict__ offc,
        int* __restrict__ cur, int* __restrict__ rev){
    int i = blockIdx.x*256 + threadIdx.x;
    if (i >= NN) return;
    #pragma unroll
    for (int t=0;t<9;t++){
        int j = nbr[i*9+t];
        int gmin = t<3 ? 0 : (t<5 ? 1 : 2);
        for (int g=gmin; g<3; g++){
            int pos = atomicAdd(&cur[g*NN+j], 1);
            int rb = (g==0) ? 0 : (g==1 ? NN*3 : NN*8);
            rev[rb + offc[g*NN+j] + pos] = i;
        }
    }
}

// ---------- phase 3: GCN layer-1 input transform ----------
__global__ void k_y1(const float* __restrict__ x0, const float* __restrict__ Wg1,
                     float* __restrict__ xw){
    int idx = blockIdx.x*256 + threadIdx.x;
    if (idx >= NN*64) return;
    int n = idx>>6, c = idx&63;
    float acc = 0.f;
    #pragma unroll
    for (int k=0;k<8;k++) acc += x0[n*8+k]*Wg1[k*64+c];
    xw[idx] = acc;
}

// ---------- phase 3b: gather layer-1 + relu + layer-2 matmul ----------
__global__ __launch_bounds__(256) void k_h1y2(const float* __restrict__ xw,
        const int* __restrict__ offc,
        const int* __restrict__ cnt3, const int* __restrict__ cnt5, const int* __restrict__ cnt9,
        const int* __restrict__ rev, const float* __restrict__ dinvc,
        const float* __restrict__ bg1, const float* __restrict__ Wg2,
        float* __restrict__ y2){
    __shared__ float h1s[12][64];
    int n0 = blockIdx.x*4, tid = threadIdx.x;
    for (int s=tid; s<768; s+=256){
        int p = s>>6, k = s&63, g = p>>2, n = n0+(p&3);
        const int* cp = g==0?cnt3:(g==1?cnt5:cnt9);
        int rb = (g==0) ? 0 : (g==1 ? NN*3 : NN*8);
        int cnt = cp[n];
        int o = rb + offc[g*NN+n];
        float dv = dinvc[g*NN+n];
        float srow = dv*xw[n*64+k];
        for (int e=0;e<cnt;e++){
            int i = rev[o+e];
            srow += dinvc[g*NN+i]*xw[i*64+k];
        }
        float v = dv*srow + bg1[k];
        h1s[p][k] = v>0.f ? v : 0.f;
    }
    __syncthreads();
    int c = tid & 127, ph = tid>>7;
    float a6[6] = {0,0,0,0,0,0};
    for (int k=0;k<64;k++){
        float w = Wg2[k*128+c];
        #pragma unroll
        for (int q=0;q<6;q++) a6[q] += h1s[q*2+ph][k]*w;
    }
    #pragma unroll
    for (int q=0;q<6;q++){
        int p = q*2+ph, g = p>>2, n = n0+(p&3);
        float dv = dinvc[g*NN+n];
        y2[(size_t)g*NN*128 + (size_t)n*128 + c] = dv*a6[q];
    }
}

// ---------- phase 3c: gather layer-2 + bias + log_softmax ----------
__global__ __launch_bounds__(128) void k_fin(const float* __restrict__ y2,
        const int* __restrict__ offc,
        const int* __restrict__ cnt3, const int* __restrict__ cnt5, const int* __restrict__ cnt9,
        const int* __restrict__ rev, const float* __restrict__ dinvc,
        const float* __restrict__ bg2, float* __restrict__ emb){
    __shared__ float sm[2], ss[2];
    int b = blockIdx.x;
    int n = b & (NN-1), g = b >> 12;
    const int* cp = g==0?cnt3:(g==1?cnt5:cnt9);
    int rb = (g==0) ? 0 : (g==1 ? NN*3 : NN*8);
    int cnt = cp[n];
    int o = rb + offc[g*NN+n];
    float dv = dinvc[g*NN+n];
    int c = threadIdx.x;
    const float* yg = y2 + (size_t)g*NN*128;
    float s = yg[(size_t)n*128 + c];
    for (int e=0;e<cnt;e++){
        int i = rev[o+e];
        s += yg[(size_t)i*128 + c];
    }
    float v = dv*s + bg2[c];
    float m = v;
    #pragma unroll
    for (int st=1;st<64;st<<=1) m = fmaxf(m, __shfl_xor(m, st, 64));
    if ((c&63)==0) sm[c>>6] = m;
    __syncthreads();
    m = fmaxf(sm[0], sm[1]);
    float e = expf(v - m);
    float t = e;
    #pragma unroll
    for (int st=1;st<64;st<<=1) t += __shfl_xor(t, st, 64);
    if ((c&63)==0) ss[c>>6] = t;
    __syncthreads();
    t = ss[0]+ss[1];
    emb[n*384 + g*128 + c] = v - m - logf(t);
}

// ---------- phase 4: q/k projections -> bf16 hi/lo split ----------
__global__ __launch_bounds__(256) void k_qk(const float* __restrict__ emb,
        const float* __restrict__ Wq, const float* __restrict__ bq,
        const float* __restrict__ Wkey, const float* __restrict__ bkey,
        __bf16* __restrict__ qh, __bf16* __restrict__ ql,
        __bf16* __restrict__ kh, __bf16* __restrict__ kl){
    __shared__ float es[8][384];
    int n0 = blockIdx.x*8;
    int tid = threadIdx.x;
    for (int idx=tid; idx<8*384; idx+=256){
        int m = idx/384, k = idx%384;
        es[m][k] = emb[(n0+m)*384+k];
    }
    __syncthreads();
    int c = tid & 127;
    int sel = tid >> 7;
    const float* W = sel ? Wkey : Wq;
    float b = sel ? bkey[c] : bq[c];
    float acc[8];
    #pragma unroll
    for (int m=0;m<8;m++) acc[m]=b;
    for (int k=0;k<384;k++){
        float w = W[k*128+c];
        #pragma unroll
        for (int m=0;m<8;m++) acc[m] += es[m][k]*w;
    }
    __bf16* oh = sel ? kh : qh;
    __bf16* ol = sel ? kl : ql;
    #pragma unroll
    for (int m=0;m<8;m++){
        float v = acc[m];
        __bf16 h = (__bf16)v;
        oh[(size_t)(n0+m)*128+c] = h;
        ol[(size_t)(n0+m)*128+c] = (__bf16)(v - (float)h);
    }
}

// ---------- phase 5: scores = q @ k^T via bf16-split MFMA + fused row max/min ----------
__global__ __launch_bounds__(256) void k_scores(
        const __bf16* __restrict__ qh, const __bf16* __restrict__ ql,
        const __bf16* __restrict__ kh, const __bf16* __restrict__ kl,
        float* __restrict__ scores,
        unsigned* __restrict__ rowmaxenc, unsigned* __restrict__ rowminenc){
    int bx = blockIdx.x & 31;
    int by = blockIdx.x >> 5;
    int tid = threadIdx.x;
    int w = tid >> 6, lane = tid & 63;
    int li = lane & 15, g = lane >> 4;
    int r0 = by*128 + (w>>1)*64;
    int c0 = bx*128 + (w&1)*64;

    f32x4 acc[4][4] = {};
    for (int ks=0; ks<4; ++ks){
        int kofs = ks*32 + g*8;
        bf16x8 ah[4], al[4], bh[4], bl[4];
        #pragma unroll
        for (int f=0; f<4; ++f){
            ah[f] = *(const bf16x8*)&qh[(size_t)(r0+f*16+li)*128 + kofs];
            al[f] = *(const bf16x8*)&ql[(size_t)(r0+f*16+li)*128 + kofs];
            bh[f] = *(const bf16x8*)&kh[(size_t)(c0+f*16+li)*128 + kofs];
            bl[f] = *(const bf16x8*)&kl[(size_t)(c0+f*16+li)*128 + kofs];
        }
        #pragma unroll
        for (int fr=0; fr<4; ++fr){
            #pragma unroll
            for (int fc=0; fc<4; ++fc){
                acc[fr][fc] = __builtin_amdgcn_mfma_f32_16x16x32_bf16(ah[fr], bh[fc], acc[fr][fc], 0, 0, 0);
                acc[fr][fc] = __builtin_amdgcn_mfma_f32_16x16x32_bf16(ah[fr], bl[fc], acc[fr][fc], 0, 0, 0);
                acc[fr][fc] = __builtin_amdgcn_mfma_f32_16x16x32_bf16(al[fr], bh[fc], acc[fr][fc], 0, 0, 0);
            }
        }
    }
    #pragma unroll
    for (int fr=0; fr<4; ++fr){
        #pragma unroll
        for (int r=0; r<4; ++r){
            int row = r0 + fr*16 + g*4 + r;
            float mx = -INFINITY, mn = INFINITY;
            #pragma unroll
            for (int fc=0; fc<4; ++fc){
                float v = acc[fr][fc][r];
                scores[(size_t)row*NN + c0 + fc*16 + li] = v;
                mx = fmaxf(mx, v);
                mn = fminf(mn, v);
            }
            #pragma unroll
            for (int s=1; s<16; s<<=1){
                mx = fmaxf(mx, __shfl_xor(mx, s, 64));
                mn = fminf(mn, __shfl_xor(mn, s, 64));
            }
            if (li == 0){
                atomicMax(&rowmaxenc[row], enc_f(mx));
                atomicMin(&rowminenc[row], enc_f(mn));
            }
        }
    }
}

// ---------- phase 5b: invr = 1/rowmax ----------
__global__ void k_invr(const unsigned* __restrict__ rowmaxenc, float* __restrict__ invr){
    int i = blockIdx.x*256 + threadIdx.x;
    if (i >= NN) return;
    invr[i] = 1.f/dec_f(rowmaxenc[i]);
}

// ---------- phase 6: streaming conv min/max over A, float4/lane, no dots ----------
// wave: 248 output cols (lanes 1..62 x4), 19 output rows (stream 27 = 3 ring periods)
__global__ __launch_bounds__(256) void k_cconv(const float* __restrict__ scores,
        const float* __restrict__ invr,
        const float* __restrict__ Wcy3, const float* __restrict__ Wcx3,
        const float* __restrict__ Wcy5, const float* __restrict__ Wcx5,
        const float* __restrict__ Wcy9, const float* __restrict__ Wcx9,
        const float* __restrict__ bcy3, const float* __restrict__ bcx3,
        const float* __restrict__ bcy5, const float* __restrict__ bcx5,
        const float* __restrict__ bcy9, const float* __restrict__ bcx9,
        float* __restrict__ mnmx){
    __shared__ float smn[4], smx[4];
    int tid = threadIdx.x;
    int w = tid >> 6, lane = tid & 63;
    int strip = blockIdx.x;                       // 0..16
    int i0 = (blockIdx.y*4 + w)*19;
    int colbase = strip*248 - 4 + lane*4;
    bool lv = (colbase >= 0) && (colbase + 3 < NN);
    bool outLane = (lane >= 1) && (lane < 63) && lv;

    float wy3[3],wx3[3],wy5[5],wx5[5],wy9[9],wx9[9];
    #pragma unroll
    for (int t=0;t<3;t++){ wy3[t]=Wcy3[t]; wx3[t]=Wcx3[t]; }
    #pragma unroll
    for (int t=0;t<5;t++){ wy5[t]=Wcy5[t]; wx5[t]=Wcx5[t]; }
    #pragma unroll
    for (int t=0;t<9;t++){ wy9[t]=Wcy9[t]; wx9[t]=Wcx9[t]; }
    float bc3 = bcy3[0]+bcx3[0];
    float bc5 = bcy5[0]+bcx5[0];
    float bc9 = bcy9[0]+bcx9[0];

    float4 win[9];
    float mn = INFINITY, mx = -INFINITY;
    const int laneL = lane - 1, laneR = lane + 1;

    for (int tb = 0; tb < 3; ++tb){
        #pragma unroll
        for (int u = 0; u < 9; ++u){
            int t  = tb*9 + u;
            int ri = i0 - 4 + t;
            float4 a = make_float4(0,0,0,0);
            if (((unsigned)ri < NN) && lv){
                float iv = invr[ri];
                float4 v = *(const float4*)&scores[(size_t)ri*NN + colbase];
                a.x = v.x*iv; a.y = v.y*iv; a.z = v.z*iv; a.w = v.w*iv;
            }
            win[u] = a;
            int ro = i0 + t - 8;
            if (t >= 8 && ro < NN){
                float4 ctr = win[(u+5)%9];
                float4 wl = shfl4(ctr, laneL);
                float4 wr = shfl4(ctr, laneR);
                if (outLane){
                    float cw[12] = {wl.x,wl.y,wl.z,wl.w, ctr.x,ctr.y,ctr.z,ctr.w, wr.x,wr.y,wr.z,wr.w};
                    #pragma unroll
                    for (int c=0;c<4;c++){
                        // row-axis convs (Wcx): row ro-4+k at slot (u+1+k)%9
                        float cx9 = ((win[(u+1)%9][c]*wx9[0] + win[(u+2)%9][c]*wx9[1]) + (win[(u+3)%9][c]*wx9[2] + win[(u+4)%9][c]*wx9[3]))
                                  + ((win[(u+5)%9][c]*wx9[4] + win[(u+6)%9][c]*wx9[5]) + (win[(u+7)%9][c]*wx9[6] + win[(u+8)%9][c]*wx9[7]))
                                  + win[u][c]*wx9[8];
                        float cx5 = ((win[(u+3)%9][c]*wx5[0] + win[(u+4)%9][c]*wx5[1]) + (win[(u+5)%9][c]*wx5[2] + win[(u+6)%9][c]*wx5[3]))
                                  + win[(u+7)%9][c]*wx5[4];
                        float cx3 = (win[(u+4)%9][c]*wx3[0] + win[(u+5)%9][c]*wx3[1]) + win[(u+6)%9][c]*wx3[2];
                        // col-axis convs (Wcy): window cw[c..c+8]
                        float cy9 = ((cw[c+0]*wy9[0] + cw[c+1]*wy9[1]) + (cw[c+2]*wy9[2] + cw[c+3]*wy9[3]))
                                  + ((cw[c+4]*wy9[4] + cw[c+5]*wy9[5]) + (cw[c+6]*wy9[6] + cw[c+7]*wy9[7]))
                                  + cw[c+8]*wy9[8];
                        float cy5 = ((cw[c+2]*wy5[0] + cw[c+3]*wy5[1]) + (cw[c+4]*wy5[2] + cw[c+5]*wy5[3]))
                                  + cw[c+6]*wy5[4];
                        float cy3 = (cw[c+3]*wy3[0] + cw[c+4]*wy3[1]) + cw[c+5]*wy3[2];
                        float c3v = cy3+cx3+bc3, c5v = cy5+cx5+bc5, c9v = cy9+cx9+bc9;
                        mn = fminf(mn, fminf(fminf(c3v,c5v),c9v));
                        mx = fmaxf(mx, fmaxf(fmaxf(c3v,c5v),c9v));
                    }
                }
            }
        }
    }
    #pragma unroll
    for (int m=1; m<64; m<<=1){
        mn = fminf(mn, __shfl_xor(mn, m, 64));
        mx = fmaxf(mx, __shfl_xor(mx, m, 64));
    }
    if (lane == 0){ smn[w] = mn; smx[w] = mx; }
    __syncthreads();
    if (tid == 0){
        float a0 = fminf(fminf(smn[0],smn[1]), fminf(smn[2],smn[3]));
        float b0 = fmaxf(fmaxf(smx[0],smx[1]), fmaxf(smx[2],smx[3]));
        int bid = blockIdx.y*gridDim.x + blockIdx.x;
        mnmx[bid] = a0;
        mnmx[1024 + bid] = b0;
    }
}

// ---------- phase 6b: kOt[d][0:4]=sum_j k[j][d]*Ot[j], [4:8]=...*Ty[j] ----------
__global__ __launch_bounds__(256) void k_kot(const __bf16* __restrict__ kh, const __bf16* __restrict__ kl,
        const float* __restrict__ x0, const float* __restrict__ Ty,
        float* __restrict__ kOt){
    __shared__ float red[256][8];
    int d = blockIdx.x, tid = threadIdx.x;
    float a[8] = {0,0,0,0,0,0,0,0};
    for (int j = tid; j < NN; j += 256){
        float kv = (float)kh[(size_t)j*128 + d] + (float)kl[(size_t)j*128 + d];
        float4 ot = *(const float4*)&x0[j*8+4];
        float4 ty = *(const float4*)&Ty[j*4];
        a[0] += kv*ot.x; a[1] += kv*ot.y; a[2] += kv*ot.z; a[3] += kv*ot.w;
        a[4] += kv*ty.x; a[5] += kv*ty.y; a[6] += kv*ty.z; a[7] += kv*ty.w;
    }
    #pragma unroll
    for (int q=0;q<8;q++) red[tid][q] = a[q];
    __syncthreads();
    for (int s=128; s>0; s>>=1){
        if (tid < s){
            #pragma unroll
            for (int q=0;q<8;q++) red[tid][q] += red[tid+s][q];
        }
        __syncthreads();
    }
    if (tid < 8) kOt[d*8 + tid] = red[0][tid];
}

// ---------- phase 6c: ASd = invr*(q@kOt), Bv from q@kTy + closed-form ----------
__global__ __launch_bounds__(256) void k_asd(
        const __bf16* __restrict__ qh, const __bf16* __restrict__ ql,
        const float* __restrict__ kOt,
        const unsigned* __restrict__ rowmaxenc, const float* __restrict__ maxd,
        const float* __restrict__ dOt, const float* __restrict__ colsum,
        const float* __restrict__ bcy3, const float* __restrict__ bcx3,
        const float* __restrict__ bcy5, const float* __restrict__ bcx5,
        const float* __restrict__ bcy9, const float* __restrict__ bcx9,
        float* __restrict__ ASdot, float* __restrict__ Bv){
    __shared__ float kst[128*8];
    int tid = threadIdx.x;
    for (int s = tid; s < 1024; s += 256) kst[s] = kOt[s];
    __syncthreads();
    int lane = tid & 63, r = tid >> 6;
    int i = blockIdx.x*4 + r;
    float a[8] = {0,0,0,0,0,0,0,0};
    #pragma unroll
    for (int dd=0; dd<2; ++dd){
        int d = lane + dd*64;
        float qv = (float)qh[(size_t)i*128 + d] + (float)ql[(size_t)i*128 + d];
        #pragma unroll
        for (int q=0;q<8;q++) a[q] += qv * kst[d*8+q];
    }
    #pragma unroll
    for (int m=1; m<64; m<<=1){
        #pragma unroll
        for (int q=0;q<8;q++) a[q] += __shfl_xor(a[q], m, 64);
    }
    if (lane == 0){
        float iv = 1.f/dec_f(rowmaxenc[i]);
        float imv = 1.f/maxd[i];
        float bcsum = bcy3[0]+bcx3[0]+bcy5[0]+bcx5[0]+bcy9[0]+bcx9[0];
        float k = 1.f + bcsum;
        float4 cs = *(const float4*)colsum;
        float4 dv = *(const float4*)&dOt[i*4];
        float4 pa = {iv*a[0], iv*a[1], iv*a[2], iv*a[3]};
        float4 b;
        b.x = cs.x*k - imv*dv.x + iv*a[4];
        b.y = cs.y*k - imv*dv.y + iv*a[5];
        b.z = cs.z*k - imv*dv.z + iv*a[6];
        b.w = cs.w*k - imv*dv.w + iv*a[7];
        *(float4*)&ASdot[i*4] = pa;
        *(float4*)&Bv[i*4]    = b;
    }
}

// ---------- phase 6d: global min/max = conv blocks U A-range U {0,1} ----------
__global__ __launch_bounds__(256) void k_gmm(const float* __restrict__ mnmx,
        const unsigned* __restrict__ rowminenc, const unsigned* __restrict__ rowmaxenc,
        float* __restrict__ gmm){
    __shared__ float smn[256], smx[256];
    int tid = threadIdx.x;
    float mn = 0.f, mx = 1.f;   // oushi range is exactly [0,1]
    for (int i=tid; i<NN; i+=256){
        float rmx = dec_f(rowmaxenc[i]);
        float q = dec_f(rowminenc[i]) / rmx;
        mn = fminf(mn, fminf(1.f, q));
        mx = fmaxf(mx, fmaxf(1.f, q));
    }
    for (int b=tid; b<918; b+=256){   // 17 x 54 blocks
        mn = fminf(mn, mnmx[b]);
        mx = fmaxf(mx, mnmx[1024+b]);
    }
    smn[tid]=mn; smx[tid]=mx; __syncthreads();
    for (int s=128;s>0;s>>=1){
        if (tid<s){ smn[tid]=fminf(smn[tid],smn[tid+s]); smx[tid]=fmaxf(smx[tid],smx[tid+s]); }
        __syncthreads();
    }
    if (tid==0){ gmm[0]=smn[0]; gmm[1]=smx[0]; }
}

// ---------- phase 7a: row-conv of ASdot + affine -> hfin ----------
__global__ void k_hfin(const float* __restrict__ ASdot, const float* __restrict__ Bv,
        const float* __restrict__ Wcx3, const float* __restrict__ Wcx5, const float* __restrict__ Wcx9,
        const float* __restrict__ gmm, const float* __restrict__ colsum,
        float* __restrict__ hfin){
    int i = blockIdx.x*256 + threadIdx.x;
    if (i >= NN) return;
    float Cx[9];
    #pragma unroll
    for (int o=-4;o<=4;o++){
        float c = Wcx9[o+4];
        if (o>=-2 && o<=2) c += Wcx5[o+2];
        if (o>=-1 && o<=1) c += Wcx3[o+1];
        Cx[o+4] = c;
    }
    float4 h = *(const float4*)&Bv[i*4];
    float4 a0 = *(const float4*)&ASdot[i*4];
    h.x += a0.x; h.y += a0.y; h.z += a0.z; h.w += a0.w;
    #pragma unroll
    for (int o=-4;o<=4;o++){
        int r = i + o;
        if ((unsigned)r < NN){
            float4 av = *(const float4*)&ASdot[r*4];
            float c = Cx[o+4];
            h.x += c*av.x; h.y += c*av.y; h.z += c*av.z; h.w += c*av.w;
        }
    }
    float mnv = gmm[0], mxv = gmm[1];
    float s = 1.f/(mxv-mnv), oa = -mnv*s;
    float4 cs = *(const float4*)colsum;
    float4 out;
    out.x = s*h.x + 5.f*oa*cs.x;
    out.y = s*h.y + 5.f*oa*cs.y;
    out.z = s*h.z + 5.f*oa*cs.z;
    out.w = s*h.w + 5.f*oa*cs.w;
    *(float4*)&hfin[i*4] = out;
}

// ---------- phase 7b: MLP head ----------
__global__ __launch_bounds__(256) void k_mlp(const float* __restrict__ hfin,
        const float* __restrict__ Woff, const float* __restrict__ boff, const float* __restrict__ pw,
        const float* __restrict__ Wf1, const float* __restrict__ bf1,
        const float* __restrict__ Wf2, const float* __restrict__ bf2,
        const float* __restrict__ Wf3, const float* __restrict__ bf3,
        float* __restrict__ out){
    __shared__ float h1[8][128];
    __shared__ float h2[8][256];
    __shared__ float h3[8][256];
    __shared__ float4 red4[256];
    int n0 = blockIdx.x*8, tid = threadIdx.x;
    float p = pw[0];
    {
        int c = tid & 127, mb = (tid>>7)*4;
        #pragma unroll
        for (int mm=0; mm<4; mm++){
            int m = mb+mm;
            float v = boff[c];
            #pragma unroll
            for (int k=0;k<4;k++) v += hfin[(n0+m)*4+k]*Woff[k*128+c];
            h1[m][c] = v>0.f ? v : p*v;
        }
    }
    __syncthreads();
    {
        int c = tid;
        float acc[8];
        #pragma unroll
        for (int m=0;m<8;m++) acc[m] = bf1[c];
        for (int k=0;k<128;k++){
            float w = Wf1[k*256+c];
            #pragma unroll
            for (int m=0;m<8;m++) acc[m] += h1[m][k]*w;
        }
        #pragma unroll
        for (int m=0;m<8;m++) h2[m][c] = acc[m]>0.f?acc[m]:0.f;
    }
    __syncthreads();
    {
        int c = tid;
        float acc[8];
        #pragma unroll
        for (int m=0;m<8;m++) acc[m] = bf2[c];
        for (int k=0;k<256;k++){
            float w = Wf2[k*256+c];
            #pragma unroll
            for (int m=0;m<8;m++) acc[m] += h2[m][k]*w;
        }
        #pragma unroll
        for (int m=0;m<8;m++) h3[m][c] = acc[m]>0.f?acc[m]:0.f;
    }
    __syncthreads();
    float w3_0 = Wf3[tid*4+0], w3_1 = Wf3[tid*4+1], w3_2 = Wf3[tid*4+2], w3_3 = Wf3[tid*4+3];
    for (int m=0;m<8;m++){
        float hv = h3[m][tid];
        float4 r; r.x = hv*w3_0; r.y = hv*w3_1; r.z = hv*w3_2; r.w = hv*w3_3;
        red4[tid]=r; __syncthreads();
        for (int s=128;s>0;s>>=1){
            if(tid<s){
                red4[tid].x+=red4[tid+s].x; red4[tid].y+=red4[tid+s].y;
                red4[tid].z+=red4[tid+s].z; red4[tid].w+=red4[tid+s].w;
            }
            __syncthreads();
        }
        if (tid==0){
            float4 o;
            o.x = red4[0].x + bf3[0]; o.y = red4[0].y + bf3[1];
            o.z = red4[0].z + bf3[2]; o.w = red4[0].w + bf3[3];
            *(float4*)&out[(n0+m)*4] = o;
        }
        __syncthreads();
    }
}

// ---------- host ----------
extern "C" void kernel_launch(void* const* d_in, const int* in_sizes, int n_in,
                              void* d_out, int out_size, void* d_ws, size_t ws_size,
                              hipStream_t stream){
    const float* dx1  = (const float*)d_in[0];
    const float* dx2  = (const float*)d_in[1];
    const float* Wk   = (const float*)d_in[2];
    const float* bk   = (const float*)d_in[3];
    const float* Wg1  = (const float*)d_in[4];
    const float* bg1  = (const float*)d_in[5];
    const float* Wg2  = (const float*)d_in[6];
    const float* bg2  = (const float*)d_in[7];
    const float* Wq   = (const float*)d_in[8];
    const float* bq   = (const float*)d_in[9];
    const float* Wkey = (const float*)d_in[10];
    const float* bkey = (const float*)d_in[11];
    const float* Woff = (const float*)d_in[12];
    const float* boff = (const float*)d_in[13];
    const float* pw   = (const float*)d_in[14];
    const float* Wf1  = (const float*)d_in[15];
    const float* bf1  = (const float*)d_in[16];
    const float* Wf2  = (const float*)d_in[17];
    const float* bf2  = (const float*)d_in[18];
    const float* Wf3  = (const float*)d_in[19];
    const float* bf3  = (const float*)d_in[20];
    const float* Wcy3 = (const float*)d_in[21];
    const float* bcy3 = (const float*)d_in[22];
    const float* Wcx3 = (const float*)d_in[23];
    const float* bcx3 = (const float*)d_in[24];
    const float* Wcy5 = (const float*)d_in[25];
    const float* bcy5 = (const float*)d_in[26];
    const float* Wcx5 = (const float*)d_in[27];
    const float* bcx5 = (const float*)d_in[28];
    const float* Wcy9 = (const float*)d_in[29];
    const float* bcy9 = (const float*)d_in[30];
    const float* Wcx9 = (const float*)d_in[31];
    const float* bcx9 = (const float*)d_in[32];

    char* ws = (char*)d_ws;
    size_t off = 0;
    auto alloc = [&](size_t b)->void*{ void* p = ws + off; off += (b + 255) & ~(size_t)255; return p; };

    // --- zero-init region (one small memset) ---
    char* zbase = ws + off;
    float*    colsum    = (float*)   alloc(4*4);
    int*      cnt3      = (int*)     alloc((size_t)NN*4);
    int*      cnt5      = (int*)     alloc((size_t)NN*4);
    int*      cnt9      = (int*)     alloc((size_t)NN*4);
    int*      cur       = (int*)     alloc((size_t)3*NN*4);
    unsigned* rowmaxenc = (unsigned*)alloc((size_t)NN*4);
    size_t zbytes = (size_t)((ws + off) - zbase);
    unsigned* rowminenc = (unsigned*)alloc((size_t)NN*4);   // memset 0xFF

    // --- non-zeroed ---
    float* x0     = (float*)alloc((size_t)NN*8*4);
    float* maxd   = (float*)alloc((size_t)NN*4);
    int*   nbr    = (int*)  alloc((size_t)NN*9*4);
    int*   offc   = (int*)  alloc((size_t)3*NN*4);
    float* dinvc  = (float*)alloc((size_t)3*NN*4);
    int*   rev    = (int*)  alloc((size_t)NN*17*4);
    float* xw     = (float*)alloc((size_t)NN*64*4);
    float* y2     = (float*)alloc((size_t)3*NN*128*4);
    float* emb    = (float*)alloc((size_t)NN*384*4);
    __bf16* qh   = (__bf16*)alloc((size_t)NN*128*2);
    __bf16* ql   = (__bf16*)alloc((size_t)NN*128*2);
    __bf16* kh   = (__bf16*)alloc((size_t)NN*128*2);
    __bf16* kl   = (__bf16*)alloc((size_t)NN*128*2);
    float* scores = (float*)alloc((size_t)NN*NN*4);
    float* Tyb    = (float*)alloc((size_t)NN*4*4);
    float* invr   = (float*)alloc((size_t)NN*4);
    float* dOt    = (float*)alloc((size_t)NN*4*4);
    float* kOt    = (float*)alloc((size_t)128*8*4);
    float* ASd    = (float*)alloc((size_t)NN*4*4);
    float* Bv     = (float*)alloc((size_t)NN*4*4);
    float* mnmx   = (float*)alloc((size_t)2*1024*4);
    float* gmm    = (float*)alloc(2*4);
    float* hfin   = (float*)alloc((size_t)NN*4*4);
    (void)ws_size; (void)in_sizes; (void)n_in; (void)out_size;

    hipMemsetAsync(zbase, 0, zbytes, stream);
    hipMemsetAsync(rowminenc, 0xFF, (size_t)NN*4, stream);

    k_prep<<<16,256,0,stream>>>(dx1,dx2,Wk,bk,x0,colsum);
    k_ty  <<<16,256,0,stream>>>(x0,Wcy3,Wcy5,Wcy9,Tyb);
    k_dist<<<NN/4,256,0,stream>>>(dx1,x0,maxd,nbr,cnt3,cnt5,cnt9,dOt);
    k_scan<<<1,256,0,stream>>>(cnt3,cnt5,cnt9,offc,dinvc);
    k_fill<<<16,256,0,stream>>>(nbr,offc,cur,rev);

    k_y1  <<<NN*64/256,256,0,stream>>>(x0,Wg1,xw);
    k_h1y2<<<NN/4,256,0,stream>>>(xw,offc,cnt3,cnt5,cnt9,rev,dinvc,bg1,Wg2,y2);
    k_fin <<<NN*3,128,0,stream>>>(y2,offc,cnt3,cnt5,cnt9,rev,dinvc,bg2,emb);

    k_qk<<<NN/8,256,0,stream>>>(emb,Wq,bq,Wkey,bkey,qh,ql,kh,kl);
    k_scores<<<1024,256,0,stream>>>(qh,ql,kh,kl,scores,rowmaxenc,rowminenc);
    k_invr<<<16,256,0,stream>>>(rowmaxenc,invr);
    k_kot<<<128,256,0,stream>>>(kh,kl,x0,Tyb,kOt);

    k_cconv<<<dim3(17,54),256,0,stream>>>(scores,invr,
        Wcy3,Wcx3,Wcy5,Wcx5,Wcy9,Wcx9,
        bcy3,bcx3,bcy5,bcx5,bcy9,bcx9, mnmx);
    k_asd<<<NN/4,256,0,stream>>>(qh,ql,kOt,rowmaxenc,maxd,dOt,colsum,
        bcy3,bcx3,bcy5,bcx5,bcy9,bcx9, ASd, Bv);
    k_gmm<<<1,256,0,stream>>>(mnmx,rowminenc,rowmaxenc,gmm);
    k_hfin<<<16,256,0,stream>>>(ASd,Bv,Wcx3,Wcx5,Wcx9,gmm,colsum,hfin);
    k_mlp<<<NN/8,256,0,stream>>>(hfin,Woff,boff,pw,Wf1,bf1,Wf2,bf2,Wf3,bf3,(float*)d_out);
}

// Round 12
// 305.503 us; speedup vs baseline: 1.3329x; 1.0145x over previous
//
#include <hip/hip_runtime.h>
#include <math.h>

#define NN 4096

typedef __bf16 bf16x8 __attribute__((ext_vector_type(8)));
typedef float  f32x4  __attribute__((ext_vector_type(4)));

static __device__ __forceinline__ unsigned enc_f(float f){
    unsigned u = __float_as_uint(f);
    return (u & 0x80000000u) ? ~u : (u | 0x80000000u);
}
static __device__ __forceinline__ float dec_f(unsigned u){
    unsigned b = (u & 0x80000000u) ? (u & 0x7fffffffu) : ~u;
    return __uint_as_float(b);
}
static __device__ __forceinline__ float4 shfl4(float4 v, int src){
    float4 r;
    r.x = __shfl(v.x, src, 64);
    r.y = __shfl(v.y, src, 64);
    r.z = __shfl(v.z, src, 64);
    r.w = __shfl(v.w, src, 64);
    return r;
}

// ---------- phase 1: x0 assembly + packed pos/Ot + column sums ----------
__global__ void k_prep(const float* __restrict__ dx1, const float* __restrict__ dx2,
                       const float* __restrict__ Wk, const float* __restrict__ bk,
                       float* __restrict__ x0, float* __restrict__ colsum,
                       float2* __restrict__ pos, float4* __restrict__ otp){
    int n = blockIdx.x*blockDim.x + threadIdx.x;
    if (n >= NN) return;
    float wk[8];
    #pragma unroll
    for (int j=0;j<8;j++) wk[j] = Wk[j];
    float bkv = bk[0];
    float4 d1 = *(const float4*)&dx1[n*4];
    pos[n] = make_float2(d1.x, d1.y);
    #pragma unroll
    for (int c=0;c<4;c++) x0[n*8+c] = (&d1.x)[c];
    float4 ot;
    #pragma unroll
    for (int c=0;c<4;c++){
        float acc = bkv;
        #pragma unroll
        for (int j=0;j<8;j++) acc += dx2[(n*8+j)*4+c]*wk[j];
        x0[n*8+4+c] = acc;
        (&ot.x)[c] = acc;
        atomicAdd(&colsum[c], acc);
    }
    otp[n] = ot;
}

// ---------- phase 1b: Ty[j] = column-conv kernel applied to Ot ----------
__global__ void k_ty(const float* __restrict__ x0,
        const float* __restrict__ Wcy3, const float* __restrict__ Wcy5, const float* __restrict__ Wcy9,
        float* __restrict__ Ty){
    int j = blockIdx.x*256 + threadIdx.x;
    if (j >= NN) return;
    float Cy[9];
    #pragma unroll
    for (int o=-4;o<=4;o++){
        float c = Wcy9[o+4];
        if (o>=-2 && o<=2) c += Wcy5[o+2];
        if (o>=-1 && o<=1) c += Wcy3[o+1];
        Cy[o+4] = c;
    }
    float4 acc = {0,0,0,0};
    #pragma unroll
    for (int o=-4;o<=4;o++){
        int jj = j - o;
        if ((unsigned)jj < NN){
            float4 ot = *(const float4*)&x0[jj*8+4];
            float c = Cy[o+4];
            acc.x += c*ot.x; acc.y += c*ot.y; acc.z += c*ot.z; acc.w += c*ot.w;
        }
    }
    *(float4*)&Ty[j*4] = acc;
}

// ---------- phase 2: row max dist + top-9 knn + in-deg counts + dOt ----------
// no LDS staging: pos (32KB) is L1-resident, otp (64KB) L2-resident -> full occupancy
__global__ __launch_bounds__(256) void k_dist(const float2* __restrict__ pos,
        const float4* __restrict__ otp,
        float* __restrict__ maxd, int* __restrict__ nbr,
        int* __restrict__ cnt3, int* __restrict__ cnt5, int* __restrict__ cnt9,
        float* __restrict__ dOt){
    int tid = threadIdx.x;
    int lane = tid & 63;
    int i = blockIdx.x*4 + (tid>>6);
    float2 pi = pos[i];
    unsigned long long best[9];
    #pragma unroll
    for (int q=0;q<9;q++) best[q] = ~0ULL;
    float lmax = 0.f;
    float4 dacc = {0,0,0,0};
    for (int t=0;t<64;t++){
        int j = (t<<6) | lane;
        float2 p = pos[j];
        float dx = pi.x - p.x, dy = pi.y - p.y;
        float d = sqrtf(dx*dx + dy*dy);
        lmax = fmaxf(lmax, d);
        float4 otj = otp[j];
        dacc.x += d*otj.x; dacc.y += d*otj.y; dacc.z += d*otj.z; dacc.w += d*otj.w;
        unsigned long long cand = ((unsigned long long)__float_as_uint(d) << 32) | (unsigned)j;
        if (j != i && cand < best[8]){
            best[8] = cand;
            #pragma unroll
            for (int q=8; q>0; --q){
                if (best[q] < best[q-1]){ unsigned long long tm=best[q]; best[q]=best[q-1]; best[q-1]=tm; }
            }
        }
    }
    #pragma unroll
    for (int m=1;m<64;m<<=1){
        lmax = fmaxf(lmax, __shfl_xor(lmax, m, 64));
        dacc.x += __shfl_xor(dacc.x, m, 64);
        dacc.y += __shfl_xor(dacc.y, m, 64);
        dacc.z += __shfl_xor(dacc.z, m, 64);
        dacc.w += __shfl_xor(dacc.w, m, 64);
    }
    if (lane==0){
        maxd[i] = lmax;
        *(float4*)&dOt[i*4] = dacc;
    }
    for (int t=0;t<9;t++){
        unsigned long long w = best[0];
        #pragma unroll
        for (int m=1;m<64;m<<=1){
            unsigned long long o = __shfl_xor(w, m, 64);
            if (o < w) w = o;
        }
        if (best[0] == w){
            #pragma unroll
            for (int q=0;q<8;q++) best[q] = best[q+1];
            best[8] = ~0ULL;
        }
        if (lane==0){
            int j = (int)(w & 0xffffffffu);
            nbr[i*9+t] = j;
            atomicAdd(&cnt9[j], 1);
            if (t<5) atomicAdd(&cnt5[j], 1);
            if (t<3) atomicAdd(&cnt3[j], 1);
        }
    }
}

// ---------- phase 2b: CSR offsets (exclusive scan) + dinv ----------
__global__ __launch_bounds__(256) void k_scan(const int* __restrict__ cnt3,
        const int* __restrict__ cnt5, const int* __restrict__ cnt9,
        int* __restrict__ offc, float* __restrict__ dinvc){
    __shared__ int part[256];
    int tid = threadIdx.x;
    for (int g=0; g<3; g++){
        const int* cp = g==0?cnt3:(g==1?cnt5:cnt9);
        int base = tid*16;
        int loc[16]; int s=0;
        #pragma unroll
        for (int q=0;q<16;q++){ loc[q]=s; s += cp[base+q]; }
        part[tid]=s; __syncthreads();
        for (int d=1; d<256; d<<=1){
            int v = (tid>=d) ? part[tid-d] : 0;
            __syncthreads();
            part[tid] += v;
            __syncthreads();
        }
        int pre = (tid==0) ? 0 : part[tid-1];
        #pragma unroll
        for (int q=0;q<16;q++){
            offc[g*NN + base + q]  = pre + loc[q];
            dinvc[g*NN + base + q] = rsqrtf((float)cp[base+q] + 1.f);
        }
        __syncthreads();
    }
}

// ---------- phase 2c: fill reverse-edge lists ----------
__global__ void k_fill(const int* __restrict__ nbr, const int* __restrict__ offc,
        int* __restrict__ cur, int* __restrict__ rev){
    int i = blockIdx.x*256 + threadIdx.x;
    if (i >= NN) return;
    #pragma unroll
    for (int t=0;t<9;t++){
        int j = nbr[i*9+t];
        int gmin = t<3 ? 0 : (t<5 ? 1 : 2);
        for (int g=gmin; g<3; g++){
            int pos = atomicAdd(&cur[g*NN+j], 1);
            int rb = (g==0) ? 0 : (g==1 ? NN*3 : NN*8);
            rev[rb + offc[g*NN+j] + pos] = i;
        }
    }
}

// ---------- phase 3: GCN layer-1 input transform ----------
__global__ void k_y1(const float* __restrict__ x0, const float* __restrict__ Wg1,
                     float* __restrict__ xw){
    int idx = blockIdx.x*256 + threadIdx.x;
    if (idx >= NN*64) return;
    int n = idx>>6, c = idx&63;
    float acc = 0.f;
    #pragma unroll
    for (int k=0;k<8;k++) acc += x0[n*8+k]*Wg1[k*64+c];
    xw[idx] = acc;
}

// ---------- phase 3b: gather layer-1 + relu + layer-2 matmul ----------
__global__ __launch_bounds__(256) void k_h1y2(const float* __restrict__ xw,
        const int* __restrict__ offc,
        const int* __restrict__ cnt3, const int* __restrict__ cnt5, const int* __restrict__ cnt9,
        const int* __restrict__ rev, const float* __restrict__ dinvc,
        const float* __restrict__ bg1, const float* __restrict__ Wg2,
        float* __restrict__ y2){
    __shared__ float h1s[12][64];
    int n0 = blockIdx.x*4, tid = threadIdx.x;
    for (int s=tid; s<768; s+=256){
        int p = s>>6, k = s&63, g = p>>2, n = n0+(p&3);
        const int* cp = g==0?cnt3:(g==1?cnt5:cnt9);
        int rb = (g==0) ? 0 : (g==1 ? NN*3 : NN*8);
        int cnt = cp[n];
        int o = rb + offc[g*NN+n];
        float dv = dinvc[g*NN+n];
        float srow = dv*xw[n*64+k];
        for (int e=0;e<cnt;e++){
            int i = rev[o+e];
            srow += dinvc[g*NN+i]*xw[i*64+k];
        }
        float v = dv*srow + bg1[k];
        h1s[p][k] = v>0.f ? v : 0.f;
    }
    __syncthreads();
    int c = tid & 127, ph = tid>>7;
    float a6[6] = {0,0,0,0,0,0};
    for (int k=0;k<64;k++){
        float w = Wg2[k*128+c];
        #pragma unroll
        for (int q=0;q<6;q++) a6[q] += h1s[q*2+ph][k]*w;
    }
    #pragma unroll
    for (int q=0;q<6;q++){
        int p = q*2+ph, g = p>>2, n = n0+(p&3);
        float dv = dinvc[g*NN+n];
        y2[(size_t)g*NN*128 + (size_t)n*128 + c] = dv*a6[q];
    }
}

// ---------- phase 3c: gather layer-2 + bias + log_softmax ----------
__global__ __launch_bounds__(128) void k_fin(const float* __restrict__ y2,
        const int* __restrict__ offc,
        const int* __restrict__ cnt3, const int* __restrict__ cnt5, const int* __restrict__ cnt9,
        const int* __restrict__ rev, const float* __restrict__ dinvc,
        const float* __restrict__ bg2, float* __restrict__ emb){
    __shared__ float sm[2], ss[2];
    int b = blockIdx.x;
    int n = b & (NN-1), g = b >> 12;
    const int* cp = g==0?cnt3:(g==1?cnt5:cnt9);
    int rb = (g==0) ? 0 : (g==1 ? NN*3 : NN*8);
    int cnt = cp[n];
    int o = rb + offc[g*NN+n];
    float dv = dinvc[g*NN+n];
    int c = threadIdx.x;
    const float* yg = y2 + (size_t)g*NN*128;
    float s = yg[(size_t)n*128 + c];
    for (int e=0;e<cnt;e++){
        int i = rev[o+e];
        s += yg[(size_t)i*128 + c];
    }
    float v = dv*s + bg2[c];
    float m = v;
    #pragma unroll
    for (int st=1;st<64;st<<=1) m = fmaxf(m, __shfl_xor(m, st, 64));
    if ((c&63)==0) sm[c>>6] = m;
    __syncthreads();
    m = fmaxf(sm[0], sm[1]);
    float e = expf(v - m);
    float t = e;
    #pragma unroll
    for (int st=1;st<64;st<<=1) t += __shfl_xor(t, st, 64);
    if ((c&63)==0) ss[c>>6] = t;
    __syncthreads();
    t = ss[0]+ss[1];
    emb[n*384 + g*128 + c] = v - m - logf(t);
}

// ---------- phase 4: q/k projections -> bf16 hi/lo split ----------
__global__ __launch_bounds__(256) void k_qk(const float* __restrict__ emb,
        const float* __restrict__ Wq, const float* __restrict__ bq,
        const float* __restrict__ Wkey, const float* __restrict__ bkey,
        __bf16* __restrict__ qh, __bf16* __restrict__ ql,
        __bf16* __restrict__ kh, __bf16* __restrict__ kl){
    __shared__ float es[8][384];
    int n0 = blockIdx.x*8;
    int tid = threadIdx.x;
    for (int idx=tid; idx<8*384; idx+=256){
        int m = idx/384, k = idx%384;
        es[m][k] = emb[(n0+m)*384+k];
    }
    __syncthreads();
    int c = tid & 127;
    int sel = tid >> 7;
    const float* W = sel ? Wkey : Wq;
    float b = sel ? bkey[c] : bq[c];
    float acc[8];
    #pragma unroll
    for (int m=0;m<8;m++) acc[m]=b;
    for (int k=0;k<384;k++){
        float w = W[k*128+c];
        #pragma unroll
        for (int m=0;m<8;m++) acc[m] += es[m][k]*w;
    }
    __bf16* oh = sel ? kh : qh;
    __bf16* ol = sel ? kl : ql;
    #pragma unroll
    for (int m=0;m<8;m++){
        float v = acc[m];
        __bf16 h = (__bf16)v;
        oh[(size_t)(n0+m)*128+c] = h;
        ol[(size_t)(n0+m)*128+c] = (__bf16)(v - (float)h);
    }
}

// ---------- phase 5: scores = q @ k^T via bf16-split MFMA + fused row max/min ----------
__global__ __launch_bounds__(256) void k_scores(
        const __bf16* __restrict__ qh, const __bf16* __restrict__ ql,
        const __bf16* __restrict__ kh, const __bf16* __restrict__ kl,
        float* __restrict__ scores,
        unsigned* __restrict__ rowmaxenc, unsigned* __restrict__ rowminenc){
    int bx = blockIdx.x & 31;
    int by = blockIdx.x >> 5;
    int tid = threadIdx.x;
    int w = tid >> 6, lane = tid & 63;
    int li = lane & 15, g = lane >> 4;
    int r0 = by*128 + (w>>1)*64;
    int c0 = bx*128 + (w&1)*64;

    f32x4 acc[4][4] = {};
    for (int ks=0; ks<4; ++ks){
        int kofs = ks*32 + g*8;
        bf16x8 ah[4], al[4], bh[4], bl[4];
        #pragma unroll
        for (int f=0; f<4; ++f){
            ah[f] = *(const bf16x8*)&qh[(size_t)(r0+f*16+li)*128 + kofs];
            al[f] = *(const bf16x8*)&ql[(size_t)(r0+f*16+li)*128 + kofs];
            bh[f] = *(const bf16x8*)&kh[(size_t)(c0+f*16+li)*128 + kofs];
            bl[f] = *(const bf16x8*)&kl[(size_t)(c0+f*16+li)*128 + kofs];
        }
        #pragma unroll
        for (int fr=0; fr<4; ++fr){
            #pragma unroll
            for (int fc=0; fc<4; ++fc){
                acc[fr][fc] = __builtin_amdgcn_mfma_f32_16x16x32_bf16(ah[fr], bh[fc], acc[fr][fc], 0, 0, 0);
                acc[fr][fc] = __builtin_amdgcn_mfma_f32_16x16x32_bf16(ah[fr], bl[fc], acc[fr][fc], 0, 0, 0);
                acc[fr][fc] = __builtin_amdgcn_mfma_f32_16x16x32_bf16(al[fr], bh[fc], acc[fr][fc], 0, 0, 0);
            }
        }
    }
    #pragma unroll
    for (int fr=0; fr<4; ++fr){
        #pragma unroll
        for (int r=0; r<4; ++r){
            int row = r0 + fr*16 + g*4 + r;
            float mx = -INFINITY, mn = INFINITY;
            #pragma unroll
            for (int fc=0; fc<4; ++fc){
                float v = acc[fr][fc][r];
                scores[(size_t)row*NN + c0 + fc*16 + li] = v;
                mx = fmaxf(mx, v);
                mn = fminf(mn, v);
            }
            #pragma unroll
            for (int s=1; s<16; s<<=1){
                mx = fmaxf(mx, __shfl_xor(mx, s, 64));
                mn = fminf(mn, __shfl_xor(mn, s, 64));
            }
            if (li == 0){
                atomicMax(&rowmaxenc[row], enc_f(mx));
                atomicMin(&rowminenc[row], enc_f(mn));
            }
        }
    }
}

// ---------- phase 5b: invr = 1/rowmax ----------
__global__ void k_invr(const unsigned* __restrict__ rowmaxenc, float* __restrict__ invr){
    int i = blockIdx.x*256 + threadIdx.x;
    if (i >= NN) return;
    invr[i] = 1.f/dec_f(rowmaxenc[i]);
}

// ---------- phase 6: streaming conv min/max over A, float4/lane ----------
__global__ __launch_bounds__(256) void k_cconv(const float* __restrict__ scores,
        const float* __restrict__ invr,
        const float* __restrict__ Wcy3, const float* __restrict__ Wcx3,
        const float* __restrict__ Wcy5, const float* __restrict__ Wcx5,
        const float* __restrict__ Wcy9, const float* __restrict__ Wcx9,
        const float* __restrict__ bcy3, const float* __restrict__ bcx3,
        const float* __restrict__ bcy5, const float* __restrict__ bcx5,
        const float* __restrict__ bcy9, const float* __restrict__ bcx9,
        float* __restrict__ mnmx){
    __shared__ float smn[4], smx[4];
    int tid = threadIdx.x;
    int w = tid >> 6, lane = tid & 63;
    int strip = blockIdx.x;                       // 0..16
    int i0 = (blockIdx.y*4 + w)*19;
    int colbase = strip*248 - 4 + lane*4;
    bool lv = (colbase >= 0) && (colbase + 3 < NN);
    bool outLane = (lane >= 1) && (lane < 63) && lv;

    float wy3[3],wx3[3],wy5[5],wx5[5],wy9[9],wx9[9];
    #pragma unroll
    for (int t=0;t<3;t++){ wy3[t]=Wcy3[t]; wx3[t]=Wcx3[t]; }
    #pragma unroll
    for (int t=0;t<5;t++){ wy5[t]=Wcy5[t]; wx5[t]=Wcx5[t]; }
    #pragma unroll
    for (int t=0;t<9;t++){ wy9[t]=Wcy9[t]; wx9[t]=Wcx9[t]; }
    float bc3 = bcy3[0]+bcx3[0];
    float bc5 = bcy5[0]+bcx5[0];
    float bc9 = bcy9[0]+bcx9[0];

    float4 win[9];
    float mn = INFINITY, mx = -INFINITY;
    const int laneL = lane - 1, laneR = lane + 1;

    for (int tb = 0; tb < 3; ++tb){
        #pragma unroll
        for (int u = 0; u < 9; ++u){
            int t  = tb*9 + u;
            int ri = i0 - 4 + t;
            float4 a = make_float4(0,0,0,0);
            if (((unsigned)ri < NN) && lv){
                float iv = invr[ri];
                float4 v = *(const float4*)&scores[(size_t)ri*NN + colbase];
                a.x = v.x*iv; a.y = v.y*iv; a.z = v.z*iv; a.w = v.w*iv;
            }
            win[u] = a;
            int ro = i0 + t - 8;
            if (t >= 8 && ro < NN){
                float4 ctr = win[(u+5)%9];
                float4 wl = shfl4(ctr, laneL);
                float4 wr = shfl4(ctr, laneR);
                if (outLane){
                    float cw[12] = {wl.x,wl.y,wl.z,wl.w, ctr.x,ctr.y,ctr.z,ctr.w, wr.x,wr.y,wr.z,wr.w};
                    #pragma unroll
                    for (int c=0;c<4;c++){
                        float cx9 = ((win[(u+1)%9][c]*wx9[0] + win[(u+2)%9][c]*wx9[1]) + (win[(u+3)%9][c]*wx9[2] + win[(u+4)%9][c]*wx9[3]))
                                  + ((win[(u+5)%9][c]*wx9[4] + win[(u+6)%9][c]*wx9[5]) + (win[(u+7)%9][c]*wx9[6] + win[(u+8)%9][c]*wx9[7]))
                                  + win[u][c]*wx9[8];
                        float cx5 = ((win[(u+3)%9][c]*wx5[0] + win[(u+4)%9][c]*wx5[1]) + (win[(u+5)%9][c]*wx5[2] + win[(u+6)%9][c]*wx5[3]))
                                  + win[(u+7)%9][c]*wx5[4];
                        float cx3 = (win[(u+4)%9][c]*wx3[0] + win[(u+5)%9][c]*wx3[1]) + win[(u+6)%9][c]*wx3[2];
                        float cy9 = ((cw[c+0]*wy9[0] + cw[c+1]*wy9[1]) + (cw[c+2]*wy9[2] + cw[c+3]*wy9[3]))
                                  + ((cw[c+4]*wy9[4] + cw[c+5]*wy9[5]) + (cw[c+6]*wy9[6] + cw[c+7]*wy9[7]))
                                  + cw[c+8]*wy9[8];
                        float cy5 = ((cw[c+2]*wy5[0] + cw[c+3]*wy5[1]) + (cw[c+4]*wy5[2] + cw[c+5]*wy5[3]))
                                  + cw[c+6]*wy5[4];
                        float cy3 = (cw[c+3]*wy3[0] + cw[c+4]*wy3[1]) + cw[c+5]*wy3[2];
                        float c3v = cy3+cx3+bc3, c5v = cy5+cx5+bc5, c9v = cy9+cx9+bc9;
                        mn = fminf(mn, fminf(fminf(c3v,c5v),c9v));
                        mx = fmaxf(mx, fmaxf(fmaxf(c3v,c5v),c9v));
                    }
                }
            }
        }
    }
    #pragma unroll
    for (int m=1; m<64; m<<=1){
        mn = fminf(mn, __shfl_xor(mn, m, 64));
        mx = fmaxf(mx, __shfl_xor(mx, m, 64));
    }
    if (lane == 0){ smn[w] = mn; smx[w] = mx; }
    __syncthreads();
    if (tid == 0){
        float a0 = fminf(fminf(smn[0],smn[1]), fminf(smn[2],smn[3]));
        float b0 = fmaxf(fmaxf(smx[0],smx[1]), fmaxf(smx[2],smx[3]));
        int bid = blockIdx.y*gridDim.x + blockIdx.x;
        mnmx[bid] = a0;
        mnmx[1024 + bid] = b0;
    }
}

// ---------- phase 6b: kOt[d][0:4]=sum_j k[j][d]*Ot[j], [4:8]=...*Ty[j] ----------
__global__ __launch_bounds__(256) void k_kot(const __bf16* __restrict__ kh, const __bf16* __restrict__ kl,
        const float* __restrict__ x0, const float* __restrict__ Ty,
        float* __restrict__ kOt){
    __shared__ float red[256][8];
    int d = blockIdx.x, tid = threadIdx.x;
    float a[8] = {0,0,0,0,0,0,0,0};
    for (int j = tid; j < NN; j += 256){
        float kv = (float)kh[(size_t)j*128 + d] + (float)kl[(size_t)j*128 + d];
        float4 ot = *(const float4*)&x0[j*8+4];
        float4 ty = *(const float4*)&Ty[j*4];
        a[0] += kv*ot.x; a[1] += kv*ot.y; a[2] += kv*ot.z; a[3] += kv*ot.w;
        a[4] += kv*ty.x; a[5] += kv*ty.y; a[6] += kv*ty.z; a[7] += kv*ty.w;
    }
    #pragma unroll
    for (int q=0;q<8;q++) red[tid][q] = a[q];
    __syncthreads();
    for (int s=128; s>0; s>>=1){
        if (tid < s){
            #pragma unroll
            for (int q=0;q<8;q++) red[tid][q] += red[tid+s][q];
        }
        __syncthreads();
    }
    if (tid < 8) kOt[d*8 + tid] = red[0][tid];
}

// ---------- phase 6c: ASd = invr*(q@kOt), Bv from q@kTy + closed-form ----------
__global__ __launch_bounds__(256) void k_asd(
        const __bf16* __restrict__ qh, const __bf16* __restrict__ ql,
        const float* __restrict__ kOt,
        const unsigned* __restrict__ rowmaxenc, const float* __restrict__ maxd,
        const float* __restrict__ dOt, const float* __restrict__ colsum,
        const float* __restrict__ bcy3, const float* __restrict__ bcx3,
        const float* __restrict__ bcy5, const float* __restrict__ bcx5,
        const float* __restrict__ bcy9, const float* __restrict__ bcx9,
        float* __restrict__ ASdot, float* __restrict__ Bv){
    __shared__ float kst[128*8];
    int tid = threadIdx.x;
    for (int s = tid; s < 1024; s += 256) kst[s] = kOt[s];
    __syncthreads();
    int lane = tid & 63, r = tid >> 6;
    int i = blockIdx.x*4 + r;
    float a[8] = {0,0,0,0,0,0,0,0};
    #pragma unroll
    for (int dd=0; dd<2; ++dd){
        int d = lane + dd*64;
        float qv = (float)qh[(size_t)i*128 + d] + (float)ql[(size_t)i*128 + d];
        #pragma unroll
        for (int q=0;q<8;q++) a[q] += qv * kst[d*8+q];
    }
    #pragma unroll
    for (int m=1; m<64; m<<=1){
        #pragma unroll
        for (int q=0;q<8;q++) a[q] += __shfl_xor(a[q], m, 64);
    }
    if (lane == 0){
        float iv = 1.f/dec_f(rowmaxenc[i]);
        float imv = 1.f/maxd[i];
        float bcsum = bcy3[0]+bcx3[0]+bcy5[0]+bcx5[0]+bcy9[0]+bcx9[0];
        float k = 1.f + bcsum;
        float4 cs = *(const float4*)colsum;
        float4 dv = *(const float4*)&dOt[i*4];
        float4 pa = {iv*a[0], iv*a[1], iv*a[2], iv*a[3]};
        float4 b;
        b.x = cs.x*k - imv*dv.x + iv*a[4];
        b.y = cs.y*k - imv*dv.y + iv*a[5];
        b.z = cs.z*k - imv*dv.z + iv*a[6];
        b.w = cs.w*k - imv*dv.w + iv*a[7];
        *(float4*)&ASdot[i*4] = pa;
        *(float4*)&Bv[i*4]    = b;
    }
}

// ---------- phase 6d: global min/max = conv blocks U A-range U {0,1} ----------
__global__ __launch_bounds__(256) void k_gmm(const float* __restrict__ mnmx,
        const unsigned* __restrict__ rowminenc, const unsigned* __restrict__ rowmaxenc,
        float* __restrict__ gmm){
    __shared__ float smn[256], smx[256];
    int tid = threadIdx.x;
    float mn = 0.f, mx = 1.f;   // oushi range is exactly [0,1]
    for (int i=tid; i<NN; i+=256){
        float rmx = dec_f(rowmaxenc[i]);
        float q = dec_f(rowminenc[i]) / rmx;
        mn = fminf(mn, fminf(1.f, q));
        mx = fmaxf(mx, fmaxf(1.f, q));
    }
    for (int b=tid; b<918; b+=256){   // 17 x 54 blocks
        mn = fminf(mn, mnmx[b]);
        mx = fmaxf(mx, mnmx[1024+b]);
    }
    smn[tid]=mn; smx[tid]=mx; __syncthreads();
    for (int s=128;s>0;s>>=1){
        if (tid<s){ smn[tid]=fminf(smn[tid],smn[tid+s]); smx[tid]=fmaxf(smx[tid],smx[tid+s]); }
        __syncthreads();
    }
    if (tid==0){ gmm[0]=smn[0]; gmm[1]=smx[0]; }
}

// ---------- phase 7a: row-conv of ASdot + affine -> hfin ----------
__global__ void k_hfin(const float* __restrict__ ASdot, const float* __restrict__ Bv,
        const float* __restrict__ Wcx3, const float* __restrict__ Wcx5, const float* __restrict__ Wcx9,
        const float* __restrict__ gmm, const float* __restrict__ colsum,
        float* __restrict__ hfin){
    int i = blockIdx.x*256 + threadIdx.x;
    if (i >= NN) return;
    float Cx[9];
    #pragma unroll
    for (int o=-4;o<=4;o++){
        float c = Wcx9[o+4];
        if (o>=-2 && o<=2) c += Wcx5[o+2];
        if (o>=-1 && o<=1) c += Wcx3[o+1];
        Cx[o+4] = c;
    }
    float4 h = *(const float4*)&Bv[i*4];
    float4 a0 = *(const float4*)&ASdot[i*4];
    h.x += a0.x; h.y += a0.y; h.z += a0.z; h.w += a0.w;
    #pragma unroll
    for (int o=-4;o<=4;o++){
        int r = i + o;
        if ((unsigned)r < NN){
            float4 av = *(const float4*)&ASdot[r*4];
            float c = Cx[o+4];
            h.x += c*av.x; h.y += c*av.y; h.z += c*av.z; h.w += c*av.w;
        }
    }
    float mnv = gmm[0], mxv = gmm[1];
    float s = 1.f/(mxv-mnv), oa = -mnv*s;
    float4 cs = *(const float4*)colsum;
    float4 out;
    out.x = s*h.x + 5.f*oa*cs.x;
    out.y = s*h.y + 5.f*oa*cs.y;
    out.z = s*h.z + 5.f*oa*cs.z;
    out.w = s*h.w + 5.f*oa*cs.w;
    *(float4*)&hfin[i*4] = out;
}

// ---------- phase 7b: MLP head (barrier-free epilogue) ----------
__global__ __launch_bounds__(256) void k_mlp(const float* __restrict__ hfin,
        const float* __restrict__ Woff, const float* __restrict__ boff, const float* __restrict__ pw,
        const float* __restrict__ Wf1, const float* __restrict__ bf1,
        const float* __restrict__ Wf2, const float* __restrict__ bf2,
        const float* __restrict__ Wf3, const float* __restrict__ bf3,
        float* __restrict__ out){
    __shared__ float h1[8][128];
    __shared__ float h2[8][256];
    __shared__ float h3[8][256];
    int n0 = blockIdx.x*8, tid = threadIdx.x;
    float p = pw[0];
    {
        int c = tid & 127, mb = (tid>>7)*4;
        #pragma unroll
        for (int mm=0; mm<4; mm++){
            int m = mb+mm;
            float v = boff[c];
            #pragma unroll
            for (int k=0;k<4;k++) v += hfin[(n0+m)*4+k]*Woff[k*128+c];
            h1[m][c] = v>0.f ? v : p*v;
        }
    }
    __syncthreads();
    {
        int c = tid;
        float acc[8];
        #pragma unroll
        for (int m=0;m<8;m++) acc[m] = bf1[c];
        for (int k=0;k<128;k++){
            float w = Wf1[k*256+c];
            #pragma unroll
            for (int m=0;m<8;m++) acc[m] += h1[m][k]*w;
        }
        #pragma unroll
        for (int m=0;m<8;m++) h2[m][c] = acc[m]>0.f?acc[m]:0.f;
    }
    __syncthreads();
    {
        int c = tid;
        float acc[8];
        #pragma unroll
        for (int m=0;m<8;m++) acc[m] = bf2[c];
        for (int k=0;k<256;k++){
            float w = Wf2[k*256+c];
            #pragma unroll
            for (int m=0;m<8;m++) acc[m] += h2[m][k]*w;
        }
        #pragma unroll
        for (int m=0;m<8;m++) h3[m][c] = acc[m]>0.f?acc[m]:0.f;
    }
    __syncthreads();
    // epilogue: wave w handles nodes m = 2w, 2w+1; shuffle reduce, zero barriers
    int w = tid >> 6, lane = tid & 63;
    #pragma unroll
    for (int mm=0; mm<2; ++mm){
        int m = w*2 + mm;
        float4 acc = {0,0,0,0};
        #pragma unroll
        for (int q=0;q<4;q++){
            int k = lane + q*64;
            float hv = h3[m][k];
            float4 w3 = *(const float4*)&Wf3[k*4];
            acc.x += hv*w3.x; acc.y += hv*w3.y; acc.z += hv*w3.z; acc.w += hv*w3.w;
        }
        #pragma unroll
        for (int s=1; s<64; s<<=1){
            acc.x += __shfl_xor(acc.x, s, 64);
            acc.y += __shfl_xor(acc.y, s, 64);
            acc.z += __shfl_xor(acc.z, s, 64);
            acc.w += __shfl_xor(acc.w, s, 64);
        }
        if (lane == 0){
            float4 o;
            o.x = acc.x + bf3[0]; o.y = acc.y + bf3[1];
            o.z = acc.z + bf3[2]; o.w = acc.w + bf3[3];
            *(float4*)&out[(n0+m)*4] = o;
        }
    }
}

// ---------- host ----------
extern "C" void kernel_launch(void* const* d_in, const int* in_sizes, int n_in,
                              void* d_out, int out_size, void* d_ws, size_t ws_size,
                              hipStream_t stream){
    const float* dx1  = (const float*)d_in[0];
    const float* dx2  = (const float*)d_in[1];
    const float* Wk   = (const float*)d_in[2];
    const float* bk   = (const float*)d_in[3];
    const float* Wg1  = (const float*)d_in[4];
    const float* bg1  = (const float*)d_in[5];
    const float* Wg2  = (const float*)d_in[6];
    const float* bg2  = (const float*)d_in[7];
    const float* Wq   = (const float*)d_in[8];
    const float* bq   = (const float*)d_in[9];
    const float* Wkey = (const float*)d_in[10];
    const float* bkey = (const float*)d_in[11];
    const float* Woff = (const float*)d_in[12];
    const float* boff = (const float*)d_in[13];
    const float* pw   = (const float*)d_in[14];
    const float* Wf1  = (const float*)d_in[15];
    const float* bf1  = (const float*)d_in[16];
    const float* Wf2  = (const float*)d_in[17];
    const float* bf2  = (const float*)d_in[18];
    const float* Wf3  = (const float*)d_in[19];
    const float* bf3  = (const float*)d_in[20];
    const float* Wcy3 = (const float*)d_in[21];
    const float* bcy3 = (const float*)d_in[22];
    const float* Wcx3 = (const float*)d_in[23];
    const float* bcx3 = (const float*)d_in[24];
    const float* Wcy5 = (const float*)d_in[25];
    const float* bcy5 = (const float*)d_in[26];
    const float* Wcx5 = (const float*)d_in[27];
    const float* bcx5 = (const float*)d_in[28];
    const float* Wcy9 = (const float*)d_in[29];
    const float* bcy9 = (const float*)d_in[30];
    const float* Wcx9 = (const float*)d_in[31];
    const float* bcx9 = (const float*)d_in[32];

    char* ws = (char*)d_ws;
    size_t off = 0;
    auto alloc = [&](size_t b)->void*{ void* p = ws + off; off += (b + 255) & ~(size_t)255; return p; };

    // --- zero-init region (one small memset) ---
    char* zbase = ws + off;
    float*    colsum    = (float*)   alloc(4*4);
    int*      cnt3      = (int*)     alloc((size_t)NN*4);
    int*      cnt5      = (int*)     alloc((size_t)NN*4);
    int*      cnt9      = (int*)     alloc((size_t)NN*4);
    int*      cur       = (int*)     alloc((size_t)3*NN*4);
    unsigned* rowmaxenc = (unsigned*)alloc((size_t)NN*4);
    size_t zbytes = (size_t)((ws + off) - zbase);
    unsigned* rowminenc = (unsigned*)alloc((size_t)NN*4);   // memset 0xFF

    // --- non-zeroed ---
    float*  x0    = (float*) alloc((size_t)NN*8*4);
    float2* pos   = (float2*)alloc((size_t)NN*8);
    float4* otp   = (float4*)alloc((size_t)NN*16);
    float*  maxd  = (float*) alloc((size_t)NN*4);
    int*    nbr   = (int*)   alloc((size_t)NN*9*4);
    int*    offc  = (int*)   alloc((size_t)3*NN*4);
    float*  dinvc = (float*) alloc((size_t)3*NN*4);
    int*    rev   = (int*)   alloc((size_t)NN*17*4);
    float*  xw    = (float*) alloc((size_t)NN*64*4);
    float*  y2    = (float*) alloc((size_t)3*NN*128*4);
    float*  emb   = (float*) alloc((size_t)NN*384*4);
    __bf16* qh    = (__bf16*)alloc((size_t)NN*128*2);
    __bf16* ql    = (__bf16*)alloc((size_t)NN*128*2);
    __bf16* kh    = (__bf16*)alloc((size_t)NN*128*2);
    __bf16* kl    = (__bf16*)alloc((size_t)NN*128*2);
    float* scores = (float*)alloc((size_t)NN*NN*4);
    float* Tyb    = (float*)alloc((size_t)NN*4*4);
    float* invr   = (float*)alloc((size_t)NN*4);
    float* dOt    = (float*)alloc((size_t)NN*4*4);
    float* kOt    = (float*)alloc((size_t)128*8*4);
    float* ASd    = (float*)alloc((size_t)NN*4*4);
    float* Bv     = (float*)alloc((size_t)NN*4*4);
    float* mnmx   = (float*)alloc((size_t)2*1024*4);
    float* gmm    = (float*)alloc(2*4);
    float* hfin   = (float*)alloc((size_t)NN*4*4);
    (void)ws_size; (void)in_sizes; (void)n_in; (void)out_size;

    hipMemsetAsync(zbase, 0, zbytes, stream);
    hipMemsetAsync(rowminenc, 0xFF, (size_t)NN*4, stream);

    k_prep<<<16,256,0,stream>>>(dx1,dx2,Wk,bk,x0,colsum,pos,otp);
    k_ty  <<<16,256,0,stream>>>(x0,Wcy3,Wcy5,Wcy9,Tyb);
    k_dist<<<NN/4,256,0,stream>>>(pos,otp,maxd,nbr,cnt3,cnt5,cnt9,dOt);
    k_scan<<<1,256,0,stream>>>(cnt3,cnt5,cnt9,offc,dinvc);
    k_fill<<<16,256,0,stream>>>(nbr,offc,cur,rev);

    k_y1  <<<NN*64/256,256,0,stream>>>(x0,Wg1,xw);
    k_h1y2<<<NN/4,256,0,stream>>>(xw,offc,cnt3,cnt5,cnt9,rev,dinvc,bg1,Wg2,y2);
    k_fin <<<NN*3,128,0,stream>>>(y2,offc,cnt3,cnt5,cnt9,rev,dinvc,bg2,emb);

    k_qk<<<NN/8,256,0,stream>>>(emb,Wq,bq,Wkey,bkey,qh,ql,kh,kl);
    k_scores<<<1024,256,0,stream>>>(qh,ql,kh,kl,scores,rowmaxenc,rowminenc);
    k_invr<<<16,256,0,stream>>>(rowmaxenc,invr);
    k_kot<<<128,256,0,stream>>>(kh,kl,x0,Tyb,kOt);

    k_cconv<<<dim3(17,54),256,0,stream>>>(scores,invr,
        Wcy3,Wcx3,Wcy5,Wcx5,Wcy9,Wcx9,
        bcy3,bcx3,bcy5,bcx5,bcy9,bcx9, mnmx);
    k_asd<<<NN/4,256,0,stream>>>(qh,ql,kOt,rowmaxenc,maxd,dOt,colsum,
        bcy3,bcx3,bcy5,bcx5,bcy9,bcx9, ASd, Bv);
    k_gmm<<<1,256,0,stream>>>(mnmx,rowminenc,rowmaxenc,gmm);
    k_hfin<<<16,256,0,stream>>>(ASd,Bv,Wcx3,Wcx5,Wcx9,gmm,colsum,hfin);
    k_mlp<<<NN/8,256,0,stream>>>(hfin,Woff,boff,pw,Wf1,bf1,Wf2,bf2,Wf3,bf3,(float*)d_out);
}

// Round 13
// 303.493 us; speedup vs baseline: 1.3418x; 1.0066x over previous
//
#include <hip/hip_runtime.h>
#include <math.h>

#define NN 4096

typedef __bf16 bf16x8 __attribute__((ext_vector_type(8)));
typedef float  f32x4  __attribute__((ext_vector_type(4)));

static __device__ __forceinline__ unsigned enc_f(float f){
    unsigned u = __float_as_uint(f);
    return (u & 0x80000000u) ? ~u : (u | 0x80000000u);
}
static __device__ __forceinline__ float dec_f(unsigned u){
    unsigned b = (u & 0x80000000u) ? (u & 0x7fffffffu) : ~u;
    return __uint_as_float(b);
}
static __device__ __forceinline__ float4 shfl4(float4 v, int src){
    float4 r;
    r.x = __shfl(v.x, src, 64);
    r.y = __shfl(v.y, src, 64);
    r.z = __shfl(v.z, src, 64);
    r.w = __shfl(v.w, src, 64);
    return r;
}
static __device__ __forceinline__ unsigned long long shflx_u64(unsigned long long v, int m){
    unsigned lo = __shfl_xor((unsigned)(v & 0xffffffffu), m, 64);
    unsigned hi = __shfl_xor((unsigned)(v >> 32), m, 64);
    return ((unsigned long long)hi << 32) | lo;
}

// ---------- phase 1: x0 assembly + packed pos/Ot + column sums ----------
__global__ void k_prep(const float* __restrict__ dx1, const float* __restrict__ dx2,
                       const float* __restrict__ Wk, const float* __restrict__ bk,
                       float* __restrict__ x0, float* __restrict__ colsum,
                       float2* __restrict__ pos, float4* __restrict__ otp){
    int n = blockIdx.x*blockDim.x + threadIdx.x;
    if (n >= NN) return;
    float wk[8];
    #pragma unroll
    for (int j=0;j<8;j++) wk[j] = Wk[j];
    float bkv = bk[0];
    float4 d1 = *(const float4*)&dx1[n*4];
    pos[n] = make_float2(d1.x, d1.y);
    #pragma unroll
    for (int c=0;c<4;c++) x0[n*8+c] = (&d1.x)[c];
    float4 ot;
    #pragma unroll
    for (int c=0;c<4;c++){
        float acc = bkv;
        #pragma unroll
        for (int j=0;j<8;j++) acc += dx2[(n*8+j)*4+c]*wk[j];
        x0[n*8+4+c] = acc;
        (&ot.x)[c] = acc;
        atomicAdd(&colsum[c], acc);
    }
    otp[n] = ot;
}

// ---------- phase 1b: Ty[j] = column-conv kernel applied to Ot ----------
__global__ void k_ty(const float* __restrict__ x0,
        const float* __restrict__ Wcy3, const float* __restrict__ Wcy5, const float* __restrict__ Wcy9,
        float* __restrict__ Ty){
    int j = blockIdx.x*256 + threadIdx.x;
    if (j >= NN) return;
    float Cy[9];
    #pragma unroll
    for (int o=-4;o<=4;o++){
        float c = Wcy9[o+4];
        if (o>=-2 && o<=2) c += Wcy5[o+2];
        if (o>=-1 && o<=1) c += Wcy3[o+1];
        Cy[o+4] = c;
    }
    float4 acc = {0,0,0,0};
    #pragma unroll
    for (int o=-4;o<=4;o++){
        int jj = j - o;
        if ((unsigned)jj < NN){
            float4 ot = *(const float4*)&x0[jj*8+4];
            float c = Cy[o+4];
            acc.x += c*ot.x; acc.y += c*ot.y; acc.z += c*ot.z; acc.w += c*ot.w;
        }
    }
    *(float4*)&Ty[j*4] = acc;
}

// ---------- phase 2: two-pass knn: threshold from lane-minima, ballot-compact, extract 9 ----------
#define KCAP 192
__global__ __launch_bounds__(256) void k_dist(const float2* __restrict__ pos,
        const float4* __restrict__ otp,
        float* __restrict__ maxd, int* __restrict__ nbr,
        int* __restrict__ cnt3, int* __restrict__ cnt5, int* __restrict__ cnt9,
        float* __restrict__ dOt){
    __shared__ unsigned long long cbuf[4][KCAP];
    int tid = threadIdx.x;
    int w = tid >> 6, lane = tid & 63;
    int i = blockIdx.x*4 + w;
    float2 pi = pos[i];

    // pass 1: full N work (maxd, dOt) + per-lane min
    float lmax = 0.f, lmin = INFINITY;
    float4 dacc = {0,0,0,0};
    for (int t=0;t<64;t++){
        int j = (t<<6) | lane;
        float2 p = pos[j];
        float dx = pi.x - p.x, dy = pi.y - p.y;
        float d = sqrtf(dx*dx + dy*dy);
        lmax = fmaxf(lmax, d);
        float4 otj = otp[j];
        dacc.x += d*otj.x; dacc.y += d*otj.y; dacc.z += d*otj.z; dacc.w += d*otj.w;
        if (j != i) lmin = fminf(lmin, d);
    }
    #pragma unroll
    for (int m=1;m<64;m<<=1){
        lmax = fmaxf(lmax, __shfl_xor(lmax, m, 64));
        dacc.x += __shfl_xor(dacc.x, m, 64);
        dacc.y += __shfl_xor(dacc.y, m, 64);
        dacc.z += __shfl_xor(dacc.z, m, 64);
        dacc.w += __shfl_xor(dacc.w, m, 64);
    }
    if (lane==0){
        maxd[i] = lmax;
        *(float4*)&dOt[i*4] = dacc;
    }
    // T = 9th smallest lane-min (>= global 9th smallest: valid filter threshold)
    float v = lmin, T = 0.f;
    #pragma unroll
    for (int r=0;r<9;r++){
        float m = v;
        #pragma unroll
        for (int s=1;s<64;s<<=1) m = fminf(m, __shfl_xor(m, s, 64));
        T = m;
        if (v == m) v = INFINITY;
    }

    // pass 2: ballot-compact candidates d<=T into LDS (usually 0-1 per iteration)
    int base = 0;
    for (int t=0;t<64;t++){
        int j = (t<<6) | lane;
        float2 p = pos[j];
        float dx = pi.x - p.x, dy = pi.y - p.y;
        float d = sqrtf(dx*dx + dy*dy);
        bool pass = (j != i) && (d <= T);
        unsigned long long b = __ballot(pass);
        if (b){
            int pre = __popcll(b & ((1ull<<lane)-1ull));
            int idx = base + pre;
            if (pass && idx < KCAP)
                cbuf[w][idx] = ((unsigned long long)__float_as_uint(d) << 32) | (unsigned)j;
            base += __popcll(b);
        }
    }
    int M = base < KCAP ? base : KCAP;

    // extract 9 smallest (u64 keys unique -> exact lexicographic (d,j) order)
    unsigned long long c0 = (lane      < M) ? cbuf[w][lane]      : ~0ULL;
    unsigned long long c1 = (lane+64   < M) ? cbuf[w][lane+64]   : ~0ULL;
    unsigned long long c2 = (lane+128  < M) ? cbuf[w][lane+128]  : ~0ULL;
    for (int r=0;r<9;r++){
        unsigned long long mv = c0 < c1 ? c0 : c1;
        mv = mv < c2 ? mv : c2;
        #pragma unroll
        for (int s=1;s<64;s<<=1){
            unsigned long long o = shflx_u64(mv, s);
            if (o < mv) mv = o;
        }
        if (c0 == mv) c0 = ~0ULL;
        else if (c1 == mv) c1 = ~0ULL;
        else if (c2 == mv) c2 = ~0ULL;
        if (lane == 0){
            int j = (int)(mv & 0xffffffffu);
            nbr[i*9+r] = j;
            atomicAdd(&cnt9[j], 1);
            if (r<5) atomicAdd(&cnt5[j], 1);
            if (r<3) atomicAdd(&cnt3[j], 1);
        }
    }
}

// ---------- phase 2b: CSR offsets (exclusive scan) + dinv ----------
__global__ __launch_bounds__(256) void k_scan(const int* __restrict__ cnt3,
        const int* __restrict__ cnt5, const int* __restrict__ cnt9,
        int* __restrict__ offc, float* __restrict__ dinvc){
    __shared__ int part[256];
    int tid = threadIdx.x;
    for (int g=0; g<3; g++){
        const int* cp = g==0?cnt3:(g==1?cnt5:cnt9);
        int base = tid*16;
        int loc[16]; int s=0;
        #pragma unroll
        for (int q=0;q<16;q++){ loc[q]=s; s += cp[base+q]; }
        part[tid]=s; __syncthreads();
        for (int d=1; d<256; d<<=1){
            int v = (tid>=d) ? part[tid-d] : 0;
            __syncthreads();
            part[tid] += v;
            __syncthreads();
        }
        int pre = (tid==0) ? 0 : part[tid-1];
        #pragma unroll
        for (int q=0;q<16;q++){
            offc[g*NN + base + q]  = pre + loc[q];
            dinvc[g*NN + base + q] = rsqrtf((float)cp[base+q] + 1.f);
        }
        __syncthreads();
    }
}

// ---------- phase 2c: fill reverse-edge lists ----------
__global__ void k_fill(const int* __restrict__ nbr, const int* __restrict__ offc,
        int* __restrict__ cur, int* __restrict__ rev){
    int i = blockIdx.x*256 + threadIdx.x;
    if (i >= NN) return;
    #pragma unroll
    for (int t=0;t<9;t++){
        int j = nbr[i*9+t];
        int gmin = t<3 ? 0 : (t<5 ? 1 : 2);
        for (int g=gmin; g<3; g++){
            int pos = atomicAdd(&cur[g*NN+j], 1);
            int rb = (g==0) ? 0 : (g==1 ? NN*3 : NN*8);
            rev[rb + offc[g*NN+j] + pos] = i;
        }
    }
}

// ---------- phase 3: GCN layer-1 input transform ----------
__global__ void k_y1(const float* __restrict__ x0, const float* __restrict__ Wg1,
                     float* __restrict__ xw){
    int idx = blockIdx.x*256 + threadIdx.x;
    if (idx >= NN*64) return;
    int n = idx>>6, c = idx&63;
    float acc = 0.f;
    #pragma unroll
    for (int k=0;k<8;k++) acc += x0[n*8+k]*Wg1[k*64+c];
    xw[idx] = acc;
}

// ---------- phase 3b: gather layer-1 + relu + layer-2 matmul ----------
__global__ __launch_bounds__(256) void k_h1y2(const float* __restrict__ xw,
        const int* __restrict__ offc,
        const int* __restrict__ cnt3, const int* __restrict__ cnt5, const int* __restrict__ cnt9,
        const int* __restrict__ rev, const float* __restrict__ dinvc,
        const float* __restrict__ bg1, const float* __restrict__ Wg2,
        float* __restrict__ y2){
    __shared__ float h1s[12][64];
    int n0 = blockIdx.x*4, tid = threadIdx.x;
    for (int s=tid; s<768; s+=256){
        int p = s>>6, k = s&63, g = p>>2, n = n0+(p&3);
        const int* cp = g==0?cnt3:(g==1?cnt5:cnt9);
        int rb = (g==0) ? 0 : (g==1 ? NN*3 : NN*8);
        int cnt = cp[n];
        int o = rb + offc[g*NN+n];
        float dv = dinvc[g*NN+n];
        float srow = dv*xw[n*64+k];
        for (int e=0;e<cnt;e++){
            int i = rev[o+e];
            srow += dinvc[g*NN+i]*xw[i*64+k];
        }
        float v = dv*srow + bg1[k];
        h1s[p][k] = v>0.f ? v : 0.f;
    }
    __syncthreads();
    int c = tid & 127, ph = tid>>7;
    float a6[6] = {0,0,0,0,0,0};
    for (int k=0;k<64;k++){
        float w = Wg2[k*128+c];
        #pragma unroll
        for (int q=0;q<6;q++) a6[q] += h1s[q*2+ph][k]*w;
    }
    #pragma unroll
    for (int q=0;q<6;q++){
        int p = q*2+ph, g = p>>2, n = n0+(p&3);
        float dv = dinvc[g*NN+n];
        y2[(size_t)g*NN*128 + (size_t)n*128 + c] = dv*a6[q];
    }
}

// ---------- phase 3c: gather layer-2 + bias + log_softmax ----------
__global__ __launch_bounds__(128) void k_fin(const float* __restrict__ y2,
        const int* __restrict__ offc,
        const int* __restrict__ cnt3, const int* __restrict__ cnt5, const int* __restrict__ cnt9,
        const int* __restrict__ rev, const float* __restrict__ dinvc,
        const float* __restrict__ bg2, float* __restrict__ emb){
    __shared__ float sm[2], ss[2];
    int b = blockIdx.x;
    int n = b & (NN-1), g = b >> 12;
    const int* cp = g==0?cnt3:(g==1?cnt5:cnt9);
    int rb = (g==0) ? 0 : (g==1 ? NN*3 : NN*8);
    int cnt = cp[n];
    int o = rb + offc[g*NN+n];
    float dv = dinvc[g*NN+n];
    int c = threadIdx.x;
    const float* yg = y2 + (size_t)g*NN*128;
    float s = yg[(size_t)n*128 + c];
    for (int e=0;e<cnt;e++){
        int i = rev[o+e];
        s += yg[(size_t)i*128 + c];
    }
    float v = dv*s + bg2[c];
    float m = v;
    #pragma unroll
    for (int st=1;st<64;st<<=1) m = fmaxf(m, __shfl_xor(m, st, 64));
    if ((c&63)==0) sm[c>>6] = m;
    __syncthreads();
    m = fmaxf(sm[0], sm[1]);
    float e = expf(v - m);
    float t = e;
    #pragma unroll
    for (int st=1;st<64;st<<=1) t += __shfl_xor(t, st, 64);
    if ((c&63)==0) ss[c>>6] = t;
    __syncthreads();
    t = ss[0]+ss[1];
    emb[n*384 + g*128 + c] = v - m - logf(t);
}

// ---------- phase 4: q/k projections -> bf16 hi/lo split ----------
__global__ __launch_bounds__(256) void k_qk(const float* __restrict__ emb,
        const float* __restrict__ Wq, const float* __restrict__ bq,
        const float* __restrict__ Wkey, const float* __restrict__ bkey,
        __bf16* __restrict__ qh, __bf16* __restrict__ ql,
        __bf16* __restrict__ kh, __bf16* __restrict__ kl){
    __shared__ float es[8][384];
    int n0 = blockIdx.x*8;
    int tid = threadIdx.x;
    for (int idx=tid; idx<8*384; idx+=256){
        int m = idx/384, k = idx%384;
        es[m][k] = emb[(n0+m)*384+k];
    }
    __syncthreads();
    int c = tid & 127;
    int sel = tid >> 7;
    const float* W = sel ? Wkey : Wq;
    float b = sel ? bkey[c] : bq[c];
    float acc[8];
    #pragma unroll
    for (int m=0;m<8;m++) acc[m]=b;
    for (int k=0;k<384;k++){
        float w = W[k*128+c];
        #pragma unroll
        for (int m=0;m<8;m++) acc[m] += es[m][k]*w;
    }
    __bf16* oh = sel ? kh : qh;
    __bf16* ol = sel ? kl : ql;
    #pragma unroll
    for (int m=0;m<8;m++){
        float v = acc[m];
        __bf16 h = (__bf16)v;
        oh[(size_t)(n0+m)*128+c] = h;
        ol[(size_t)(n0+m)*128+c] = (__bf16)(v - (float)h);
    }
}

// ---------- phase 5: scores = q @ k^T via bf16-split MFMA + fused row max/min ----------
__global__ __launch_bounds__(256) void k_scores(
        const __bf16* __restrict__ qh, const __bf16* __restrict__ ql,
        const __bf16* __restrict__ kh, const __bf16* __restrict__ kl,
        float* __restrict__ scores,
        unsigned* __restrict__ rowmaxenc, unsigned* __restrict__ rowminenc){
    int bx = blockIdx.x & 31;
    int by = blockIdx.x >> 5;
    int tid = threadIdx.x;
    int w = tid >> 6, lane = tid & 63;
    int li = lane & 15, g = lane >> 4;
    int r0 = by*128 + (w>>1)*64;
    int c0 = bx*128 + (w&1)*64;

    f32x4 acc[4][4] = {};
    for (int ks=0; ks<4; ++ks){
        int kofs = ks*32 + g*8;
        bf16x8 ah[4], al[4], bh[4], bl[4];
        #pragma unroll
        for (int f=0; f<4; ++f){
            ah[f] = *(const bf16x8*)&qh[(size_t)(r0+f*16+li)*128 + kofs];
            al[f] = *(const bf16x8*)&ql[(size_t)(r0+f*16+li)*128 + kofs];
            bh[f] = *(const bf16x8*)&kh[(size_t)(c0+f*16+li)*128 + kofs];
            bl[f] = *(const bf16x8*)&kl[(size_t)(c0+f*16+li)*128 + kofs];
        }
        #pragma unroll
        for (int fr=0; fr<4; ++fr){
            #pragma unroll
            for (int fc=0; fc<4; ++fc){
                acc[fr][fc] = __builtin_amdgcn_mfma_f32_16x16x32_bf16(ah[fr], bh[fc], acc[fr][fc], 0, 0, 0);
                acc[fr][fc] = __builtin_amdgcn_mfma_f32_16x16x32_bf16(ah[fr], bl[fc], acc[fr][fc], 0, 0, 0);
                acc[fr][fc] = __builtin_amdgcn_mfma_f32_16x16x32_bf16(al[fr], bh[fc], acc[fr][fc], 0, 0, 0);
            }
        }
    }
    #pragma unroll
    for (int fr=0; fr<4; ++fr){
        #pragma unroll
        for (int r=0; r<4; ++r){
            int row = r0 + fr*16 + g*4 + r;
            float mx = -INFINITY, mn = INFINITY;
            #pragma unroll
            for (int fc=0; fc<4; ++fc){
                float v = acc[fr][fc][r];
                scores[(size_t)row*NN + c0 + fc*16 + li] = v;
                mx = fmaxf(mx, v);
                mn = fminf(mn, v);
            }
            #pragma unroll
            for (int s=1; s<16; s<<=1){
                mx = fmaxf(mx, __shfl_xor(mx, s, 64));
                mn = fminf(mn, __shfl_xor(mn, s, 64));
            }
            if (li == 0){
                atomicMax(&rowmaxenc[row], enc_f(mx));
                atomicMin(&rowminenc[row], enc_f(mn));
            }
        }
    }
}

// ---------- phase 5b: invr = 1/rowmax ----------
__global__ void k_invr(const unsigned* __restrict__ rowmaxenc, float* __restrict__ invr){
    int i = blockIdx.x*256 + threadIdx.x;
    if (i >= NN) return;
    invr[i] = 1.f/dec_f(rowmaxenc[i]);
}

// ---------- phase 6: streaming conv min/max over A, float4/lane ----------
__global__ __launch_bounds__(256) void k_cconv(const float* __restrict__ scores,
        const float* __restrict__ invr,
        const float* __restrict__ Wcy3, const float* __restrict__ Wcx3,
        const float* __restrict__ Wcy5, const float* __restrict__ Wcx5,
        const float* __restrict__ Wcy9, const float* __restrict__ Wcx9,
        const float* __restrict__ bcy3, const float* __restrict__ bcx3,
        const float* __restrict__ bcy5, const float* __restrict__ bcx5,
        const float* __restrict__ bcy9, const float* __restrict__ bcx9,
        float* __restrict__ mnmx){
    __shared__ float smn[4], smx[4];
    int tid = threadIdx.x;
    int w = tid >> 6, lane = tid & 63;
    int strip = blockIdx.x;                       // 0..16
    int i0 = (blockIdx.y*4 + w)*19;
    int colbase = strip*248 - 4 + lane*4;
    bool lv = (colbase >= 0) && (colbase + 3 < NN);
    bool outLane = (lane >= 1) && (lane < 63) && lv;

    float wy3[3],wx3[3],wy5[5],wx5[5],wy9[9],wx9[9];
    #pragma unroll
    for (int t=0;t<3;t++){ wy3[t]=Wcy3[t]; wx3[t]=Wcx3[t]; }
    #pragma unroll
    for (int t=0;t<5;t++){ wy5[t]=Wcy5[t]; wx5[t]=Wcx5[t]; }
    #pragma unroll
    for (int t=0;t<9;t++){ wy9[t]=Wcy9[t]; wx9[t]=Wcx9[t]; }
    float bc3 = bcy3[0]+bcx3[0];
    float bc5 = bcy5[0]+bcx5[0];
    float bc9 = bcy9[0]+bcx9[0];

    float4 win[9];
    float mn = INFINITY, mx = -INFINITY;
    const int laneL = lane - 1, laneR = lane + 1;

    for (int tb = 0; tb < 3; ++tb){
        #pragma unroll
        for (int u = 0; u < 9; ++u){
            int t  = tb*9 + u;
            int ri = i0 - 4 + t;
            float4 a = make_float4(0,0,0,0);
            if (((unsigned)ri < NN) && lv){
                float iv = invr[ri];
                float4 v = *(const float4*)&scores[(size_t)ri*NN + colbase];
                a.x = v.x*iv; a.y = v.y*iv; a.z = v.z*iv; a.w = v.w*iv;
            }
            win[u] = a;
            int ro = i0 + t - 8;
            if (t >= 8 && ro < NN){
                float4 ctr = win[(u+5)%9];
                float4 wl = shfl4(ctr, laneL);
                float4 wr = shfl4(ctr, laneR);
                if (outLane){
                    float cw[12] = {wl.x,wl.y,wl.z,wl.w, ctr.x,ctr.y,ctr.z,ctr.w, wr.x,wr.y,wr.z,wr.w};
                    #pragma unroll
                    for (int c=0;c<4;c++){
                        float cx9 = ((win[(u+1)%9][c]*wx9[0] + win[(u+2)%9][c]*wx9[1]) + (win[(u+3)%9][c]*wx9[2] + win[(u+4)%9][c]*wx9[3]))
                                  + ((win[(u+5)%9][c]*wx9[4] + win[(u+6)%9][c]*wx9[5]) + (win[(u+7)%9][c]*wx9[6] + win[(u+8)%9][c]*wx9[7]))
                                  + win[u][c]*wx9[8];
                        float cx5 = ((win[(u+3)%9][c]*wx5[0] + win[(u+4)%9][c]*wx5[1]) + (win[(u+5)%9][c]*wx5[2] + win[(u+6)%9][c]*wx5[3]))
                                  + win[(u+7)%9][c]*wx5[4];
                        float cx3 = (win[(u+4)%9][c]*wx3[0] + win[(u+5)%9][c]*wx3[1]) + win[(u+6)%9][c]*wx3[2];
                        float cy9 = ((cw[c+0]*wy9[0] + cw[c+1]*wy9[1]) + (cw[c+2]*wy9[2] + cw[c+3]*wy9[3]))
                                  + ((cw[c+4]*wy9[4] + cw[c+5]*wy9[5]) + (cw[c+6]*wy9[6] + cw[c+7]*wy9[7]))
                                  + cw[c+8]*wy9[8];
                        float cy5 = ((cw[c+2]*wy5[0] + cw[c+3]*wy5[1]) + (cw[c+4]*wy5[2] + cw[c+5]*wy5[3]))
                                  + cw[c+6]*wy5[4];
                        float cy3 = (cw[c+3]*wy3[0] + cw[c+4]*wy3[1]) + cw[c+5]*wy3[2];
                        float c3v = cy3+cx3+bc3, c5v = cy5+cx5+bc5, c9v = cy9+cx9+bc9;
                        mn = fminf(mn, fminf(fminf(c3v,c5v),c9v));
                        mx = fmaxf(mx, fmaxf(fmaxf(c3v,c5v),c9v));
                    }
                }
            }
        }
    }
    #pragma unroll
    for (int m=1; m<64; m<<=1){
        mn = fminf(mn, __shfl_xor(mn, m, 64));
        mx = fmaxf(mx, __shfl_xor(mx, m, 64));
    }
    if (lane == 0){ smn[w] = mn; smx[w] = mx; }
    __syncthreads();
    if (tid == 0){
        float a0 = fminf(fminf(smn[0],smn[1]), fminf(smn[2],smn[3]));
        float b0 = fmaxf(fmaxf(smx[0],smx[1]), fmaxf(smx[2],smx[3]));
        int bid = blockIdx.y*gridDim.x + blockIdx.x;
        mnmx[bid] = a0;
        mnmx[1024 + bid] = b0;
    }
}

// ---------- phase 6b: kOt[d][0:4]=sum_j k[j][d]*Ot[j], [4:8]=...*Ty[j] ----------
__global__ __launch_bounds__(256) void k_kot(const __bf16* __restrict__ kh, const __bf16* __restrict__ kl,
        const float* __restrict__ x0, const float* __restrict__ Ty,
        float* __restrict__ kOt){
    __shared__ float red[256][8];
    int d = blockIdx.x, tid = threadIdx.x;
    float a[8] = {0,0,0,0,0,0,0,0};
    for (int j = tid; j < NN; j += 256){
        float kv = (float)kh[(size_t)j*128 + d] + (float)kl[(size_t)j*128 + d];
        float4 ot = *(const float4*)&x0[j*8+4];
        float4 ty = *(const float4*)&Ty[j*4];
        a[0] += kv*ot.x; a[1] += kv*ot.y; a[2] += kv*ot.z; a[3] += kv*ot.w;
        a[4] += kv*ty.x; a[5] += kv*ty.y; a[6] += kv*ty.z; a[7] += kv*ty.w;
    }
    #pragma unroll
    for (int q=0;q<8;q++) red[tid][q] = a[q];
    __syncthreads();
    for (int s=128; s>0; s>>=1){
        if (tid < s){
            #pragma unroll
            for (int q=0;q<8;q++) red[tid][q] += red[tid+s][q];
        }
        __syncthreads();
    }
    if (tid < 8) kOt[d*8 + tid] = red[0][tid];
}

// ---------- phase 6c: ASd = invr*(q@kOt), Bv from q@kTy + closed-form ----------
__global__ __launch_bounds__(256) void k_asd(
        const __bf16* __restrict__ qh, const __bf16* __restrict__ ql,
        const float* __restrict__ kOt,
        const unsigned* __restrict__ rowmaxenc, const float* __restrict__ maxd,
        const float* __restrict__ dOt, const float* __restrict__ colsum,
        const float* __restrict__ bcy3, const float* __restrict__ bcx3,
        const float* __restrict__ bcy5, const float* __restrict__ bcx5,
        const float* __restrict__ bcy9, const float* __restrict__ bcx9,
        float* __restrict__ ASdot, float* __restrict__ Bv){
    __shared__ float kst[128*8];
    int tid = threadIdx.x;
    for (int s = tid; s < 1024; s += 256) kst[s] = kOt[s];
    __syncthreads();
    int lane = tid & 63, r = tid >> 6;
    int i = blockIdx.x*4 + r;
    float a[8] = {0,0,0,0,0,0,0,0};
    #pragma unroll
    for (int dd=0; dd<2; ++dd){
        int d = lane + dd*64;
        float qv = (float)qh[(size_t)i*128 + d] + (float)ql[(size_t)i*128 + d];
        #pragma unroll
        for (int q=0;q<8;q++) a[q] += qv * kst[d*8+q];
    }
    #pragma unroll
    for (int m=1; m<64; m<<=1){
        #pragma unroll
        for (int q=0;q<8;q++) a[q] += __shfl_xor(a[q], m, 64);
    }
    if (lane == 0){
        float iv = 1.f/dec_f(rowmaxenc[i]);
        float imv = 1.f/maxd[i];
        float bcsum = bcy3[0]+bcx3[0]+bcy5[0]+bcx5[0]+bcy9[0]+bcx9[0];
        float k = 1.f + bcsum;
        float4 cs = *(const float4*)colsum;
        float4 dv = *(const float4*)&dOt[i*4];
        float4 pa = {iv*a[0], iv*a[1], iv*a[2], iv*a[3]};
        float4 b;
        b.x = cs.x*k - imv*dv.x + iv*a[4];
        b.y = cs.y*k - imv*dv.y + iv*a[5];
        b.z = cs.z*k - imv*dv.z + iv*a[6];
        b.w = cs.w*k - imv*dv.w + iv*a[7];
        *(float4*)&ASdot[i*4] = pa;
        *(float4*)&Bv[i*4]    = b;
    }
}

// ---------- phase 6d: global min/max = conv blocks U A-range U {0,1} ----------
__global__ __launch_bounds__(256) void k_gmm(const float* __restrict__ mnmx,
        const unsigned* __restrict__ rowminenc, const unsigned* __restrict__ rowmaxenc,
        float* __restrict__ gmm){
    __shared__ float smn[256], smx[256];
    int tid = threadIdx.x;
    float mn = 0.f, mx = 1.f;   // oushi range is exactly [0,1]
    for (int i=tid; i<NN; i+=256){
        float rmx = dec_f(rowmaxenc[i]);
        float q = dec_f(rowminenc[i]) / rmx;
        mn = fminf(mn, fminf(1.f, q));
        mx = fmaxf(mx, fmaxf(1.f, q));
    }
    for (int b=tid; b<918; b+=256){   // 17 x 54 blocks
        mn = fminf(mn, mnmx[b]);
        mx = fmaxf(mx, mnmx[1024+b]);
    }
    smn[tid]=mn; smx[tid]=mx; __syncthreads();
    for (int s=128;s>0;s>>=1){
        if (tid<s){ smn[tid]=fminf(smn[tid],smn[tid+s]); smx[tid]=fmaxf(smx[tid],smx[tid+s]); }
        __syncthreads();
    }
    if (tid==0){ gmm[0]=smn[0]; gmm[1]=smx[0]; }
}

// ---------- phase 7a: row-conv of ASdot + affine -> hfin ----------
__global__ void k_hfin(const float* __restrict__ ASdot, const float* __restrict__ Bv,
        const float* __restrict__ Wcx3, const float* __restrict__ Wcx5, const float* __restrict__ Wcx9,
        const float* __restrict__ gmm, const float* __restrict__ colsum,
        float* __restrict__ hfin){
    int i = blockIdx.x*256 + threadIdx.x;
    if (i >= NN) return;
    float Cx[9];
    #pragma unroll
    for (int o=-4;o<=4;o++){
        float c = Wcx9[o+4];
        if (o>=-2 && o<=2) c += Wcx5[o+2];
        if (o>=-1 && o<=1) c += Wcx3[o+1];
        Cx[o+4] = c;
    }
    float4 h = *(const float4*)&Bv[i*4];
    float4 a0 = *(const float4*)&ASdot[i*4];
    h.x += a0.x; h.y += a0.y; h.z += a0.z; h.w += a0.w;
    #pragma unroll
    for (int o=-4;o<=4;o++){
        int r = i + o;
        if ((unsigned)r < NN){
            float4 av = *(const float4*)&ASdot[r*4];
            float c = Cx[o+4];
            h.x += c*av.x; h.y += c*av.y; h.z += c*av.z; h.w += c*av.w;
        }
    }
    float mnv = gmm[0], mxv = gmm[1];
    float s = 1.f/(mxv-mnv), oa = -mnv*s;
    float4 cs = *(const float4*)colsum;
    float4 out;
    out.x = s*h.x + 5.f*oa*cs.x;
    out.y = s*h.y + 5.f*oa*cs.y;
    out.z = s*h.z + 5.f*oa*cs.z;
    out.w = s*h.w + 5.f*oa*cs.w;
    *(float4*)&hfin[i*4] = out;
}

// ---------- phase 7b: MLP head (barrier-free epilogue) ----------
__global__ __launch_bounds__(256) void k_mlp(const float* __restrict__ hfin,
        const float* __restrict__ Woff, const float* __restrict__ boff, const float* __restrict__ pw,
        const float* __restrict__ Wf1, const float* __restrict__ bf1,
        const float* __restrict__ Wf2, const float* __restrict__ bf2,
        const float* __restrict__ Wf3, const float* __restrict__ bf3,
        float* __restrict__ out){
    __shared__ float h1[8][128];
    __shared__ float h2[8][256];
    __shared__ float h3[8][256];
    int n0 = blockIdx.x*8, tid = threadIdx.x;
    float p = pw[0];
    {
        int c = tid & 127, mb = (tid>>7)*4;
        #pragma unroll
        for (int mm=0; mm<4; mm++){
            int m = mb+mm;
            float v = boff[c];
            #pragma unroll
            for (int k=0;k<4;k++) v += hfin[(n0+m)*4+k]*Woff[k*128+c];
            h1[m][c] = v>0.f ? v : p*v;
        }
    }
    __syncthreads();
    {
        int c = tid;
        float acc[8];
        #pragma unroll
        for (int m=0;m<8;m++) acc[m] = bf1[c];
        for (int k=0;k<128;k++){
            float w = Wf1[k*256+c];
            #pragma unroll
            for (int m=0;m<8;m++) acc[m] += h1[m][k]*w;
        }
        #pragma unroll
        for (int m=0;m<8;m++) h2[m][c] = acc[m]>0.f?acc[m]:0.f;
    }
    __syncthreads();
    {
        int c = tid;
        float acc[8];
        #pragma unroll
        for (int m=0;m<8;m++) acc[m] = bf2[c];
        for (int k=0;k<256;k++){
            float w = Wf2[k*256+c];
            #pragma unroll
            for (int m=0;m<8;m++) acc[m] += h2[m][k]*w;
        }
        #pragma unroll
        for (int m=0;m<8;m++) h3[m][c] = acc[m]>0.f?acc[m]:0.f;
    }
    __syncthreads();
    int w = tid >> 6, lane = tid & 63;
    #pragma unroll
    for (int mm=0; mm<2; ++mm){
        int m = w*2 + mm;
        float4 acc = {0,0,0,0};
        #pragma unroll
        for (int q=0;q<4;q++){
            int k = lane + q*64;
            float hv = h3[m][k];
            float4 w3 = *(const float4*)&Wf3[k*4];
            acc.x += hv*w3.x; acc.y += hv*w3.y; acc.z += hv*w3.z; acc.w += hv*w3.w;
        }
        #pragma unroll
        for (int s=1; s<64; s<<=1){
            acc.x += __shfl_xor(acc.x, s, 64);
            acc.y += __shfl_xor(acc.y, s, 64);
            acc.z += __shfl_xor(acc.z, s, 64);
            acc.w += __shfl_xor(acc.w, s, 64);
        }
        if (lane == 0){
            float4 o;
            o.x = acc.x + bf3[0]; o.y = acc.y + bf3[1];
            o.z = acc.z + bf3[2]; o.w = acc.w + bf3[3];
            *(float4*)&out[(n0+m)*4] = o;
        }
    }
}

// ---------- host ----------
extern "C" void kernel_launch(void* const* d_in, const int* in_sizes, int n_in,
                              void* d_out, int out_size, void* d_ws, size_t ws_size,
                              hipStream_t stream){
    const float* dx1  = (const float*)d_in[0];
    const float* dx2  = (const float*)d_in[1];
    const float* Wk   = (const float*)d_in[2];
    const float* bk   = (const float*)d_in[3];
    const float* Wg1  = (const float*)d_in[4];
    const float* bg1  = (const float*)d_in[5];
    const float* Wg2  = (const float*)d_in[6];
    const float* bg2  = (const float*)d_in[7];
    const float* Wq   = (const float*)d_in[8];
    const float* bq   = (const float*)d_in[9];
    const float* Wkey = (const float*)d_in[10];
    const float* bkey = (const float*)d_in[11];
    const float* Woff = (const float*)d_in[12];
    const float* boff = (const float*)d_in[13];
    const float* pw   = (const float*)d_in[14];
    const float* Wf1  = (const float*)d_in[15];
    const float* bf1  = (const float*)d_in[16];
    const float* Wf2  = (const float*)d_in[17];
    const float* bf2  = (const float*)d_in[18];
    const float* Wf3  = (const float*)d_in[19];
    const float* bf3  = (const float*)d_in[20];
    const float* Wcy3 = (const float*)d_in[21];
    const float* bcy3 = (const float*)d_in[22];
    const float* Wcx3 = (const float*)d_in[23];
    const float* bcx3 = (const float*)d_in[24];
    const float* Wcy5 = (const float*)d_in[25];
    const float* bcy5 = (const float*)d_in[26];
    const float* Wcx5 = (const float*)d_in[27];
    const float* bcx5 = (const float*)d_in[28];
    const float* Wcy9 = (const float*)d_in[29];
    const float* bcy9 = (const float*)d_in[30];
    const float* Wcx9 = (const float*)d_in[31];
    const float* bcx9 = (const float*)d_in[32];

    char* ws = (char*)d_ws;
    size_t off = 0;
    auto alloc = [&](size_t b)->void*{ void* p = ws + off; off += (b + 255) & ~(size_t)255; return p; };

    // --- zero-init region (one small memset) ---
    char* zbase = ws + off;
    float*    colsum    = (float*)   alloc(4*4);
    int*      cnt3      = (int*)     alloc((size_t)NN*4);
    int*      cnt5      = (int*)     alloc((size_t)NN*4);
    int*      cnt9      = (int*)     alloc((size_t)NN*4);
    int*      cur       = (int*)     alloc((size_t)3*NN*4);
    unsigned* rowmaxenc = (unsigned*)alloc((size_t)NN*4);
    size_t zbytes = (size_t)((ws + off) - zbase);
    unsigned* rowminenc = (unsigned*)alloc((size_t)NN*4);   // memset 0xFF

    // --- non-zeroed ---
    float*  x0    = (float*) alloc((size_t)NN*8*4);
    float2* pos   = (float2*)alloc((size_t)NN*8);
    float4* otp   = (float4*)alloc((size_t)NN*16);
    float*  maxd  = (float*) alloc((size_t)NN*4);
    int*    nbr   = (int*)   alloc((size_t)NN*9*4);
    int*    offc  = (int*)   alloc((size_t)3*NN*4);
    float*  dinvc = (float*) alloc((size_t)3*NN*4);
    int*    rev   = (int*)   alloc((size_t)NN*17*4);
    float*  xw    = (float*) alloc((size_t)NN*64*4);
    float*  y2    = (float*) alloc((size_t)3*NN*128*4);
    float*  emb   = (float*) alloc((size_t)NN*384*4);
    __bf16* qh    = (__bf16*)alloc((size_t)NN*128*2);
    __bf16* ql    = (__bf16*)alloc((size_t)NN*128*2);
    __bf16* kh    = (__bf16*)alloc((size_t)NN*128*2);
    __bf16* kl    = (__bf16*)alloc((size_t)NN*128*2);
    float* scores = (float*)alloc((size_t)NN*NN*4);
    float* Tyb    = (float*)alloc((size_t)NN*4*4);
    float* invr   = (float*)alloc((size_t)NN*4);
    float* dOt    = (float*)alloc((size_t)NN*4*4);
    float* kOt    = (float*)alloc((size_t)128*8*4);
    float* ASd    = (float*)alloc((size_t)NN*4*4);
    float* Bv     = (float*)alloc((size_t)NN*4*4);
    float* mnmx   = (float*)alloc((size_t)2*1024*4);
    float* gmm    = (float*)alloc(2*4);
    float* hfin   = (float*)alloc((size_t)NN*4*4);
    (void)ws_size; (void)in_sizes; (void)n_in; (void)out_size;

    hipMemsetAsync(zbase, 0, zbytes, stream);
    hipMemsetAsync(rowminenc, 0xFF, (size_t)NN*4, stream);

    k_prep<<<16,256,0,stream>>>(dx1,dx2,Wk,bk,x0,colsum,pos,otp);
    k_ty  <<<16,256,0,stream>>>(x0,Wcy3,Wcy5,Wcy9,Tyb);
    k_dist<<<NN/4,256,0,stream>>>(pos,otp,maxd,nbr,cnt3,cnt5,cnt9,dOt);
    k_scan<<<1,256,0,stream>>>(cnt3,cnt5,cnt9,offc,dinvc);
    k_fill<<<16,256,0,stream>>>(nbr,offc,cur,rev);

    k_y1  <<<NN*64/256,256,0,stream>>>(x0,Wg1,xw);
    k_h1y2<<<NN/4,256,0,stream>>>(xw,offc,cnt3,cnt5,cnt9,rev,dinvc,bg1,Wg2,y2);
    k_fin <<<NN*3,128,0,stream>>>(y2,offc,cnt3,cnt5,cnt9,rev,dinvc,bg2,emb);

    k_qk<<<NN/8,256,0,stream>>>(emb,Wq,bq,Wkey,bkey,qh,ql,kh,kl);
    k_scores<<<1024,256,0,stream>>>(qh,ql,kh,kl,scores,rowmaxenc,rowminenc);
    k_invr<<<16,256,0,stream>>>(rowmaxenc,invr);
    k_kot<<<128,256,0,stream>>>(kh,kl,x0,Tyb,kOt);

    k_cconv<<<dim3(17,54),256,0,stream>>>(scores,invr,
        Wcy3,Wcx3,Wcy5,Wcx5,Wcy9,Wcx9,
        bcy3,bcx3,bcy5,bcx5,bcy9,bcx9, mnmx);
    k_asd<<<NN/4,256,0,stream>>>(qh,ql,kOt,rowmaxenc,maxd,dOt,colsum,
        bcy3,bcx3,bcy5,bcx5,bcy9,bcx9, ASd, Bv);
    k_gmm<<<1,256,0,stream>>>(mnmx,rowminenc,rowmaxenc,gmm);
    k_hfin<<<16,256,0,stream>>>(ASd,Bv,Wcx3,Wcx5,Wcx9,gmm,colsum,hfin);
    k_mlp<<<NN/8,256,0,stream>>>(hfin,Woff,boff,pw,Wf1,bf1,Wf2,bf2,Wf3,bf3,(float*)d_out);
}

// Round 14
// 302.785 us; speedup vs baseline: 1.3449x; 1.0023x over previous
//
#include <hip/hip_runtime.h>
#include <math.h>

#define NN 4096

typedef __bf16 bf16x8 __attribute__((ext_vector_type(8)));
typedef float  f32x4  __attribute__((ext_vector_type(4)));
typedef _Float16 half4 __attribute__((ext_vector_type(4)));

static __device__ __forceinline__ unsigned enc_f(float f){
    unsigned u = __float_as_uint(f);
    return (u & 0x80000000u) ? ~u : (u | 0x80000000u);
}
static __device__ __forceinline__ float dec_f(unsigned u){
    unsigned b = (u & 0x80000000u) ? (u & 0x7fffffffu) : ~u;
    return __uint_as_float(b);
}
static __device__ __forceinline__ float4 shfl4(float4 v, int src){
    float4 r;
    r.x = __shfl(v.x, src, 64);
    r.y = __shfl(v.y, src, 64);
    r.z = __shfl(v.z, src, 64);
    r.w = __shfl(v.w, src, 64);
    return r;
}
static __device__ __forceinline__ unsigned long long shflx_u64(unsigned long long v, int m){
    unsigned lo = __shfl_xor((unsigned)(v & 0xffffffffu), m, 64);
    unsigned hi = __shfl_xor((unsigned)(v >> 32), m, 64);
    return ((unsigned long long)hi << 32) | lo;
}

// ---------- phase 1: x0 assembly + packed pos/Ot + column sums ----------
__global__ void k_prep(const float* __restrict__ dx1, const float* __restrict__ dx2,
                       const float* __restrict__ Wk, const float* __restrict__ bk,
                       float* __restrict__ x0, float* __restrict__ colsum,
                       float2* __restrict__ pos, float4* __restrict__ otp){
    int n = blockIdx.x*blockDim.x + threadIdx.x;
    if (n >= NN) return;
    float wk[8];
    #pragma unroll
    for (int j=0;j<8;j++) wk[j] = Wk[j];
    float bkv = bk[0];
    float4 d1 = *(const float4*)&dx1[n*4];
    pos[n] = make_float2(d1.x, d1.y);
    #pragma unroll
    for (int c=0;c<4;c++) x0[n*8+c] = (&d1.x)[c];
    float4 ot;
    #pragma unroll
    for (int c=0;c<4;c++){
        float acc = bkv;
        #pragma unroll
        for (int j=0;j<8;j++) acc += dx2[(n*8+j)*4+c]*wk[j];
        x0[n*8+4+c] = acc;
        (&ot.x)[c] = acc;
        atomicAdd(&colsum[c], acc);
    }
    otp[n] = ot;
}

// ---------- phase 1b: Ty[j] = column-conv kernel applied to Ot ----------
__global__ void k_ty(const float* __restrict__ x0,
        const float* __restrict__ Wcy3, const float* __restrict__ Wcy5, const float* __restrict__ Wcy9,
        float* __restrict__ Ty){
    int j = blockIdx.x*256 + threadIdx.x;
    if (j >= NN) return;
    float Cy[9];
    #pragma unroll
    for (int o=-4;o<=4;o++){
        float c = Wcy9[o+4];
        if (o>=-2 && o<=2) c += Wcy5[o+2];
        if (o>=-1 && o<=1) c += Wcy3[o+1];
        Cy[o+4] = c;
    }
    float4 acc = {0,0,0,0};
    #pragma unroll
    for (int o=-4;o<=4;o++){
        int jj = j - o;
        if ((unsigned)jj < NN){
            float4 ot = *(const float4*)&x0[jj*8+4];
            float c = Cy[o+4];
            acc.x += c*ot.x; acc.y += c*ot.y; acc.z += c*ot.z; acc.w += c*ot.w;
        }
    }
    *(float4*)&Ty[j*4] = acc;
}

// ---------- phase 2: two-pass knn: threshold from lane-minima, ballot-compact, extract 9 ----------
#define KCAP 192
__global__ __launch_bounds__(256) void k_dist(const float2* __restrict__ pos,
        const float4* __restrict__ otp,
        float* __restrict__ maxd, int* __restrict__ nbr,
        int* __restrict__ cnt3, int* __restrict__ cnt5, int* __restrict__ cnt9,
        float* __restrict__ dOt){
    __shared__ unsigned long long cbuf[4][KCAP];
    int tid = threadIdx.x;
    int w = tid >> 6, lane = tid & 63;
    int i = blockIdx.x*4 + w;
    float2 pi = pos[i];

    float lmax = 0.f, lmin = INFINITY;
    float4 dacc = {0,0,0,0};
    for (int t=0;t<64;t++){
        int j = (t<<6) | lane;
        float2 p = pos[j];
        float dx = pi.x - p.x, dy = pi.y - p.y;
        float d = sqrtf(dx*dx + dy*dy);
        lmax = fmaxf(lmax, d);
        float4 otj = otp[j];
        dacc.x += d*otj.x; dacc.y += d*otj.y; dacc.z += d*otj.z; dacc.w += d*otj.w;
        if (j != i) lmin = fminf(lmin, d);
    }
    #pragma unroll
    for (int m=1;m<64;m<<=1){
        lmax = fmaxf(lmax, __shfl_xor(lmax, m, 64));
        dacc.x += __shfl_xor(dacc.x, m, 64);
        dacc.y += __shfl_xor(dacc.y, m, 64);
        dacc.z += __shfl_xor(dacc.z, m, 64);
        dacc.w += __shfl_xor(dacc.w, m, 64);
    }
    if (lane==0){
        maxd[i] = lmax;
        *(float4*)&dOt[i*4] = dacc;
    }
    float v = lmin, T = 0.f;
    #pragma unroll
    for (int r=0;r<9;r++){
        float m = v;
        #pragma unroll
        for (int s=1;s<64;s<<=1) m = fminf(m, __shfl_xor(m, s, 64));
        T = m;
        if (v == m) v = INFINITY;
    }

    int base = 0;
    for (int t=0;t<64;t++){
        int j = (t<<6) | lane;
        float2 p = pos[j];
        float dx = pi.x - p.x, dy = pi.y - p.y;
        float d = sqrtf(dx*dx + dy*dy);
        bool pass = (j != i) && (d <= T);
        unsigned long long b = __ballot(pass);
        if (b){
            int pre = __popcll(b & ((1ull<<lane)-1ull));
            int idx = base + pre;
            if (pass && idx < KCAP)
                cbuf[w][idx] = ((unsigned long long)__float_as_uint(d) << 32) | (unsigned)j;
            base += __popcll(b);
        }
    }
    int M = base < KCAP ? base : KCAP;

    unsigned long long c0 = (lane      < M) ? cbuf[w][lane]      : ~0ULL;
    unsigned long long c1 = (lane+64   < M) ? cbuf[w][lane+64]   : ~0ULL;
    unsigned long long c2 = (lane+128  < M) ? cbuf[w][lane+128]  : ~0ULL;
    for (int r=0;r<9;r++){
        unsigned long long mv = c0 < c1 ? c0 : c1;
        mv = mv < c2 ? mv : c2;
        #pragma unroll
        for (int s=1;s<64;s<<=1){
            unsigned long long o = shflx_u64(mv, s);
            if (o < mv) mv = o;
        }
        if (c0 == mv) c0 = ~0ULL;
        else if (c1 == mv) c1 = ~0ULL;
        else if (c2 == mv) c2 = ~0ULL;
        if (lane == 0){
            int j = (int)(mv & 0xffffffffu);
            nbr[i*9+r] = j;
            atomicAdd(&cnt9[j], 1);
            if (r<5) atomicAdd(&cnt5[j], 1);
            if (r<3) atomicAdd(&cnt3[j], 1);
        }
    }
}

// ---------- phase 2b: CSR offsets (exclusive scan) + dinv ----------
__global__ __launch_bounds__(256) void k_scan(const int* __restrict__ cnt3,
        const int* __restrict__ cnt5, const int* __restrict__ cnt9,
        int* __restrict__ offc, float* __restrict__ dinvc){
    __shared__ int part[256];
    int tid = threadIdx.x;
    for (int g=0; g<3; g++){
        const int* cp = g==0?cnt3:(g==1?cnt5:cnt9);
        int base = tid*16;
        int loc[16]; int s=0;
        #pragma unroll
        for (int q=0;q<16;q++){ loc[q]=s; s += cp[base+q]; }
        part[tid]=s; __syncthreads();
        for (int d=1; d<256; d<<=1){
            int v = (tid>=d) ? part[tid-d] : 0;
            __syncthreads();
            part[tid] += v;
            __syncthreads();
        }
        int pre = (tid==0) ? 0 : part[tid-1];
        #pragma unroll
        for (int q=0;q<16;q++){
            offc[g*NN + base + q]  = pre + loc[q];
            dinvc[g*NN + base + q] = rsqrtf((float)cp[base+q] + 1.f);
        }
        __syncthreads();
    }
}

// ---------- phase 2c: fill reverse-edge lists ----------
__global__ void k_fill(const int* __restrict__ nbr, const int* __restrict__ offc,
        int* __restrict__ cur, int* __restrict__ rev){
    int i = blockIdx.x*256 + threadIdx.x;
    if (i >= NN) return;
    #pragma unroll
    for (int t=0;t<9;t++){
        int j = nbr[i*9+t];
        int gmin = t<3 ? 0 : (t<5 ? 1 : 2);
        for (int g=gmin; g<3; g++){
            int pos = atomicAdd(&cur[g*NN+j], 1);
            int rb = (g==0) ? 0 : (g==1 ? NN*3 : NN*8);
            rev[rb + offc[g*NN+j] + pos] = i;
        }
    }
}

// ---------- phase 3: GCN layer-1 input transform ----------
__global__ void k_y1(const float* __restrict__ x0, const float* __restrict__ Wg1,
                     float* __restrict__ xw){
    int idx = blockIdx.x*256 + threadIdx.x;
    if (idx >= NN*64) return;
    int n = idx>>6, c = idx&63;
    float acc = 0.f;
    #pragma unroll
    for (int k=0;k<8;k++) acc += x0[n*8+k]*Wg1[k*64+c];
    xw[idx] = acc;
}

// ---------- phase 3b: gather layer-1 + relu + layer-2 matmul ----------
__global__ __launch_bounds__(256) void k_h1y2(const float* __restrict__ xw,
        const int* __restrict__ offc,
        const int* __restrict__ cnt3, const int* __restrict__ cnt5, const int* __restrict__ cnt9,
        const int* __restrict__ rev, const float* __restrict__ dinvc,
        const float* __restrict__ bg1, const float* __restrict__ Wg2,
        float* __restrict__ y2){
    __shared__ float h1s[12][64];
    int n0 = blockIdx.x*4, tid = threadIdx.x;
    for (int s=tid; s<768; s+=256){
        int p = s>>6, k = s&63, g = p>>2, n = n0+(p&3);
        const int* cp = g==0?cnt3:(g==1?cnt5:cnt9);
        int rb = (g==0) ? 0 : (g==1 ? NN*3 : NN*8);
        int cnt = cp[n];
        int o = rb + offc[g*NN+n];
        float dv = dinvc[g*NN+n];
        float srow = dv*xw[n*64+k];
        for (int e=0;e<cnt;e++){
            int i = rev[o+e];
            srow += dinvc[g*NN+i]*xw[i*64+k];
        }
        float v = dv*srow + bg1[k];
        h1s[p][k] = v>0.f ? v : 0.f;
    }
    __syncthreads();
    int c = tid & 127, ph = tid>>7;
    float a6[6] = {0,0,0,0,0,0};
    for (int k=0;k<64;k++){
        float w = Wg2[k*128+c];
        #pragma unroll
        for (int q=0;q<6;q++) a6[q] += h1s[q*2+ph][k]*w;
    }
    #pragma unroll
    for (int q=0;q<6;q++){
        int p = q*2+ph, g = p>>2, n = n0+(p&3);
        float dv = dinvc[g*NN+n];
        y2[(size_t)g*NN*128 + (size_t)n*128 + c] = dv*a6[q];
    }
}

// ---------- phase 3c: gather layer-2 + bias + log_softmax ----------
__global__ __launch_bounds__(128) void k_fin(const float* __restrict__ y2,
        const int* __restrict__ offc,
        const int* __restrict__ cnt3, const int* __restrict__ cnt5, const int* __restrict__ cnt9,
        const int* __restrict__ rev, const float* __restrict__ dinvc,
        const float* __restrict__ bg2, float* __restrict__ emb){
    __shared__ float sm[2], ss[2];
    int b = blockIdx.x;
    int n = b & (NN-1), g = b >> 12;
    const int* cp = g==0?cnt3:(g==1?cnt5:cnt9);
    int rb = (g==0) ? 0 : (g==1 ? NN*3 : NN*8);
    int cnt = cp[n];
    int o = rb + offc[g*NN+n];
    float dv = dinvc[g*NN+n];
    int c = threadIdx.x;
    const float* yg = y2 + (size_t)g*NN*128;
    float s = yg[(size_t)n*128 + c];
    for (int e=0;e<cnt;e++){
        int i = rev[o+e];
        s += yg[(size_t)i*128 + c];
    }
    float v = dv*s + bg2[c];
    float m = v;
    #pragma unroll
    for (int st=1;st<64;st<<=1) m = fmaxf(m, __shfl_xor(m, st, 64));
    if ((c&63)==0) sm[c>>6] = m;
    __syncthreads();
    m = fmaxf(sm[0], sm[1]);
    float e = expf(v - m);
    float t = e;
    #pragma unroll
    for (int st=1;st<64;st<<=1) t += __shfl_xor(t, st, 64);
    if ((c&63)==0) ss[c>>6] = t;
    __syncthreads();
    t = ss[0]+ss[1];
    emb[n*384 + g*128 + c] = v - m - logf(t);
}

// ---------- phase 4: q/k projections -> bf16 hi/lo split ----------
__global__ __launch_bounds__(256) void k_qk(const float* __restrict__ emb,
        const float* __restrict__ Wq, const float* __restrict__ bq,
        const float* __restrict__ Wkey, const float* __restrict__ bkey,
        __bf16* __restrict__ qh, __bf16* __restrict__ ql,
        __bf16* __restrict__ kh, __bf16* __restrict__ kl){
    __shared__ float es[8][384];
    int n0 = blockIdx.x*8;
    int tid = threadIdx.x;
    for (int idx=tid; idx<8*384; idx+=256){
        int m = idx/384, k = idx%384;
        es[m][k] = emb[(n0+m)*384+k];
    }
    __syncthreads();
    int c = tid & 127;
    int sel = tid >> 7;
    const float* W = sel ? Wkey : Wq;
    float b = sel ? bkey[c] : bq[c];
    float acc[8];
    #pragma unroll
    for (int m=0;m<8;m++) acc[m]=b;
    for (int k=0;k<384;k++){
        float w = W[k*128+c];
        #pragma unroll
        for (int m=0;m<8;m++) acc[m] += es[m][k]*w;
    }
    __bf16* oh = sel ? kh : qh;
    __bf16* ol = sel ? kl : ql;
    #pragma unroll
    for (int m=0;m<8;m++){
        float v = acc[m];
        __bf16 h = (__bf16)v;
        oh[(size_t)(n0+m)*128+c] = h;
        ol[(size_t)(n0+m)*128+c] = (__bf16)(v - (float)h);
    }
}

// ---------- phase 5: scores (fp16) = q @ k^T via bf16-split MFMA + row max/min ----------
// Epilogue transposes each wave's 64x64 quadrant through LDS so global stores are
// 128B-contiguous half4 rows (the direct MFMA-layout store was 64B-scattered and
// held the kernel at ~1.5 TB/s write).
__global__ __launch_bounds__(256) void k_scores(
        const __bf16* __restrict__ qh, const __bf16* __restrict__ ql,
        const __bf16* __restrict__ kh, const __bf16* __restrict__ kl,
        _Float16* __restrict__ scores,
        unsigned* __restrict__ rowmaxenc, unsigned* __restrict__ rowminenc){
    __shared__ float tl[4][16][68];
    int bx = blockIdx.x & 31;
    int by = blockIdx.x >> 5;
    int tid = threadIdx.x;
    int w = tid >> 6, lane = tid & 63;
    int li = lane & 15, g = lane >> 4;
    int r0 = by*128 + (w>>1)*64;
    int c0 = bx*128 + (w&1)*64;

    f32x4 acc[4][4] = {};
    for (int ks=0; ks<4; ++ks){
        int kofs = ks*32 + g*8;
        bf16x8 ah[4], al[4], bh[4], bl[4];
        #pragma unroll
        for (int f=0; f<4; ++f){
            ah[f] = *(const bf16x8*)&qh[(size_t)(r0+f*16+li)*128 + kofs];
            al[f] = *(const bf16x8*)&ql[(size_t)(r0+f*16+li)*128 + kofs];
            bh[f] = *(const bf16x8*)&kh[(size_t)(c0+f*16+li)*128 + kofs];
            bl[f] = *(const bf16x8*)&kl[(size_t)(c0+f*16+li)*128 + kofs];
        }
        #pragma unroll
        for (int fr=0; fr<4; ++fr){
            #pragma unroll
            for (int fc=0; fc<4; ++fc){
                acc[fr][fc] = __builtin_amdgcn_mfma_f32_16x16x32_bf16(ah[fr], bh[fc], acc[fr][fc], 0, 0, 0);
                acc[fr][fc] = __builtin_amdgcn_mfma_f32_16x16x32_bf16(ah[fr], bl[fc], acc[fr][fc], 0, 0, 0);
                acc[fr][fc] = __builtin_amdgcn_mfma_f32_16x16x32_bf16(al[fr], bh[fc], acc[fr][fc], 0, 0, 0);
            }
        }
    }
    // row max/min from exact f32 accumulators
    #pragma unroll
    for (int fr=0; fr<4; ++fr){
        #pragma unroll
        for (int r=0; r<4; ++r){
            int row = r0 + fr*16 + g*4 + r;
            float mx = -INFINITY, mn = INFINITY;
            #pragma unroll
            for (int fc=0; fc<4; ++fc){
                float v = acc[fr][fc][r];
                mx = fmaxf(mx, v);
                mn = fminf(mn, v);
            }
            #pragma unroll
            for (int s=1; s<16; s<<=1){
                mx = fmaxf(mx, __shfl_xor(mx, s, 64));
                mn = fminf(mn, __shfl_xor(mn, s, 64));
            }
            if (li == 0){
                atomicMax(&rowmaxenc[row], enc_f(mx));
                atomicMin(&rowminenc[row], enc_f(mn));
            }
        }
    }
    // transpose epilogue: 16x64 f32 slab per wave per fr, then coalesced half4 stores
    for (int fr=0; fr<4; ++fr){
        #pragma unroll
        for (int fc=0; fc<4; ++fc)
            #pragma unroll
            for (int r=0; r<4; ++r)
                tl[w][g*4+r][fc*16+li] = acc[fr][fc][r];
        __syncthreads();
        #pragma unroll
        for (int q=0; q<4; ++q){
            int row = q*4 + g;
            float4 v;
            v.x = tl[w][row][li*4+0];
            v.y = tl[w][row][li*4+1];
            v.z = tl[w][row][li*4+2];
            v.w = tl[w][row][li*4+3];
            half4 hv = { (_Float16)v.x, (_Float16)v.y, (_Float16)v.z, (_Float16)v.w };
            *(half4*)&scores[(size_t)(r0+fr*16+row)*NN + c0 + li*4] = hv;
        }
        __syncthreads();
    }
}

// ---------- phase 5b: invr = 1/rowmax ----------
__global__ void k_invr(const unsigned* __restrict__ rowmaxenc, float* __restrict__ invr){
    int i = blockIdx.x*256 + threadIdx.x;
    if (i >= NN) return;
    invr[i] = 1.f/dec_f(rowmaxenc[i]);
}

// ---------- phase 6: streaming conv min/max over A (fp16 scores), half4/lane ----------
__global__ __launch_bounds__(256) void k_cconv(const _Float16* __restrict__ scores,
        const float* __restrict__ invr,
        const float* __restrict__ Wcy3, const float* __restrict__ Wcx3,
        const float* __restrict__ Wcy5, const float* __restrict__ Wcx5,
        const float* __restrict__ Wcy9, const float* __restrict__ Wcx9,
        const float* __restrict__ bcy3, const float* __restrict__ bcx3,
        const float* __restrict__ bcy5, const float* __restrict__ bcx5,
        const float* __restrict__ bcy9, const float* __restrict__ bcx9,
        float* __restrict__ mnmx){
    __shared__ float smn[4], smx[4];
    int tid = threadIdx.x;
    int w = tid >> 6, lane = tid & 63;
    int strip = blockIdx.x;                       // 0..16
    int i0 = (blockIdx.y*4 + w)*19;
    int colbase = strip*248 - 4 + lane*4;
    bool lv = (colbase >= 0) && (colbase + 3 < NN);
    bool outLane = (lane >= 1) && (lane < 63) && lv;

    float wy3[3],wx3[3],wy5[5],wx5[5],wy9[9],wx9[9];
    #pragma unroll
    for (int t=0;t<3;t++){ wy3[t]=Wcy3[t]; wx3[t]=Wcx3[t]; }
    #pragma unroll
    for (int t=0;t<5;t++){ wy5[t]=Wcy5[t]; wx5[t]=Wcx5[t]; }
    #pragma unroll
    for (int t=0;t<9;t++){ wy9[t]=Wcy9[t]; wx9[t]=Wcx9[t]; }
    float bc3 = bcy3[0]+bcx3[0];
    float bc5 = bcy5[0]+bcx5[0];
    float bc9 = bcy9[0]+bcx9[0];

    float4 win[9];
    float mn = INFINITY, mx = -INFINITY;
    const int laneL = lane - 1, laneR = lane + 1;

    for (int tb = 0; tb < 3; ++tb){
        #pragma unroll
        for (int u = 0; u < 9; ++u){
            int t  = tb*9 + u;
            int ri = i0 - 4 + t;
            float4 a = make_float4(0,0,0,0);
            if (((unsigned)ri < NN) && lv){
                float iv = invr[ri];
                half4 hv = *(const half4*)&scores[(size_t)ri*NN + colbase];
                a.x = (float)hv.x*iv; a.y = (float)hv.y*iv;
                a.z = (float)hv.z*iv; a.w = (float)hv.w*iv;
            }
            win[u] = a;
            int ro = i0 + t - 8;
            if (t >= 8 && ro < NN){
                float4 ctr = win[(u+5)%9];
                float4 wl = shfl4(ctr, laneL);
                float4 wr = shfl4(ctr, laneR);
                if (outLane){
                    float cw[12] = {wl.x,wl.y,wl.z,wl.w, ctr.x,ctr.y,ctr.z,ctr.w, wr.x,wr.y,wr.z,wr.w};
                    #pragma unroll
                    for (int c=0;c<4;c++){
                        float cx9 = ((win[(u+1)%9][c]*wx9[0] + win[(u+2)%9][c]*wx9[1]) + (win[(u+3)%9][c]*wx9[2] + win[(u+4)%9][c]*wx9[3]))
                                  + ((win[(u+5)%9][c]*wx9[4] + win[(u+6)%9][c]*wx9[5]) + (win[(u+7)%9][c]*wx9[6] + win[(u+8)%9][c]*wx9[7]))
                                  + win[u][c]*wx9[8];
                        float cx5 = ((win[(u+3)%9][c]*wx5[0] + win[(u+4)%9][c]*wx5[1]) + (win[(u+5)%9][c]*wx5[2] + win[(u+6)%9][c]*wx5[3]))
                                  + win[(u+7)%9][c]*wx5[4];
                        float cx3 = (win[(u+4)%9][c]*wx3[0] + win[(u+5)%9][c]*wx3[1]) + win[(u+6)%9][c]*wx3[2];
                        float cy9 = ((cw[c+0]*wy9[0] + cw[c+1]*wy9[1]) + (cw[c+2]*wy9[2] + cw[c+3]*wy9[3]))
                                  + ((cw[c+4]*wy9[4] + cw[c+5]*wy9[5]) + (cw[c+6]*wy9[6] + cw[c+7]*wy9[7]))
                                  + cw[c+8]*wy9[8];
                        float cy5 = ((cw[c+2]*wy5[0] + cw[c+3]*wy5[1]) + (cw[c+4]*wy5[2] + cw[c+5]*wy5[3]))
                                  + cw[c+6]*wy5[4];
                        float cy3 = (cw[c+3]*wy3[0] + cw[c+4]*wy3[1]) + cw[c+5]*wy3[2];
                        float c3v = cy3+cx3+bc3, c5v = cy5+cx5+bc5, c9v = cy9+cx9+bc9;
                        mn = fminf(mn, fminf(fminf(c3v,c5v),c9v));
                        mx = fmaxf(mx, fmaxf(fmaxf(c3v,c5v),c9v));
                    }
                }
            }
        }
    }
    #pragma unroll
    for (int m=1; m<64; m<<=1){
        mn = fminf(mn, __shfl_xor(mn, m, 64));
        mx = fmaxf(mx, __shfl_xor(mx, m, 64));
    }
    if (lane == 0){ smn[w] = mn; smx[w] = mx; }
    __syncthreads();
    if (tid == 0){
        float a0 = fminf(fminf(smn[0],smn[1]), fminf(smn[2],smn[3]));
        float b0 = fmaxf(fmaxf(smx[0],smx[1]), fmaxf(smx[2],smx[3]));
        int bid = blockIdx.y*gridDim.x + blockIdx.x;
        mnmx[bid] = a0;
        mnmx[1024 + bid] = b0;
    }
}

// ---------- phase 6b: kOt[d][0:4]=sum_j k[j][d]*Ot[j], [4:8]=...*Ty[j] ----------
__global__ __launch_bounds__(256) void k_kot(const __bf16* __restrict__ kh, const __bf16* __restrict__ kl,
        const float* __restrict__ x0, const float* __restrict__ Ty,
        float* __restrict__ kOt){
    __shared__ float red[256][8];
    int d = blockIdx.x, tid = threadIdx.x;
    float a[8] = {0,0,0,0,0,0,0,0};
    for (int j = tid; j < NN; j += 256){
        float kv = (float)kh[(size_t)j*128 + d] + (float)kl[(size_t)j*128 + d];
        float4 ot = *(const float4*)&x0[j*8+4];
        float4 ty = *(const float4*)&Ty[j*4];
        a[0] += kv*ot.x; a[1] += kv*ot.y; a[2] += kv*ot.z; a[3] += kv*ot.w;
        a[4] += kv*ty.x; a[5] += kv*ty.y; a[6] += kv*ty.z; a[7] += kv*ty.w;
    }
    #pragma unroll
    for (int q=0;q<8;q++) red[tid][q] = a[q];
    __syncthreads();
    for (int s=128; s>0; s>>=1){
        if (tid < s){
            #pragma unroll
            for (int q=0;q<8;q++) red[tid][q] += red[tid+s][q];
        }
        __syncthreads();
    }
    if (tid < 8) kOt[d*8 + tid] = red[0][tid];
}

// ---------- phase 6c: ASd = invr*(q@kOt), Bv from q@kTy + closed-form ----------
__global__ __launch_bounds__(256) void k_asd(
        const __bf16* __restrict__ qh, const __bf16* __restrict__ ql,
        const float* __restrict__ kOt,
        const unsigned* __restrict__ rowmaxenc, const float* __restrict__ maxd,
        const float* __restrict__ dOt, const float* __restrict__ colsum,
        const float* __restrict__ bcy3, const float* __restrict__ bcx3,
        const float* __restrict__ bcy5, const float* __restrict__ bcx5,
        const float* __restrict__ bcy9, const float* __restrict__ bcx9,
        float* __restrict__ ASdot, float* __restrict__ Bv){
    __shared__ float kst[128*8];
    int tid = threadIdx.x;
    for (int s = tid; s < 1024; s += 256) kst[s] = kOt[s];
    __syncthreads();
    int lane = tid & 63, r = tid >> 6;
    int i = blockIdx.x*4 + r;
    float a[8] = {0,0,0,0,0,0,0,0};
    #pragma unroll
    for (int dd=0; dd<2; ++dd){
        int d = lane + dd*64;
        float qv = (float)qh[(size_t)i*128 + d] + (float)ql[(size_t)i*128 + d];
        #pragma unroll
        for (int q=0;q<8;q++) a[q] += qv * kst[d*8+q];
    }
    #pragma unroll
    for (int m=1; m<64; m<<=1){
        #pragma unroll
        for (int q=0;q<8;q++) a[q] += __shfl_xor(a[q], m, 64);
    }
    if (lane == 0){
        float iv = 1.f/dec_f(rowmaxenc[i]);
        float imv = 1.f/maxd[i];
        float bcsum = bcy3[0]+bcx3[0]+bcy5[0]+bcx5[0]+bcy9[0]+bcx9[0];
        float k = 1.f + bcsum;
        float4 cs = *(const float4*)colsum;
        float4 dv = *(const float4*)&dOt[i*4];
        float4 pa = {iv*a[0], iv*a[1], iv*a[2], iv*a[3]};
        float4 b;
        b.x = cs.x*k - imv*dv.x + iv*a[4];
        b.y = cs.y*k - imv*dv.y + iv*a[5];
        b.z = cs.z*k - imv*dv.z + iv*a[6];
        b.w = cs.w*k - imv*dv.w + iv*a[7];
        *(float4*)&ASdot[i*4] = pa;
        *(float4*)&Bv[i*4]    = b;
    }
}

// ---------- phase 6d: global min/max = conv blocks U A-range U {0,1} ----------
__global__ __launch_bounds__(256) void k_gmm(const float* __restrict__ mnmx,
        const unsigned* __restrict__ rowminenc, const unsigned* __restrict__ rowmaxenc,
        float* __restrict__ gmm){
    __shared__ float smn[256], smx[256];
    int tid = threadIdx.x;
    float mn = 0.f, mx = 1.f;   // oushi range is exactly [0,1]
    for (int i=tid; i<NN; i+=256){
        float rmx = dec_f(rowmaxenc[i]);
        float q = dec_f(rowminenc[i]) / rmx;
        mn = fminf(mn, fminf(1.f, q));
        mx = fmaxf(mx, fmaxf(1.f, q));
    }
    for (int b=tid; b<918; b+=256){   // 17 x 54 blocks
        mn = fminf(mn, mnmx[b]);
        mx = fmaxf(mx, mnmx[1024+b]);
    }
    smn[tid]=mn; smx[tid]=mx; __syncthreads();
    for (int s=128;s>0;s>>=1){
        if (tid<s){ smn[tid]=fminf(smn[tid],smn[tid+s]); smx[tid]=fmaxf(smx[tid],smx[tid+s]); }
        __syncthreads();
    }
    if (tid==0){ gmm[0]=smn[0]; gmm[1]=smx[0]; }
}

// ---------- phase 7a: row-conv of ASdot + affine -> hfin ----------
__global__ void k_hfin(const float* __restrict__ ASdot, const float* __restrict__ Bv,
        const float* __restrict__ Wcx3, const float* __restrict__ Wcx5, const float* __restrict__ Wcx9,
        const float* __restrict__ gmm, const float* __restrict__ colsum,
        float* __restrict__ hfin){
    int i = blockIdx.x*256 + threadIdx.x;
    if (i >= NN) return;
    float Cx[9];
    #pragma unroll
    for (int o=-4;o<=4;o++){
        float c = Wcx9[o+4];
        if (o>=-2 && o<=2) c += Wcx5[o+2];
        if (o>=-1 && o<=1) c += Wcx3[o+1];
        Cx[o+4] = c;
    }
    float4 h = *(const float4*)&Bv[i*4];
    float4 a0 = *(const float4*)&ASdot[i*4];
    h.x += a0.x; h.y += a0.y; h.z += a0.z; h.w += a0.w;
    #pragma unroll
    for (int o=-4;o<=4;o++){
        int r = i + o;
        if ((unsigned)r < NN){
            float4 av = *(const float4*)&ASdot[r*4];
            float c = Cx[o+4];
            h.x += c*av.x; h.y += c*av.y; h.z += c*av.z; h.w += c*av.w;
        }
    }
    float mnv = gmm[0], mxv = gmm[1];
    float s = 1.f/(mxv-mnv), oa = -mnv*s;
    float4 cs = *(const float4*)colsum;
    float4 out;
    out.x = s*h.x + 5.f*oa*cs.x;
    out.y = s*h.y + 5.f*oa*cs.y;
    out.z = s*h.z + 5.f*oa*cs.z;
    out.w = s*h.w + 5.f*oa*cs.w;
    *(float4*)&hfin[i*4] = out;
}

// ---------- phase 7b: MLP head (barrier-free epilogue) ----------
__global__ __launch_bounds__(256) void k_mlp(const float* __restrict__ hfin,
        const float* __restrict__ Woff, const float* __restrict__ boff, const float* __restrict__ pw,
        const float* __restrict__ Wf1, const float* __restrict__ bf1,
        const float* __restrict__ Wf2, const float* __restrict__ bf2,
        const float* __restrict__ Wf3, const float* __restrict__ bf3,
        float* __restrict__ out){
    __shared__ float h1[8][128];
    __shared__ float h2[8][256];
    __shared__ float h3[8][256];
    int n0 = blockIdx.x*8, tid = threadIdx.x;
    float p = pw[0];
    {
        int c = tid & 127, mb = (tid>>7)*4;
        #pragma unroll
        for (int mm=0; mm<4; mm++){
            int m = mb+mm;
            float v = boff[c];
            #pragma unroll
            for (int k=0;k<4;k++) v += hfin[(n0+m)*4+k]*Woff[k*128+c];
            h1[m][c] = v>0.f ? v : p*v;
        }
    }
    __syncthreads();
    {
        int c = tid;
        float acc[8];
        #pragma unroll
        for (int m=0;m<8;m++) acc[m] = bf1[c];
        for (int k=0;k<128;k++){
            float w = Wf1[k*256+c];
            #pragma unroll
            for (int m=0;m<8;m++) acc[m] += h1[m][k]*w;
        }
        #pragma unroll
        for (int m=0;m<8;m++) h2[m][c] = acc[m]>0.f?acc[m]:0.f;
    }
    __syncthreads();
    {
        int c = tid;
        float acc[8];
        #pragma unroll
        for (int m=0;m<8;m++) acc[m] = bf2[c];
        for (int k=0;k<256;k++){
            float w = Wf2[k*256+c];
            #pragma unroll
            for (int m=0;m<8;m++) acc[m] += h2[m][k]*w;
        }
        #pragma unroll
        for (int m=0;m<8;m++) h3[m][c] = acc[m]>0.f?acc[m]:0.f;
    }
    __syncthreads();
    int w = tid >> 6, lane = tid & 63;
    #pragma unroll
    for (int mm=0; mm<2; ++mm){
        int m = w*2 + mm;
        float4 acc = {0,0,0,0};
        #pragma unroll
        for (int q=0;q<4;q++){
            int k = lane + q*64;
            float hv = h3[m][k];
            float4 w3 = *(const float4*)&Wf3[k*4];
            acc.x += hv*w3.x; acc.y += hv*w3.y; acc.z += hv*w3.z; acc.w += hv*w3.w;
        }
        #pragma unroll
        for (int s=1; s<64; s<<=1){
            acc.x += __shfl_xor(acc.x, s, 64);
            acc.y += __shfl_xor(acc.y, s, 64);
            acc.z += __shfl_xor(acc.z, s, 64);
            acc.w += __shfl_xor(acc.w, s, 64);
        }
        if (lane == 0){
            float4 o;
            o.x = acc.x + bf3[0]; o.y = acc.y + bf3[1];
            o.z = acc.z + bf3[2]; o.w = acc.w + bf3[3];
            *(float4*)&out[(n0+m)*4] = o;
        }
    }
}

// ---------- host ----------
extern "C" void kernel_launch(void* const* d_in, const int* in_sizes, int n_in,
                              void* d_out, int out_size, void* d_ws, size_t ws_size,
                              hipStream_t stream){
    const float* dx1  = (const float*)d_in[0];
    const float* dx2  = (const float*)d_in[1];
    const float* Wk   = (const float*)d_in[2];
    const float* bk   = (const float*)d_in[3];
    const float* Wg1  = (const float*)d_in[4];
    const float* bg1  = (const float*)d_in[5];
    const float* Wg2  = (const float*)d_in[6];
    const float* bg2  = (const float*)d_in[7];
    const float* Wq   = (const float*)d_in[8];
    const float* bq   = (const float*)d_in[9];
    const float* Wkey = (const float*)d_in[10];
    const float* bkey = (const float*)d_in[11];
    const float* Woff = (const float*)d_in[12];
    const float* boff = (const float*)d_in[13];
    const float* pw   = (const float*)d_in[14];
    const float* Wf1  = (const float*)d_in[15];
    const float* bf1  = (const float*)d_in[16];
    const float* Wf2  = (const float*)d_in[17];
    const float* bf2  = (const float*)d_in[18];
    const float* Wf3  = (const float*)d_in[19];
    const float* bf3  = (const float*)d_in[20];
    const float* Wcy3 = (const float*)d_in[21];
    const float* bcy3 = (const float*)d_in[22];
    const float* Wcx3 = (const float*)d_in[23];
    const float* bcx3 = (const float*)d_in[24];
    const float* Wcy5 = (const float*)d_in[25];
    const float* bcy5 = (const float*)d_in[26];
    const float* Wcx5 = (const float*)d_in[27];
    const float* bcx5 = (const float*)d_in[28];
    const float* Wcy9 = (const float*)d_in[29];
    const float* bcy9 = (const float*)d_in[30];
    const float* Wcx9 = (const float*)d_in[31];
    const float* bcx9 = (const float*)d_in[32];

    char* ws = (char*)d_ws;
    size_t off = 0;
    auto alloc = [&](size_t b)->void*{ void* p = ws + off; off += (b + 255) & ~(size_t)255; return p; };

    // --- zero-init region (one small memset) ---
    char* zbase = ws + off;
    float*    colsum    = (float*)   alloc(4*4);
    int*      cnt3      = (int*)     alloc((size_t)NN*4);
    int*      cnt5      = (int*)     alloc((size_t)NN*4);
    int*      cnt9      = (int*)     alloc((size_t)NN*4);
    int*      cur       = (int*)     alloc((size_t)3*NN*4);
    unsigned* rowmaxenc = (unsigned*)alloc((size_t)NN*4);
    size_t zbytes = (size_t)((ws + off) - zbase);
    unsigned* rowminenc = (unsigned*)alloc((size_t)NN*4);   // memset 0xFF

    // --- non-zeroed ---
    float*  x0    = (float*) alloc((size_t)NN*8*4);
    float2* pos   = (float2*)alloc((size_t)NN*8);
    float4* otp   = (float4*)alloc((size_t)NN*16);
    float*  maxd  = (float*) alloc((size_t)NN*4);
    int*    nbr   = (int*)   alloc((size_t)NN*9*4);
    int*    offc  = (int*)   alloc((size_t)3*NN*4);
    float*  dinvc = (float*) alloc((size_t)3*NN*4);
    int*    rev   = (int*)   alloc((size_t)NN*17*4);
    float*  xw    = (float*) alloc((size_t)NN*64*4);
    float*  y2    = (float*) alloc((size_t)3*NN*128*4);
    float*  emb   = (float*) alloc((size_t)NN*384*4);
    __bf16* qh    = (__bf16*)alloc((size_t)NN*128*2);
    __bf16* ql    = (__bf16*)alloc((size_t)NN*128*2);
    __bf16* kh    = (__bf16*)alloc((size_t)NN*128*2);
    __bf16* kl    = (__bf16*)alloc((size_t)NN*128*2);
    _Float16* scores = (_Float16*)alloc((size_t)NN*NN*2);
    float* Tyb    = (float*)alloc((size_t)NN*4*4);
    float* invr   = (float*)alloc((size_t)NN*4);
    float* dOt    = (float*)alloc((size_t)NN*4*4);
    float* kOt    = (float*)alloc((size_t)128*8*4);
    float* ASd    = (float*)alloc((size_t)NN*4*4);
    float* Bv     = (float*)alloc((size_t)NN*4*4);
    float* mnmx   = (float*)alloc((size_t)2*1024*4);
    float* gmm    = (float*)alloc(2*4);
    float* hfin   = (float*)alloc((size_t)NN*4*4);
    (void)ws_size; (void)in_sizes; (void)n_in; (void)out_size;

    hipMemsetAsync(zbase, 0, zbytes, stream);
    hipMemsetAsync(rowminenc, 0xFF, (size_t)NN*4, stream);

    k_prep<<<16,256,0,stream>>>(dx1,dx2,Wk,bk,x0,colsum,pos,otp);
    k_ty  <<<16,256,0,stream>>>(x0,Wcy3,Wcy5,Wcy9,Tyb);
    k_dist<<<NN/4,256,0,stream>>>(pos,otp,maxd,nbr,cnt3,cnt5,cnt9,dOt);
    k_scan<<<1,256,0,stream>>>(cnt3,cnt5,cnt9,offc,dinvc);
    k_fill<<<16,256,0,stream>>>(nbr,offc,cur,rev);

    k_y1  <<<NN*64/256,256,0,stream>>>(x0,Wg1,xw);
    k_h1y2<<<NN/4,256,0,stream>>>(xw,offc,cnt3,cnt5,cnt9,rev,dinvc,bg1,Wg2,y2);
    k_fin <<<NN*3,128,0,stream>>>(y2,offc,cnt3,cnt5,cnt9,rev,dinvc,bg2,emb);

    k_qk<<<NN/8,256,0,stream>>>(emb,Wq,bq,Wkey,bkey,qh,ql,kh,kl);
    k_scores<<<1024,256,0,stream>>>(qh,ql,kh,kl,scores,rowmaxenc,rowminenc);
    k_invr<<<16,256,0,stream>>>(rowmaxenc,invr);
    k_kot<<<128,256,0,stream>>>(kh,kl,x0,Tyb,kOt);

    k_cconv<<<dim3(17,54),256,0,stream>>>(scores,invr,
        Wcy3,Wcx3,Wcy5,Wcx5,Wcy9,Wcx9,
        bcy3,bcx3,bcy5,bcx5,bcy9,bcx9, mnmx);
    k_asd<<<NN/4,256,0,stream>>>(qh,ql,kOt,rowmaxenc,maxd,dOt,colsum,
        bcy3,bcx3,bcy5,bcx5,bcy9,bcx9, ASd, Bv);
    k_gmm<<<1,256,0,stream>>>(mnmx,rowminenc,rowmaxenc,gmm);
    k_hfin<<<16,256,0,stream>>>(ASd,Bv,Wcx3,Wcx5,Wcx9,gmm,colsum,hfin);
    k_mlp<<<NN/8,256,0,stream>>>(hfin,Woff,boff,pw,Wf1,bf1,Wf2,bf2,Wf3,bf3,(float*)d_out);
}